// Round 1
// baseline (2279.427 us; speedup 1.0000x reference)
//
#include <hip/hip_runtime.h>

#define T_ 4096
#define B_ 4

// ---------------- conv1+pool+relu+conv2+pool+relu ----------------
// x:(B,T,128) -> out:(B,T,64,10)
__global__ __launch_bounds__(256) void k_conv12(
    const float* __restrict__ x, const float* __restrict__ w1,
    const float* __restrict__ b1, const float* __restrict__ w2,
    const float* __restrict__ b2, float* __restrict__ out)
{
  __shared__ float sx[8][128];
  __shared__ float tmp[4][32][42];
  __shared__ float w1s[480];
  __shared__ float b1s[32];
  const int tid = threadIdx.x;
  const int t0 = blockIdx.x * 4;
  const int b = blockIdx.y;
  for (int i = tid; i < 1024; i += 256) {
    int r = i >> 7, c = i & 127;
    int t = t0 - 2 + r;
    sx[r][c] = (t >= 0 && t < T_) ? x[(b*T_ + t)*128 + c] : 0.f;
  }
  for (int i = tid; i < 480; i += 256) w1s[i] = w1[i];
  if (tid < 32) b1s[tid] = b1[tid];
  __syncthreads();
  // conv1 (5x3, pad_h=2) + pool3(W) + relu  -> tmp[tt][c1][wp], wp<42
  for (int i = tid; i < 4*32*42; i += 256) {
    int wp = i % 42;
    int c1 = (i / 42) & 31;
    int tt = i / (42*32);
    float m = -1e30f;
    #pragma unroll
    for (int j = 0; j < 3; j++) {
      int wb = wp*3 + j;
      float acc = 0.f;
      #pragma unroll
      for (int kh = 0; kh < 5; kh++)
        #pragma unroll
        for (int kw = 0; kw < 3; kw++)
          acc += sx[tt+kh][wb+kw] * w1s[c1*15 + kh*3 + kw];
      m = fmaxf(m, acc);
    }
    tmp[tt][c1][wp] = fmaxf(m + b1s[c1], 0.f);
  }
  __syncthreads();
  // conv2 (1x12) + pool3(W) + relu -> out, width 10 (uses raw w 0..29)
  for (int i = tid; i < 4*64*10; i += 256) {
    int wp = i % 10;
    int c2 = (i / 10) & 63;
    int tt = i / 640;
    float a0 = 0.f, a1 = 0.f, a2 = 0.f;
    const float* w2p = &w2[c2*384];
    for (int c1 = 0; c1 < 32; c1++) {
      const float* tp = &tmp[tt][c1][wp*3];
      #pragma unroll
      for (int kw = 0; kw < 12; kw++) {
        float wv = w2p[c1*12 + kw];
        a0 += tp[kw]   * wv;
        a1 += tp[kw+1] * wv;
        a2 += tp[kw+2] * wv;
      }
    }
    float m = fmaxf(fmaxf(a0, a1), a2) + b2[c2];
    out[((b*T_ + t0 + tt)*64 + c2)*10 + wp] = fmaxf(m, 0.f);
  }
}

// ---------------- conv3 (3x6, pad_h=1) + pool3 + relu -> h:(B,T,128) -------
__global__ __launch_bounds__(256) void k_conv3(
    const float* __restrict__ in, const float* __restrict__ w3,
    const float* __restrict__ b3, float* __restrict__ h)
{
  __shared__ float s2[18*640];
  const int tid = threadIdx.x;
  const int b = blockIdx.x >> 8;
  const int t0 = (blockIdx.x & 255) * 16;
  for (int i = tid; i < 18*640; i += 256) {
    int r = i / 640;
    int t = t0 - 1 + r;
    s2[i] = (t >= 0 && t < T_) ? in[(b*T_ + t)*640 + (i - r*640)] : 0.f;
  }
  __syncthreads();
  const int c3 = tid & 127;
  const int half = tid >> 7;
  float acc0[8] = {0,0,0,0,0,0,0,0};
  float acc1[8] = {0,0,0,0,0,0,0,0};
  float acc2[8] = {0,0,0,0,0,0,0,0};
  const float* wp = &w3[c3*1152];
  for (int c2 = 0; c2 < 64; c2++) {
    #pragma unroll
    for (int kh = 0; kh < 3; kh++) {
      float wv[6];
      #pragma unroll
      for (int kw = 0; kw < 6; kw++) wv[kw] = wp[(c2*3 + kh)*6 + kw];
      #pragma unroll
      for (int tt = 0; tt < 8; tt++) {
        const float* sp = &s2[(half*8 + tt + kh)*640 + c2*10];
        float xv[8];
        #pragma unroll
        for (int q2 = 0; q2 < 8; q2++) xv[q2] = sp[q2];
        #pragma unroll
        for (int kw = 0; kw < 6; kw++) {
          acc0[tt] += xv[kw]   * wv[kw];
          acc1[tt] += xv[kw+1] * wv[kw];
          acc2[tt] += xv[kw+2] * wv[kw];
        }
      }
    }
  }
  float bb = b3[c3];
  #pragma unroll
  for (int tt = 0; tt < 8; tt++) {
    float m = fmaxf(fmaxf(acc0[tt], acc1[tt]), acc2[tt]) + bb;
    h[(b*T_ + t0 + half*8 + tt)*128 + c3] = fmaxf(m, 0.f);
  }
}

// ---------------- LayerNorm over last dim (128), wave per row --------------
__device__ inline float wave_sum(float v) {
  #pragma unroll
  for (int m = 1; m < 64; m <<= 1) v += __shfl_xor(v, m, 64);
  return v;
}

__global__ __launch_bounds__(256) void k_ln(
    const float* __restrict__ in, const float* __restrict__ sc,
    const float* __restrict__ bi, float* __restrict__ out)
{
  const int lane = threadIdx.x & 63;
  const int row = blockIdx.x*4 + (threadIdx.x >> 6);
  float a = in[row*128 + lane];
  float c = in[row*128 + 64 + lane];
  float mean = wave_sum(a + c) * (1.f/128.f);
  float d0 = a - mean, d1 = c - mean;
  float var = wave_sum(d0*d0 + d1*d1) * (1.f/128.f);
  float rs = rsqrtf(var + 1e-5f);
  out[row*128 + lane]      = d0*rs*sc[lane]    + bi[lane];
  out[row*128 + 64 + lane] = d1*rs*sc[64+lane] + bi[64+lane];
}

// ---------------- generic fp32 GEMM: C(16384 x N) = A(16384 x K) @ W(K x N)
// EPI: 0 = +bias, 1 = relu(+bias), 2 = C += (+bias), 3 = Wo: C += s, C2 (skip)
template<int KDIM, int EPI>
__global__ __launch_bounds__(256) void k_gemm(
    const float* __restrict__ A, const float* __restrict__ W,
    const float* __restrict__ bias, float* __restrict__ C,
    float* __restrict__ C2, int N, int skip_init)
{
  __shared__ float As[16][68];
  __shared__ float Bs[16][64];
  const int tid = threadIdx.x;
  const int m0 = blockIdx.x * 64;
  const int n0 = blockIdx.y * 64;
  const int tx = tid & 15, ty = tid >> 4;
  float acc[4][4] = {};
  for (int k0 = 0; k0 < KDIM; k0 += 16) {
    {
      int r = tid >> 2, j = tid & 3;
      float4 av = *(const float4*)&A[(m0 + r)*KDIM + k0 + j*4];
      As[j*4+0][r] = av.x;
      As[j*4+1][r] = av.y;
      As[j*4+2][r] = av.z;
      As[j*4+3][r] = av.w;
      int kk = tid >> 6, cc = tid & 63;
      #pragma unroll
      for (int i2 = 0; i2 < 4; i2++)
        Bs[kk*4+i2][cc] = W[(k0 + kk*4 + i2)*N + n0 + cc];
    }
    __syncthreads();
    #pragma unroll
    for (int k = 0; k < 16; k++) {
      float4 a4 = *(const float4*)&As[k][ty*4];
      float4 b4 = *(const float4*)&Bs[k][tx*4];
      float av[4] = {a4.x, a4.y, a4.z, a4.w};
      float bv[4] = {b4.x, b4.y, b4.z, b4.w};
      #pragma unroll
      for (int i = 0; i < 4; i++)
        #pragma unroll
        for (int j = 0; j < 4; j++)
          acc[i][j] += av[i]*bv[j];
    }
    __syncthreads();
  }
  float bv4[4];
  #pragma unroll
  for (int j = 0; j < 4; j++) bv4[j] = bias[n0 + tx*4 + j];
  #pragma unroll
  for (int i = 0; i < 4; i++) {
    int row = m0 + ty*4 + i;
    float* cp = &C[row*N + n0 + tx*4];
    float v0 = acc[i][0] + bv4[0];
    float v1 = acc[i][1] + bv4[1];
    float v2 = acc[i][2] + bv4[2];
    float v3 = acc[i][3] + bv4[3];
    if (EPI == 0) {
      float4 o; o.x=v0; o.y=v1; o.z=v2; o.w=v3;
      *(float4*)cp = o;
    } else if (EPI == 1) {
      float4 o; o.x=fmaxf(v0,0.f); o.y=fmaxf(v1,0.f); o.z=fmaxf(v2,0.f); o.w=fmaxf(v3,0.f);
      *(float4*)cp = o;
    } else if (EPI == 2) {
      float4 old = *(const float4*)cp;
      float4 o; o.x=old.x+v0; o.y=old.y+v1; o.z=old.z+v2; o.w=old.w+v3;
      *(float4*)cp = o;
    } else {
      float4 old = *(const float4*)cp;
      float4 o; o.x=old.x+v0; o.y=old.y+v1; o.z=old.z+v2; o.w=old.w+v3;
      *(float4*)cp = o;
      float* sp = &C2[row*N + n0 + tx*4];
      if (skip_init) {
        float4 s; s.x=v0; s.y=v1; s.z=v2; s.w=v3;
        *(float4*)sp = s;
      } else {
        float4 os = *(const float4*)sp;
        float4 s; s.x=os.x+v0; s.y=os.y+v1; s.z=os.z+v2; s.w=os.w+v3;
        *(float4*)sp = s;
      }
    }
  }
}

// ---------------- dilated local attention (ATTN_LEN=5), wave per (b,t) -----
__global__ __launch_bounds__(256) void k_attn(
    const float* __restrict__ q, const float* __restrict__ kk,
    const float* __restrict__ vv, const float* __restrict__ Er,
    float* __restrict__ out, int dil)
{
  const int w = threadIdx.x >> 6, lane = threadIdx.x & 63;
  const int bt = blockIdx.x * 4 + w;
  const int b = bt >> 12;
  const int t = bt & 4095;
  #pragma unroll
  for (int h = 0; h < 2; h++) {
    float qd = q[bt*128 + h*64 + lane];
    float s[5];
    int tpc_arr[5];
    #pragma unroll
    for (int a = 0; a < 5; a++) {
      int tp = t + (a-2)*dil;
      bool valid = (tp >= 0 && tp < T_);
      int tpc = tp < 0 ? 0 : (tp > T_-1 ? T_-1 : tp);
      tpc_arr[a] = tpc;
      float kd = kk[(b*T_ + tpc)*128 + h*64 + lane];
      float er = Er[(h*5 + a)*64 + lane];
      float p = qd * (kd + er);
      p = wave_sum(p);
      s[a] = valid ? p * 0.125f : -1e30f;
    }
    float mx = s[0];
    #pragma unroll
    for (int a = 1; a < 5; a++) mx = fmaxf(mx, s[a]);
    float p[5], psum = 0.f;
    #pragma unroll
    for (int a = 0; a < 5; a++) { p[a] = __expf(s[a]-mx); psum += p[a]; }
    float inv = 1.f/psum;
    float o = 0.f;
    #pragma unroll
    for (int a = 0; a < 5; a++)
      o += p[a] * vv[(b*T_ + tpc_arr[a])*128 + h*64 + lane];
    out[bt*128 + h*64 + lane] = o * inv;
  }
}

// ---------------- tail kernels --------------------------------------------
__global__ __launch_bounds__(256) void k_out(
    const float* __restrict__ h, const float* __restrict__ Wout,
    const float* __restrict__ bout, float* __restrict__ out)
{
  int idx = blockIdx.x*256 + threadIdx.x;   // 32768
  int bt = idx >> 1, j = idx & 1;
  float acc = bout[j];
  const float* hp = &h[bt*128];
  #pragma unroll 4
  for (int k2 = 0; k2 < 128; k2++)
    acc += fmaxf(hp[k2], 0.f) * Wout[k2*2 + j];
  out[idx] = acc;
}

__global__ __launch_bounds__(256) void k_red1(
    const float* __restrict__ ss, float* __restrict__ part)
{
  __shared__ float red[256];
  int b = blockIdx.x >> 5, g = blockIdx.x & 31;
  int c = threadIdx.x & 127, hf = threadIdx.x >> 7;
  float acc = 0.f;
  for (int i2 = 0; i2 < 64; i2++) {
    int t = g*128 + i2*2 + hf;
    acc += fmaxf(ss[(b*T_ + t)*128 + c], 0.f);
  }
  red[threadIdx.x] = acc;
  __syncthreads();
  if (threadIdx.x < 128)
    part[(b*32+g)*128 + threadIdx.x] = red[threadIdx.x] + red[threadIdx.x+128];
}

__global__ __launch_bounds__(256) void k_red2(
    const float* __restrict__ part, float* __restrict__ meanb)
{
  int idx = blockIdx.x*256 + threadIdx.x;   // 512
  if (idx >= 512) return;
  int b = idx >> 7, c = idx & 127;
  float s = 0.f;
  for (int g = 0; g < 32; g++) s += part[(b*32+g)*128 + c];
  meanb[idx] = s * (1.f/4096.f);
}

__global__ __launch_bounds__(256) void k_tproj(
    const float* __restrict__ meanb, const float* __restrict__ Wt,
    const float* __restrict__ bt, float* __restrict__ out)
{
  int idx = blockIdx.x*256 + threadIdx.x;
  if (idx >= 1200) return;
  int b = idx / 300, j = idx % 300;
  float acc = bt[j];
  #pragma unroll 4
  for (int k2 = 0; k2 < 128; k2++)
    acc += meanb[b*128 + k2] * Wt[k2*300 + j];
  out[32768 + idx] = acc;
}

// ---------------- launcher -------------------------------------------------
extern "C" void kernel_launch(void* const* d_in, const int* in_sizes, int n_in,
                              void* d_out, int out_size, void* d_ws, size_t ws_size,
                              hipStream_t stream)
{
  const float* x    = (const float*)d_in[0];
  const float* c1w  = (const float*)d_in[1];
  const float* c1b  = (const float*)d_in[2];
  const float* c2w  = (const float*)d_in[3];
  const float* c2b  = (const float*)d_in[4];
  const float* c3w  = (const float*)d_in[5];
  const float* c3b  = (const float*)d_in[6];
  const float* ln1s = (const float*)d_in[7];
  const float* ln1b = (const float*)d_in[8];
  const float* ln2s = (const float*)d_in[9];
  const float* ln2b = (const float*)d_in[10];
  const float* Wq   = (const float*)d_in[11];
  const float* bq   = (const float*)d_in[12];
  const float* Wk   = (const float*)d_in[13];
  const float* bk   = (const float*)d_in[14];
  const float* Wv   = (const float*)d_in[15];
  const float* bv   = (const float*)d_in[16];
  const float* Wo   = (const float*)d_in[17];
  const float* bo   = (const float*)d_in[18];
  const float* Er   = (const float*)d_in[19];
  const float* W1   = (const float*)d_in[20];
  const float* b1   = (const float*)d_in[21];
  const float* W2   = (const float*)d_in[22];
  const float* b2   = (const float*)d_in[23];
  const float* Wout = (const float*)d_in[24];
  const float* bout = (const float*)d_in[25];
  const float* Wt   = (const float*)d_in[26];
  const float* bt   = (const float*)d_in[27];

  float* ws    = (float*)d_ws;
  float* buf2  = ws;                       // (B,T,64,10) = 10,485,760 fl
  float* hid   = ws;                       // reused after conv3: 8,388,608 fl
  float* hbuf  = ws + 10485760;            // (B,T,128)
  float* ssum  = hbuf  + 2097152;
  float* xl    = ssum  + 2097152;
  float* qb    = xl    + 2097152;
  float* kb    = qb    + 2097152;
  float* vb2   = kb    + 2097152;
  float* attnb = vb2   + 2097152;
  float* part  = attnb + 2097152;          // 16384
  float* meanb = part  + 16384;            // 512
  float* outf  = (float*)d_out;

  k_conv12<<<dim3(T_/4, B_), 256, 0, stream>>>(x, c1w, c1b, c2w, c2b, buf2);
  k_conv3<<<dim3(B_*256), 256, 0, stream>>>(buf2, c3w, c3b, hbuf);

  for (int l = 0; l < 9; l++) {
    k_ln<<<4096, 256, 0, stream>>>(hbuf, ln1s + l*128, ln1b + l*128, xl);
    k_gemm<128,0><<<dim3(256,2), 256, 0, stream>>>(xl, Wq + l*16384, bq + l*128, qb,  nullptr, 128, 0);
    k_gemm<128,0><<<dim3(256,2), 256, 0, stream>>>(xl, Wk + l*16384, bk + l*128, kb,  nullptr, 128, 0);
    k_gemm<128,0><<<dim3(256,2), 256, 0, stream>>>(xl, Wv + l*16384, bv + l*128, vb2, nullptr, 128, 0);
    k_attn<<<4096, 256, 0, stream>>>(qb, kb, vb2, Er + l*640, attnb, 1 << l);
    k_gemm<128,3><<<dim3(256,2), 256, 0, stream>>>(attnb, Wo + l*16384, bo + l*128, hbuf, ssum, 128, (l==0) ? 1 : 0);
    k_ln<<<4096, 256, 0, stream>>>(hbuf, ln2s + l*128, ln2b + l*128, xl);
    k_gemm<128,1><<<dim3(256,8), 256, 0, stream>>>(xl, W1 + l*65536, b1 + l*512, hid, nullptr, 512, 0);
    k_gemm<512,2><<<dim3(256,2), 256, 0, stream>>>(hid, W2 + l*65536, b2 + l*128, hbuf, nullptr, 128, 0);
  }

  k_out<<<128, 256, 0, stream>>>(hbuf, Wout, bout, outf);
  k_red1<<<128, 256, 0, stream>>>(ssum, part);
  k_red2<<<2, 256, 0, stream>>>(part, meanb);
  k_tproj<<<5, 256, 0, stream>>>(meanb, Wt, bt, outf);
}

// Round 2
// 2081.888 us; speedup vs baseline: 1.0949x; 1.0949x over previous
//
#include <hip/hip_runtime.h>

#define T_ 4096
#define B_ 4

typedef unsigned short u16;
typedef __bf16 bf16x8 __attribute__((ext_vector_type(8)));
typedef float f32x4 __attribute__((ext_vector_type(4)));

__device__ inline void splitbf(float v, u16& h, u16& l) {
  __bf16 hb = (__bf16)v;
  float r = v - (float)hb;
  __bf16 lb = (__bf16)r;
  h = __builtin_bit_cast(u16, hb);
  l = __builtin_bit_cast(u16, lb);
}

// ---------------- conv1+pool+relu+conv2+pool+relu ----------------
// x:(B,T,128) -> out:(B,T,64,10).  Block: (t-group of 4, b). 256 thr.
// w2 (64x384 = 98KB) staged in LDS once per block; thread = (c2, tt).
__global__ __launch_bounds__(256, 1) void k_conv12(
    const float* __restrict__ x, const float* __restrict__ w1,
    const float* __restrict__ b1, const float* __restrict__ w2,
    const float* __restrict__ b2, float* __restrict__ out)
{
  __shared__ float sx[8][132];
  __shared__ float w1s[480];
  __shared__ float b1s[32];
  __shared__ float tmp[32][4][44];   // [c1][tt][w<42], tt-stride 44 (bank-safe)
  __shared__ float w2s[64][386];     // stride 386: even (float2 ok), 386%32=2
  const int tid = threadIdx.x;
  const int t0 = blockIdx.x * 4;
  const int b = blockIdx.y;
  for (int i = tid; i < 1024; i += 256) {
    int r = i >> 7, c = i & 127;
    int t = t0 - 2 + r;
    sx[r][c] = (t >= 0 && t < T_) ? x[(b*T_ + t)*128 + c] : 0.f;
  }
  for (int i = tid; i < 480; i += 256) w1s[i] = w1[i];
  if (tid < 32) b1s[tid] = b1[tid];
  for (int i = tid; i < 6144; i += 256) {
    float4 v = *(const float4*)&w2[i*4];
    int el = i*4; int c2 = el / 384; int off = el - c2*384;
    w2s[c2][off] = v.x; w2s[c2][off+1] = v.y; w2s[c2][off+2] = v.z; w2s[c2][off+3] = v.w;
  }
  __syncthreads();
  // conv1 (5x3, pad_h=2) + pool3(W) + relu -> tmp   (5376 items = 21*256)
  for (int i = tid; i < 5376; i += 256) {
    int wp = i % 42;
    int c1 = (i / 42) & 31;
    int tt = i / 1344;
    float m = -1e30f;
    #pragma unroll
    for (int j = 0; j < 3; j++) {
      int wb = wp*3 + j;
      float acc = 0.f;
      #pragma unroll
      for (int kh = 0; kh < 5; kh++)
        #pragma unroll
        for (int kw = 0; kw < 3; kw++)
          acc += sx[tt+kh][wb+kw] * w1s[c1*15 + kh*3 + kw];
      m = fmaxf(m, acc);
    }
    tmp[c1][tt][wp] = fmaxf(m + b1s[c1], 0.f);
  }
  __syncthreads();
  // conv2 (1x12) + pool3 + relu.  thread = (c2 = tid>>2, tt = tid&3)
  const int c2 = tid >> 2, tt = tid & 3;
  float acc[30];
  #pragma unroll
  for (int w = 0; w < 30; w++) acc[w] = 0.f;
  const float* wrow = &w2s[c2][0];
  for (int c1 = 0; c1 < 32; c1++) {
    float tv[42];
    const float* tp = &tmp[c1][tt][0];
    #pragma unroll
    for (int q = 0; q < 21; q++) {
      float2 v2 = *(const float2*)&tp[q*2];
      tv[2*q] = v2.x; tv[2*q+1] = v2.y;
    }
    float wv[12];
    #pragma unroll
    for (int q = 0; q < 6; q++) {
      float2 v2 = *(const float2*)&wrow[c1*12 + q*2];
      wv[2*q] = v2.x; wv[2*q+1] = v2.y;
    }
    #pragma unroll
    for (int kw = 0; kw < 12; kw++)
      #pragma unroll
      for (int w = 0; w < 30; w++)
        acc[w] += tv[w+kw] * wv[kw];
  }
  float bb = b2[c2];
  #pragma unroll
  for (int wp = 0; wp < 10; wp++) {
    float m = fmaxf(fmaxf(acc[3*wp], acc[3*wp+1]), acc[3*wp+2]) + bb;
    out[((b*T_ + t0 + tt)*64 + c2)*10 + wp] = fmaxf(m, 0.f);
  }
}

// ---------------- conv3 (3x6, pad_h=1) + pool3 + relu -> h:(B,T,128) -------
__global__ __launch_bounds__(256) void k_conv3(
    const float* __restrict__ in, const float* __restrict__ w3,
    const float* __restrict__ b3, float* __restrict__ h)
{
  __shared__ float s2[18*640];
  const int tid = threadIdx.x;
  const int b = blockIdx.x >> 8;
  const int t0 = (blockIdx.x & 255) * 16;
  for (int i = tid; i < 18*640; i += 256) {
    int r = i / 640;
    int t = t0 - 1 + r;
    s2[i] = (t >= 0 && t < T_) ? in[(b*T_ + t)*640 + (i - r*640)] : 0.f;
  }
  __syncthreads();
  const int c3 = tid & 127;
  const int half = tid >> 7;
  float acc0[8] = {0,0,0,0,0,0,0,0};
  float acc1[8] = {0,0,0,0,0,0,0,0};
  float acc2[8] = {0,0,0,0,0,0,0,0};
  const float* wp = &w3[c3*1152];
  for (int c2 = 0; c2 < 64; c2++) {
    #pragma unroll
    for (int kh = 0; kh < 3; kh++) {
      float wv[6];
      #pragma unroll
      for (int q = 0; q < 3; q++) {
        float2 v2 = *(const float2*)&wp[(c2*3 + kh)*6 + q*2];
        wv[2*q] = v2.x; wv[2*q+1] = v2.y;
      }
      #pragma unroll
      for (int tt = 0; tt < 8; tt++) {
        const float* sp = &s2[(half*8 + tt + kh)*640 + c2*10];
        float xv[8];
        #pragma unroll
        for (int q = 0; q < 4; q++) {
          float2 v2 = *(const float2*)&sp[q*2];
          xv[2*q] = v2.x; xv[2*q+1] = v2.y;
        }
        #pragma unroll
        for (int kw = 0; kw < 6; kw++) {
          acc0[tt] += xv[kw]   * wv[kw];
          acc1[tt] += xv[kw+1] * wv[kw];
          acc2[tt] += xv[kw+2] * wv[kw];
        }
      }
    }
  }
  float bb = b3[c3];
  #pragma unroll
  for (int tt = 0; tt < 8; tt++) {
    float m = fmaxf(fmaxf(acc0[tt], acc1[tt]), acc2[tt]) + bb;
    h[(b*T_ + t0 + half*8 + tt)*128 + c3] = fmaxf(m, 0.f);
  }
}

// ---------------- LayerNorm (128) -> packed hi/lo bf16 planes --------------
__device__ inline float wave_sum(float v) {
  #pragma unroll
  for (int m = 1; m < 64; m <<= 1) v += __shfl_xor(v, m, 64);
  return v;
}

__global__ __launch_bounds__(256) void k_ln(
    const float* __restrict__ in, const float* __restrict__ sc,
    const float* __restrict__ bi, u16* __restrict__ oh, u16* __restrict__ ol)
{
  const int lane = threadIdx.x & 63;
  const int row = blockIdx.x*4 + (threadIdx.x >> 6);
  float a = in[row*128 + lane];
  float c = in[row*128 + 64 + lane];
  float mean = wave_sum(a + c) * (1.f/128.f);
  float d0 = a - mean, d1 = c - mean;
  float var = wave_sum(d0*d0 + d1*d1) * (1.f/128.f);
  float rs = rsqrtf(var + 1e-5f);
  float v0 = d0*rs*sc[lane]    + bi[lane];
  float v1 = d1*rs*sc[64+lane] + bi[64+lane];
  u16 h0, l0, h1, l1;
  splitbf(v0, h0, l0); splitbf(v1, h1, l1);
  oh[row*128 + lane] = h0;      ol[row*128 + lane] = l0;
  oh[row*128 + 64 + lane] = h1; ol[row*128 + 64 + lane] = l1;
}

// ---------------- weight prep: W[K][N] fp32 -> WT[n][k] hi/lo bf16 ---------
__global__ __launch_bounds__(256) void k_wprep(
    const float* __restrict__ src, u16* __restrict__ dh, u16* __restrict__ dl,
    int K, int N, int nm, int dstMatStride)
{
  int idx = blockIdx.x*256 + threadIdx.x;
  int total = nm*K*N;
  if (idx >= total) return;
  int mat = idx / (K*N);
  int rem = idx - mat*(K*N);
  int n = rem / K;
  int k = rem - n*K;
  float v = src[(size_t)(mat*K + k)*N + n];
  u16 h, l; splitbf(v, h, l);
  size_t o = (size_t)mat*dstMatStride + (size_t)n*K + k;
  dh[o] = h; dl[o] = l;
}

// ---------------- split-bf16 MFMA GEMM core --------------------------------
// C(16384 x N) = A(16384 x K) @ W(K x N);  A packed [M][K], W packed [N][K].
// 3-product: hi*hi + hi*lo + lo*hi  (error ~2^-18).
#define MFMA(a,b,c) __builtin_amdgcn_mfma_f32_16x16x32_bf16((a),(b),(c),0,0,0)

template<int KDIM>
__device__ inline void gemm_core(
    const u16* __restrict__ Ah, const u16* __restrict__ Al,
    const u16* __restrict__ Wh, const u16* __restrict__ Wl,
    int m0, int n0, int lane, f32x4 acc[2][2])
{
  const int lr = lane & 15, lk = (lane >> 4) * 8;
  const u16* a_h = Ah + (size_t)(m0 + lr)*KDIM + lk;
  const u16* a_l = Al + (size_t)(m0 + lr)*KDIM + lk;
  const u16* b_h = Wh + (size_t)(n0 + lr)*KDIM + lk;
  const u16* b_l = Wl + (size_t)(n0 + lr)*KDIM + lk;
  #pragma unroll
  for (int ks = 0; ks < KDIM/32; ks++) {
    bf16x8 ah0 = *(const bf16x8*)(a_h + ks*32);
    bf16x8 ah1 = *(const bf16x8*)(a_h + 16*KDIM + ks*32);
    bf16x8 al0 = *(const bf16x8*)(a_l + ks*32);
    bf16x8 al1 = *(const bf16x8*)(a_l + 16*KDIM + ks*32);
    bf16x8 bh0 = *(const bf16x8*)(b_h + ks*32);
    bf16x8 bh1 = *(const bf16x8*)(b_h + 16*KDIM + ks*32);
    bf16x8 bl0 = *(const bf16x8*)(b_l + ks*32);
    bf16x8 bl1 = *(const bf16x8*)(b_l + 16*KDIM + ks*32);
    acc[0][0] = MFMA(ah0, bl0, acc[0][0]);
    acc[0][0] = MFMA(al0, bh0, acc[0][0]);
    acc[0][0] = MFMA(ah0, bh0, acc[0][0]);
    acc[0][1] = MFMA(ah0, bl1, acc[0][1]);
    acc[0][1] = MFMA(al0, bh1, acc[0][1]);
    acc[0][1] = MFMA(ah0, bh1, acc[0][1]);
    acc[1][0] = MFMA(ah1, bl0, acc[1][0]);
    acc[1][0] = MFMA(al1, bh0, acc[1][0]);
    acc[1][0] = MFMA(ah1, bh0, acc[1][0]);
    acc[1][1] = MFMA(ah1, bl1, acc[1][1]);
    acc[1][1] = MFMA(al1, bh1, acc[1][1]);
    acc[1][1] = MFMA(ah1, bh1, acc[1][1]);
  }
}

// EPI: 0 = C=val   1 = relu+pack->Oh/Ol   2 = C+=val   3 = C+=val, C2 skip-acc
template<int EPI>
__device__ inline void gmm_epi(
    f32x4 acc[2][2], const float* __restrict__ bias, int N,
    float* __restrict__ C, float* __restrict__ C2, int skip_init,
    u16* __restrict__ Oh, u16* __restrict__ Ol, int m0, int n0, int lane)
{
  const int lr = lane & 15, lg = lane >> 4;
  #pragma unroll
  for (int mf = 0; mf < 2; mf++)
    #pragma unroll
    for (int nf = 0; nf < 2; nf++) {
      int col = n0 + nf*16 + lr;
      float bb = bias[col];
      #pragma unroll
      for (int r = 0; r < 4; r++) {
        int row = m0 + mf*16 + lg*4 + r;
        float val = acc[mf][nf][r] + bb;
        size_t o = (size_t)row*N + col;
        if (EPI == 0) {
          C[o] = val;
        } else if (EPI == 1) {
          float v = fmaxf(val, 0.f);
          u16 h, l; splitbf(v, h, l);
          Oh[o] = h; Ol[o] = l;
        } else if (EPI == 2) {
          C[o] += val;
        } else {
          C[o] += val;
          if (skip_init) C2[o] = val; else C2[o] += val;
        }
      }
    }
}

template<int KDIM, int EPI>
__global__ __launch_bounds__(256) void k_gmm(
    const u16* __restrict__ Ah, const u16* __restrict__ Al,
    const u16* __restrict__ Wh, const u16* __restrict__ Wl,
    const float* __restrict__ bias, int N,
    float* __restrict__ C, float* __restrict__ C2, int skip_init,
    u16* __restrict__ Oh, u16* __restrict__ Ol)
{
  const int lane = threadIdx.x & 63;
  const int wid = threadIdx.x >> 6;
  const int m0 = blockIdx.x*64 + (wid >> 1)*32;
  const int n0 = blockIdx.y*64 + (wid & 1)*32;
  f32x4 acc[2][2] = {};
  gemm_core<KDIM>(Ah, Al, Wh, Wl, m0, n0, lane, acc);
  gmm_epi<EPI>(acc, bias, N, C, C2, skip_init, Oh, Ol, m0, n0, lane);
}

// fused QKV: grid.z selects q/k/v
__global__ __launch_bounds__(256) void k_gqkv(
    const u16* __restrict__ Ah, const u16* __restrict__ Al,
    const u16* __restrict__ Wh, const u16* __restrict__ Wl,
    const float* __restrict__ bq, const float* __restrict__ bk,
    const float* __restrict__ bv, float* __restrict__ outbase)
{
  const int z = blockIdx.z;
  const u16* wh = Wh + z*16384;
  const u16* wl = Wl + z*16384;
  const float* bias = (z == 0) ? bq : (z == 1) ? bk : bv;
  float* C = outbase + (size_t)z*2097152;
  const int lane = threadIdx.x & 63;
  const int wid = threadIdx.x >> 6;
  const int m0 = blockIdx.x*64 + (wid >> 1)*32;
  const int n0 = blockIdx.y*64 + (wid & 1)*32;
  f32x4 acc[2][2] = {};
  gemm_core<128>(Ah, Al, wh, wl, m0, n0, lane, acc);
  gmm_epi<0>(acc, bias, 128, C, nullptr, 0, nullptr, nullptr, m0, n0, lane);
}

// ---------------- dilated local attention -> packed hi/lo ------------------
__global__ __launch_bounds__(256) void k_attn(
    const float* __restrict__ q, const float* __restrict__ kk,
    const float* __restrict__ vv, const float* __restrict__ Er,
    u16* __restrict__ oh, u16* __restrict__ ol, int dil)
{
  const int w = threadIdx.x >> 6, lane = threadIdx.x & 63;
  const int bt = blockIdx.x * 4 + w;
  const int b = bt >> 12;
  const int t = bt & 4095;
  #pragma unroll
  for (int h = 0; h < 2; h++) {
    float qd = q[bt*128 + h*64 + lane];
    float s[5];
    int tpc_arr[5];
    #pragma unroll
    for (int a = 0; a < 5; a++) {
      int tp = t + (a-2)*dil;
      bool valid = (tp >= 0 && tp < T_);
      int tpc = tp < 0 ? 0 : (tp > T_-1 ? T_-1 : tp);
      tpc_arr[a] = tpc;
      float kd = kk[(b*T_ + tpc)*128 + h*64 + lane];
      float er = Er[(h*5 + a)*64 + lane];
      float p = qd * (kd + er);
      p = wave_sum(p);
      s[a] = valid ? p * 0.125f : -1e30f;
    }
    float mx = s[0];
    #pragma unroll
    for (int a = 1; a < 5; a++) mx = fmaxf(mx, s[a]);
    float p[5], psum = 0.f;
    #pragma unroll
    for (int a = 0; a < 5; a++) { p[a] = __expf(s[a]-mx); psum += p[a]; }
    float inv = 1.f/psum;
    float o = 0.f;
    #pragma unroll
    for (int a = 0; a < 5; a++)
      o += p[a] * vv[(b*T_ + tpc_arr[a])*128 + h*64 + lane];
    float vo = o * inv;
    u16 hh, ll;
    splitbf(vo, hh, ll);
    oh[bt*128 + h*64 + lane] = hh;
    ol[bt*128 + h*64 + lane] = ll;
  }
}

// ---------------- tail kernels --------------------------------------------
__global__ __launch_bounds__(256) void k_out(
    const float* __restrict__ h, const float* __restrict__ Wout,
    const float* __restrict__ bout, float* __restrict__ out)
{
  int idx = blockIdx.x*256 + threadIdx.x;   // 32768
  int bt = idx >> 1, j = idx & 1;
  float acc = bout[j];
  const float* hp = &h[bt*128];
  #pragma unroll 4
  for (int k2 = 0; k2 < 128; k2++)
    acc += fmaxf(hp[k2], 0.f) * Wout[k2*2 + j];
  out[idx] = acc;
}

__global__ __launch_bounds__(256) void k_red1(
    const float* __restrict__ ss, float* __restrict__ part)
{
  __shared__ float red[256];
  int b = blockIdx.x >> 5, g = blockIdx.x & 31;
  int c = threadIdx.x & 127, hf = threadIdx.x >> 7;
  float acc = 0.f;
  for (int i2 = 0; i2 < 64; i2++) {
    int t = g*128 + i2*2 + hf;
    acc += fmaxf(ss[(b*T_ + t)*128 + c], 0.f);
  }
  red[threadIdx.x] = acc;
  __syncthreads();
  if (threadIdx.x < 128)
    part[(b*32+g)*128 + threadIdx.x] = red[threadIdx.x] + red[threadIdx.x+128];
}

__global__ __launch_bounds__(256) void k_red2(
    const float* __restrict__ part, float* __restrict__ meanb)
{
  int idx = blockIdx.x*256 + threadIdx.x;   // 512
  if (idx >= 512) return;
  int b = idx >> 7, c = idx & 127;
  float s = 0.f;
  for (int g = 0; g < 32; g++) s += part[(b*32+g)*128 + c];
  meanb[idx] = s * (1.f/4096.f);
}

__global__ __launch_bounds__(256) void k_tproj(
    const float* __restrict__ meanb, const float* __restrict__ Wt,
    const float* __restrict__ bt, float* __restrict__ out)
{
  int idx = blockIdx.x*256 + threadIdx.x;
  if (idx >= 1200) return;
  int b = idx / 300, j = idx % 300;
  float acc = bt[j];
  #pragma unroll 4
  for (int k2 = 0; k2 < 128; k2++)
    acc += meanb[b*128 + k2] * Wt[k2*300 + j];
  out[32768 + idx] = acc;
}

// ---------------- launcher -------------------------------------------------
extern "C" void kernel_launch(void* const* d_in, const int* in_sizes, int n_in,
                              void* d_out, int out_size, void* d_ws, size_t ws_size,
                              hipStream_t stream)
{
  const float* x    = (const float*)d_in[0];
  const float* c1w  = (const float*)d_in[1];
  const float* c1b  = (const float*)d_in[2];
  const float* c2w  = (const float*)d_in[3];
  const float* c2b  = (const float*)d_in[4];
  const float* c3w  = (const float*)d_in[5];
  const float* c3b  = (const float*)d_in[6];
  const float* ln1s = (const float*)d_in[7];
  const float* ln1b = (const float*)d_in[8];
  const float* ln2s = (const float*)d_in[9];
  const float* ln2b = (const float*)d_in[10];
  const float* Wq   = (const float*)d_in[11];
  const float* bq   = (const float*)d_in[12];
  const float* Wk   = (const float*)d_in[13];
  const float* bk   = (const float*)d_in[14];
  const float* Wv   = (const float*)d_in[15];
  const float* bv   = (const float*)d_in[16];
  const float* Wo   = (const float*)d_in[17];
  const float* bo   = (const float*)d_in[18];
  const float* Er   = (const float*)d_in[19];
  const float* W1   = (const float*)d_in[20];
  const float* b1   = (const float*)d_in[21];
  const float* W2   = (const float*)d_in[22];
  const float* b2   = (const float*)d_in[23];
  const float* Wout = (const float*)d_in[24];
  const float* bout = (const float*)d_in[25];
  const float* Wt   = (const float*)d_in[26];
  const float* bt   = (const float*)d_in[27];

  char* W = (char*)d_ws;
  float* buf2   = (float*)W;                       // 41,943,040 B (conv stage)
  u16*   hid_h  = (u16*)W;                         // overlay after conv3: 16 MB
  u16*   hid_l  = (u16*)(W + 16777216);            // 16 MB
  size_t o = 41943040;
  float* hbuf = (float*)(W + o); o += 8388608;
  float* ssum = (float*)(W + o); o += 8388608;
  float* qb   = (float*)(W + o); o += 25165824;    // q,k,v contiguous
  float* kb   = qb + 2097152;
  float* vb2  = qb + 4194304;
  u16* xh  = (u16*)(W + o); o += 4194304;          // LN out / attn out (aliased)
  u16* xlo = (u16*)(W + o); o += 4194304;
  u16* wqkv_h = (u16*)(W + o); o += 884736;
  u16* wqkv_l = (u16*)(W + o); o += 884736;
  u16* wo_h   = (u16*)(W + o); o += 294912;
  u16* wo_l   = (u16*)(W + o); o += 294912;
  u16* w1t_h  = (u16*)(W + o); o += 1179648;
  u16* w1t_l  = (u16*)(W + o); o += 1179648;
  u16* w2t_h  = (u16*)(W + o); o += 1179648;
  u16* w2t_l  = (u16*)(W + o); o += 1179648;
  float* part  = (float*)(W + o); o += 65536;
  float* meanb = (float*)(W + o); o += 2048;
  float* outf  = (float*)d_out;

  // weight prep (transpose + hi/lo split), every call (graph-safe, ~µs)
  k_wprep<<<576,  256, 0, stream>>>(Wq, wqkv_h,          wqkv_l,          128, 128, 9, 49152);
  k_wprep<<<576,  256, 0, stream>>>(Wk, wqkv_h + 16384,  wqkv_l + 16384,  128, 128, 9, 49152);
  k_wprep<<<576,  256, 0, stream>>>(Wv, wqkv_h + 32768,  wqkv_l + 32768,  128, 128, 9, 49152);
  k_wprep<<<576,  256, 0, stream>>>(Wo, wo_h,  wo_l,  128, 128, 9, 16384);
  k_wprep<<<2304, 256, 0, stream>>>(W1, w1t_h, w1t_l, 128, 512, 9, 65536);
  k_wprep<<<2304, 256, 0, stream>>>(W2, w2t_h, w2t_l, 512, 128, 9, 65536);

  k_conv12<<<dim3(T_/4, B_), 256, 0, stream>>>(x, c1w, c1b, c2w, c2b, buf2);
  k_conv3<<<dim3(B_*256), 256, 0, stream>>>(buf2, c3w, c3b, hbuf);

  for (int l = 0; l < 9; l++) {
    k_ln<<<4096, 256, 0, stream>>>(hbuf, ln1s + l*128, ln1b + l*128, xh, xlo);
    k_gqkv<<<dim3(256, 2, 3), 256, 0, stream>>>(
        xh, xlo, wqkv_h + l*49152, wqkv_l + l*49152,
        bq + l*128, bk + l*128, bv + l*128, qb);
    k_attn<<<4096, 256, 0, stream>>>(qb, kb, vb2, Er + l*640, xh, xlo, 1 << l);
    k_gmm<128,3><<<dim3(256, 2), 256, 0, stream>>>(
        xh, xlo, wo_h + l*16384, wo_l + l*16384, bo + l*128, 128,
        hbuf, ssum, (l == 0) ? 1 : 0, nullptr, nullptr);
    k_ln<<<4096, 256, 0, stream>>>(hbuf, ln2s + l*128, ln2b + l*128, xh, xlo);
    k_gmm<128,1><<<dim3(256, 8), 256, 0, stream>>>(
        xh, xlo, w1t_h + l*65536, w1t_l + l*65536, b1 + l*512, 512,
        nullptr, nullptr, 0, hid_h, hid_l);
    k_gmm<512,2><<<dim3(256, 2), 256, 0, stream>>>(
        hid_h, hid_l, w2t_h + l*65536, w2t_l + l*65536, b2 + l*128, 128,
        hbuf, nullptr, 0, nullptr, nullptr);
  }

  k_out<<<128, 256, 0, stream>>>(hbuf, Wout, bout, outf);
  k_red1<<<128, 256, 0, stream>>>(ssum, part);
  k_red2<<<2, 256, 0, stream>>>(part, meanb);
  k_tproj<<<5, 256, 0, stream>>>(meanb, Wt, bt, outf);
}

// Round 3
// 1587.165 us; speedup vs baseline: 1.4362x; 1.3117x over previous
//
#include <hip/hip_runtime.h>

#define T_ 4096
#define B_ 4

typedef unsigned short u16;
typedef __bf16 bf16x8 __attribute__((ext_vector_type(8)));
typedef float f32x4 __attribute__((ext_vector_type(4)));

__device__ inline void splitbf(float v, u16& h, u16& l) {
  __bf16 hb = (__bf16)v;
  float r = v - (float)hb;
  __bf16 lb = (__bf16)r;
  h = __builtin_bit_cast(u16, hb);
  l = __builtin_bit_cast(u16, lb);
}

#define MFMA(a,b,c) __builtin_amdgcn_mfma_f32_16x16x32_bf16((a),(b),(c),0,0,0)

// ---------------- conv1 (5x3, pad_h=2) + pool3(W) + relu -------------------
// x per-b (T,128) -> tmp1 hi/lo planes [t][42][32]
__global__ __launch_bounds__(256) void k_conv1(
    const float* __restrict__ x, const float* __restrict__ w1,
    const float* __restrict__ b1, u16* __restrict__ th, u16* __restrict__ tl)
{
  __shared__ float sx[12][130];
  __shared__ float w1s[480];
  __shared__ float b1s[32];
  const int tid = threadIdx.x;
  const int t0 = blockIdx.x * 8;
  for (int i = tid; i < 1536; i += 256) {
    int r = i >> 7, c = i & 127;
    int t = t0 - 2 + r;
    sx[r][c] = (t >= 0 && t < T_) ? x[t*128 + c] : 0.f;
  }
  for (int i = tid; i < 480; i += 256) w1s[i] = w1[i];
  if (tid < 32) b1s[tid] = b1[tid];
  __syncthreads();
  for (int i = tid; i < 10752; i += 256) {
    int c1 = i & 31;
    int wp = (i >> 5) % 42;
    int tt = i / 1344;
    float m = -1e30f;
    #pragma unroll
    for (int j = 0; j < 3; j++) {
      float acc = 0.f;
      int wb = wp*3 + j;
      #pragma unroll
      for (int kh = 0; kh < 5; kh++)
        #pragma unroll
        for (int kw = 0; kw < 3; kw++)
          acc += sx[tt+kh][wb+kw] * w1s[c1*15 + kh*3 + kw];
      m = fmaxf(m, acc);
    }
    float v = fmaxf(m + b1s[c1], 0.f);
    u16 hh, ll; splitbf(v, hh, ll);
    int o = (t0 + tt)*1344 + wp*32 + c1;
    th[o] = hh; tl[o] = ll;
  }
}

// ---------------- conv2 (1x12) + pool3 + relu via MFMA ---------------------
// tmp1 hi/lo [t][42][32] -> c2out hi/lo [t][10][64].  8 t per block.
__global__ __launch_bounds__(256) void k_conv2m(
    const u16* __restrict__ th, const u16* __restrict__ tl,
    const u16* __restrict__ wh, const u16* __restrict__ wl,
    const float* __restrict__ b2,
    u16* __restrict__ oh, u16* __restrict__ ol)
{
  __shared__ u16 sh[8*43*40];     // cell stride 40 u16: 16B-aligned, bank+20
  __shared__ u16 sl[8*43*40];
  __shared__ float dmp[4][15][66];
  const int tid = threadIdx.x;
  const int t0 = blockIdx.x * 8;
  for (int i = tid; i < 1344; i += 256) {
    int cg = i & 3;
    int w = (i >> 2) % 42;
    int tt = i / 168;
    int so = (t0 + tt)*1344 + w*32 + cg*8;
    int dd = (tt*43 + w)*40 + cg*8;
    *(ulonglong2*)&sh[dd] = *(const ulonglong2*)&th[so];
    *(ulonglong2*)&sl[dd] = *(const ulonglong2*)&tl[so];
  }
  for (int i = tid; i < 320; i += 256) {   // zero pad cell w=42
    int tt = i / 40, c = i - tt*40;
    sh[(tt*43 + 42)*40 + c] = 0;
    sl[(tt*43 + 42)*40 + c] = 0;
  }
  __syncthreads();
  const int lane = tid & 63;
  const int wid = tid >> 6;
  const int lr = lane & 15;
  const int lk8 = (lane >> 4) * 8;
  f32x4 acc[2][2][4] = {};
  #pragma unroll 3
  for (int kw = 0; kw < 12; kw++) {
    bf16x8 bh[4], bl[4];
    #pragma unroll
    for (int nf = 0; nf < 4; nf++) {
      int go = (nf*16 + lr)*384 + kw*32 + lk8;
      bh[nf] = *(const bf16x8*)(wh + go);
      bl[nf] = *(const bf16x8*)(wl + go);
    }
    #pragma unroll
    for (int tp = 0; tp < 2; tp++) {
      int tloc = wid*2 + tp;
      #pragma unroll
      for (int mf = 0; mf < 2; mf++) {
        int lofs = (tloc*43 + mf*16 + lr + kw)*40 + lk8;
        bf16x8 ah = *(const bf16x8*)&sh[lofs];
        bf16x8 al = *(const bf16x8*)&sl[lofs];
        #pragma unroll
        for (int nf = 0; nf < 4; nf++) {
          acc[tp][mf][nf] = MFMA(ah, bl[nf], acc[tp][mf][nf]);
          acc[tp][mf][nf] = MFMA(al, bh[nf], acc[tp][mf][nf]);
          acc[tp][mf][nf] = MFMA(ah, bh[nf], acc[tp][mf][nf]);
        }
      }
    }
  }
  // epilogue: wave-private dump -> pool3 over rows -> +bias, relu, split
  const int lg = lane >> 4;
  for (int tp = 0; tp < 2; tp++) {
    int t = t0 + wid*2 + tp;
    for (int half = 0; half < 2; half++) {
      #pragma unroll
      for (int mf = 0; mf < 2; mf++)
        #pragma unroll
        for (int r = 0; r < 4; r++) {
          int grow = mf*16 + lg*4 + r;
          int lrow = grow - half*15;
          if (lrow >= 0 && lrow < 15) {
            #pragma unroll
            for (int nf = 0; nf < 4; nf++)
              dmp[wid][lrow][nf*16 + lr] = acc[tp][mf][nf][r];
          }
        }
      asm volatile("s_waitcnt lgkmcnt(0)" ::: "memory");
      #pragma unroll
      for (int it = 0; it < 5; it++) {
        float v = fmaxf(fmaxf(dmp[wid][it*3][lane], dmp[wid][it*3+1][lane]),
                        dmp[wid][it*3+2][lane]);
        v = fmaxf(v + b2[lane], 0.f);
        u16 hh, ll; splitbf(v, hh, ll);
        int o = (t*10 + half*5 + it)*64 + lane;
        oh[o] = hh; ol[o] = ll;
      }
      asm volatile("s_waitcnt lgkmcnt(0)" ::: "memory");
    }
  }
}

// ---------------- conv3 (3x6, pad_h=1) + pool3 + relu via MFMA -------------
// c2out hi/lo [t][10][64] -> h fp32 [t][128].  16 t per block, rows=(t,wo).
__global__ __launch_bounds__(256) void k_conv3m(
    const u16* __restrict__ ih, const u16* __restrict__ il,
    const u16* __restrict__ wh, const u16* __restrict__ wl,
    const float* __restrict__ b3, float* __restrict__ hout)
{
  __shared__ u16 sh[18*720];     // cell stride 72 u16, t stride 720
  __shared__ u16 sl[18*720];
  __shared__ float dmp[48][132];
  const int tid = threadIdx.x;
  const int t0 = blockIdx.x * 16;
  for (int i = tid; i < 1440; i += 256) {
    int cg = i & 7;
    int w = (i >> 3) % 10;
    int tt = i / 80;
    int t = t0 - 1 + tt;
    int dd = tt*720 + w*72 + cg*8;
    if (t >= 0 && t < T_) {
      int so = (t*10 + w)*64 + cg*8;
      *(ulonglong2*)&sh[dd] = *(const ulonglong2*)&ih[so];
      *(ulonglong2*)&sl[dd] = *(const ulonglong2*)&il[so];
    } else {
      ulonglong2 z; z.x = 0; z.y = 0;
      *(ulonglong2*)&sh[dd] = z;
      *(ulonglong2*)&sl[dd] = z;
    }
  }
  __syncthreads();
  const int lane = tid & 63;
  const int wid = tid >> 6;
  const int lr = lane & 15;
  const int lk8 = (lane >> 4) * 8;
  int tlm[3], wom[3];
  #pragma unroll
  for (int mf = 0; mf < 3; mf++) {
    int r = mf*16 + lr;
    tlm[mf] = r / 3;
    wom[mf] = r - tlm[mf]*3;
  }
  f32x4 acc[3][2] = {};
  #pragma unroll 2
  for (int kh = 0; kh < 3; kh++) {
    #pragma unroll
    for (int kw = 0; kw < 6; kw++) {
      #pragma unroll
      for (int chh = 0; chh < 2; chh++) {
        int khkw = kh*6 + kw;
        int ch = chh*32;
        bf16x8 bh[2], bl[2];
        #pragma unroll
        for (int nfl = 0; nfl < 2; nfl++) {
          int go = ((wid*2 + nfl)*16 + lr)*1152 + khkw*64 + ch + lk8;
          bh[nfl] = *(const bf16x8*)(wh + go);
          bl[nfl] = *(const bf16x8*)(wl + go);
        }
        #pragma unroll
        for (int mf = 0; mf < 3; mf++) {
          int lofs = (tlm[mf] + kh)*720 + (wom[mf] + kw)*72 + ch + lk8;
          bf16x8 ah = *(const bf16x8*)&sh[lofs];
          bf16x8 al = *(const bf16x8*)&sl[lofs];
          #pragma unroll
          for (int nfl = 0; nfl < 2; nfl++) {
            acc[mf][nfl] = MFMA(ah, bl[nfl], acc[mf][nfl]);
            acc[mf][nfl] = MFMA(al, bh[nfl], acc[mf][nfl]);
            acc[mf][nfl] = MFMA(ah, bh[nfl], acc[mf][nfl]);
          }
        }
      }
    }
  }
  const int lg = lane >> 4;
  #pragma unroll
  for (int mf = 0; mf < 3; mf++)
    #pragma unroll
    for (int r = 0; r < 4; r++) {
      int row = mf*16 + lg*4 + r;
      #pragma unroll
      for (int nfl = 0; nfl < 2; nfl++)
        dmp[row][wid*32 + nfl*16 + lr] = acc[mf][nfl][r];
    }
  __syncthreads();
  for (int i = tid; i < 2048; i += 256) {
    int c3 = i & 127;
    int tt = i >> 7;
    float v = fmaxf(fmaxf(dmp[tt*3][c3], dmp[tt*3+1][c3]), dmp[tt*3+2][c3]);
    v = fmaxf(v + b3[c3], 0.f);
    hout[(t0 + tt)*128 + c3] = v;
  }
}

// ---------------- LayerNorm (128) -> packed hi/lo bf16 planes --------------
__device__ inline float wave_sum(float v) {
  #pragma unroll
  for (int m = 1; m < 64; m <<= 1) v += __shfl_xor(v, m, 64);
  return v;
}

__global__ __launch_bounds__(256) void k_ln(
    const float* __restrict__ in, const float* __restrict__ sc,
    const float* __restrict__ bi, u16* __restrict__ oh, u16* __restrict__ ol)
{
  const int lane = threadIdx.x & 63;
  const int row = blockIdx.x*4 + (threadIdx.x >> 6);
  float a = in[row*128 + lane];
  float c = in[row*128 + 64 + lane];
  float mean = wave_sum(a + c) * (1.f/128.f);
  float d0 = a - mean, d1 = c - mean;
  float var = wave_sum(d0*d0 + d1*d1) * (1.f/128.f);
  float rs = rsqrtf(var + 1e-5f);
  float v0 = d0*rs*sc[lane]    + bi[lane];
  float v1 = d1*rs*sc[64+lane] + bi[64+lane];
  u16 h0, l0, h1, l1;
  splitbf(v0, h0, l0); splitbf(v1, h1, l1);
  oh[row*128 + lane] = h0;      ol[row*128 + lane] = l0;
  oh[row*128 + 64 + lane] = h1; ol[row*128 + 64 + lane] = l1;
}

// ---------------- weight prep kernels --------------------------------------
__global__ __launch_bounds__(256) void k_wprep(
    const float* __restrict__ src, u16* __restrict__ dh, u16* __restrict__ dl,
    int K, int N, int nm, int dstMatStride)
{
  int idx = blockIdx.x*256 + threadIdx.x;
  int total = nm*K*N;
  if (idx >= total) return;
  int mat = idx / (K*N);
  int rem = idx - mat*(K*N);
  int n = rem / K;
  int k = rem - n*K;
  float v = src[(size_t)(mat*K + k)*N + n];
  u16 h, l; splitbf(v, h, l);
  size_t o = (size_t)mat*dstMatStride + (size_t)n*K + k;
  dh[o] = h; dl[o] = l;
}

__global__ __launch_bounds__(256) void k_wprep_c2(
    const float* __restrict__ w2, u16* __restrict__ dh, u16* __restrict__ dl)
{
  int idx = blockIdx.x*256 + threadIdx.x;
  if (idx >= 24576) return;
  int c2 = idx / 384;
  int rem = idx - c2*384;
  int kw = rem >> 5;
  int c1 = rem & 31;
  float v = w2[c2*384 + c1*12 + kw];
  u16 h, l; splitbf(v, h, l);
  dh[idx] = h; dl[idx] = l;
}

__global__ __launch_bounds__(256) void k_wprep_c3(
    const float* __restrict__ w3, u16* __restrict__ dh, u16* __restrict__ dl)
{
  int idx = blockIdx.x*256 + threadIdx.x;
  if (idx >= 147456) return;
  int c3 = idx / 1152;
  int rem = idx - c3*1152;
  int khkw = rem >> 6;
  int c2 = rem & 63;
  float v = w3[c3*1152 + c2*18 + khkw];
  u16 h, l; splitbf(v, h, l);
  dh[idx] = h; dl[idx] = l;
}

// ---------------- split-bf16 MFMA GEMM core --------------------------------
template<int KDIM>
__device__ inline void gemm_core(
    const u16* __restrict__ Ah, const u16* __restrict__ Al,
    const u16* __restrict__ Wh, const u16* __restrict__ Wl,
    int m0, int n0, int lane, f32x4 acc[2][2])
{
  const int lr = lane & 15, lk = (lane >> 4) * 8;
  const u16* a_h = Ah + (size_t)(m0 + lr)*KDIM + lk;
  const u16* a_l = Al + (size_t)(m0 + lr)*KDIM + lk;
  const u16* b_h = Wh + (size_t)(n0 + lr)*KDIM + lk;
  const u16* b_l = Wl + (size_t)(n0 + lr)*KDIM + lk;
  #pragma unroll
  for (int ks = 0; ks < KDIM/32; ks++) {
    bf16x8 ah0 = *(const bf16x8*)(a_h + ks*32);
    bf16x8 ah1 = *(const bf16x8*)(a_h + 16*KDIM + ks*32);
    bf16x8 al0 = *(const bf16x8*)(a_l + ks*32);
    bf16x8 al1 = *(const bf16x8*)(a_l + 16*KDIM + ks*32);
    bf16x8 bh0 = *(const bf16x8*)(b_h + ks*32);
    bf16x8 bh1 = *(const bf16x8*)(b_h + 16*KDIM + ks*32);
    bf16x8 bl0 = *(const bf16x8*)(b_l + ks*32);
    bf16x8 bl1 = *(const bf16x8*)(b_l + 16*KDIM + ks*32);
    acc[0][0] = MFMA(ah0, bl0, acc[0][0]);
    acc[0][0] = MFMA(al0, bh0, acc[0][0]);
    acc[0][0] = MFMA(ah0, bh0, acc[0][0]);
    acc[0][1] = MFMA(ah0, bl1, acc[0][1]);
    acc[0][1] = MFMA(al0, bh1, acc[0][1]);
    acc[0][1] = MFMA(ah0, bh1, acc[0][1]);
    acc[1][0] = MFMA(ah1, bl0, acc[1][0]);
    acc[1][0] = MFMA(al1, bh0, acc[1][0]);
    acc[1][0] = MFMA(ah1, bh0, acc[1][0]);
    acc[1][1] = MFMA(ah1, bl1, acc[1][1]);
    acc[1][1] = MFMA(al1, bh1, acc[1][1]);
    acc[1][1] = MFMA(ah1, bh1, acc[1][1]);
  }
}

template<int EPI>
__device__ inline void gmm_epi(
    f32x4 acc[2][2], const float* __restrict__ bias, int N,
    float* __restrict__ C, float* __restrict__ C2, int skip_init,
    u16* __restrict__ Oh, u16* __restrict__ Ol, int m0, int n0, int lane)
{
  const int lr = lane & 15, lg = lane >> 4;
  #pragma unroll
  for (int mf = 0; mf < 2; mf++)
    #pragma unroll
    for (int nf = 0; nf < 2; nf++) {
      int col = n0 + nf*16 + lr;
      float bb = bias[col];
      #pragma unroll
      for (int r = 0; r < 4; r++) {
        int row = m0 + mf*16 + lg*4 + r;
        float val = acc[mf][nf][r] + bb;
        size_t o = (size_t)row*N + col;
        if (EPI == 0) {
          C[o] = val;
        } else if (EPI == 1) {
          float v = fmaxf(val, 0.f);
          u16 h, l; splitbf(v, h, l);
          Oh[o] = h; Ol[o] = l;
        } else if (EPI == 2) {
          C[o] += val;
        } else {
          C[o] += val;
          if (skip_init) C2[o] = val; else C2[o] += val;
        }
      }
    }
}

template<int KDIM, int EPI>
__global__ __launch_bounds__(256) void k_gmm(
    const u16* __restrict__ Ah, const u16* __restrict__ Al,
    const u16* __restrict__ Wh, const u16* __restrict__ Wl,
    const float* __restrict__ bias, int N,
    float* __restrict__ C, float* __restrict__ C2, int skip_init,
    u16* __restrict__ Oh, u16* __restrict__ Ol)
{
  const int lane = threadIdx.x & 63;
  const int wid = threadIdx.x >> 6;
  const int m0 = blockIdx.x*64 + (wid >> 1)*32;
  const int n0 = blockIdx.y*64 + (wid & 1)*32;
  f32x4 acc[2][2] = {};
  gemm_core<KDIM>(Ah, Al, Wh, Wl, m0, n0, lane, acc);
  gmm_epi<EPI>(acc, bias, N, C, C2, skip_init, Oh, Ol, m0, n0, lane);
}

__global__ __launch_bounds__(256) void k_gqkv(
    const u16* __restrict__ Ah, const u16* __restrict__ Al,
    const u16* __restrict__ Wh, const u16* __restrict__ Wl,
    const float* __restrict__ bq, const float* __restrict__ bk,
    const float* __restrict__ bv, float* __restrict__ outbase)
{
  const int z = blockIdx.z;
  const u16* wh = Wh + z*16384;
  const u16* wl = Wl + z*16384;
  const float* bias = (z == 0) ? bq : (z == 1) ? bk : bv;
  float* C = outbase + (size_t)z*2097152;
  const int lane = threadIdx.x & 63;
  const int wid = threadIdx.x >> 6;
  const int m0 = blockIdx.x*64 + (wid >> 1)*32;
  const int n0 = blockIdx.y*64 + (wid & 1)*32;
  f32x4 acc[2][2] = {};
  gemm_core<128>(Ah, Al, wh, wl, m0, n0, lane, acc);
  gmm_epi<0>(acc, bias, 128, C, nullptr, 0, nullptr, nullptr, m0, n0, lane);
}

// ---------------- dilated local attention -> packed hi/lo ------------------
__global__ __launch_bounds__(256) void k_attn(
    const float* __restrict__ q, const float* __restrict__ kk,
    const float* __restrict__ vv, const float* __restrict__ Er,
    u16* __restrict__ oh, u16* __restrict__ ol, int dil)
{
  const int w = threadIdx.x >> 6, lane = threadIdx.x & 63;
  const int bt = blockIdx.x * 4 + w;
  const int b = bt >> 12;
  const int t = bt & 4095;
  #pragma unroll
  for (int h = 0; h < 2; h++) {
    float qd = q[bt*128 + h*64 + lane];
    float s[5];
    int tpc_arr[5];
    #pragma unroll
    for (int a = 0; a < 5; a++) {
      int tp = t + (a-2)*dil;
      bool valid = (tp >= 0 && tp < T_);
      int tpc = tp < 0 ? 0 : (tp > T_-1 ? T_-1 : tp);
      tpc_arr[a] = tpc;
      float kd = kk[(b*T_ + tpc)*128 + h*64 + lane];
      float er = Er[(h*5 + a)*64 + lane];
      float p = qd * (kd + er);
      p = wave_sum(p);
      s[a] = valid ? p * 0.125f : -1e30f;
    }
    float mx = s[0];
    #pragma unroll
    for (int a = 1; a < 5; a++) mx = fmaxf(mx, s[a]);
    float p[5], psum = 0.f;
    #pragma unroll
    for (int a = 0; a < 5; a++) { p[a] = __expf(s[a]-mx); psum += p[a]; }
    float inv = 1.f/psum;
    float o = 0.f;
    #pragma unroll
    for (int a = 0; a < 5; a++)
      o += p[a] * vv[(b*T_ + tpc_arr[a])*128 + h*64 + lane];
    float vo = o * inv;
    u16 hh, ll;
    splitbf(vo, hh, ll);
    oh[bt*128 + h*64 + lane] = hh;
    ol[bt*128 + h*64 + lane] = ll;
  }
}

// ---------------- tail kernels --------------------------------------------
__global__ __launch_bounds__(256) void k_out(
    const float* __restrict__ h, const float* __restrict__ Wout,
    const float* __restrict__ bout, float* __restrict__ out)
{
  int idx = blockIdx.x*256 + threadIdx.x;
  int bt = idx >> 1, j = idx & 1;
  float acc = bout[j];
  const float* hp = &h[bt*128];
  #pragma unroll 4
  for (int k2 = 0; k2 < 128; k2++)
    acc += fmaxf(hp[k2], 0.f) * Wout[k2*2 + j];
  out[idx] = acc;
}

__global__ __launch_bounds__(256) void k_red1(
    const float* __restrict__ ss, float* __restrict__ part)
{
  __shared__ float red[256];
  int b = blockIdx.x >> 5, g = blockIdx.x & 31;
  int c = threadIdx.x & 127, hf = threadIdx.x >> 7;
  float acc = 0.f;
  for (int i2 = 0; i2 < 64; i2++) {
    int t = g*128 + i2*2 + hf;
    acc += fmaxf(ss[(b*T_ + t)*128 + c], 0.f);
  }
  red[threadIdx.x] = acc;
  __syncthreads();
  if (threadIdx.x < 128)
    part[(b*32+g)*128 + threadIdx.x] = red[threadIdx.x] + red[threadIdx.x+128];
}

__global__ __launch_bounds__(256) void k_red2(
    const float* __restrict__ part, float* __restrict__ meanb)
{
  int idx = blockIdx.x*256 + threadIdx.x;
  if (idx >= 512) return;
  int b = idx >> 7, c = idx & 127;
  float s = 0.f;
  for (int g = 0; g < 32; g++) s += part[(b*32+g)*128 + c];
  meanb[idx] = s * (1.f/4096.f);
}

__global__ __launch_bounds__(256) void k_tproj(
    const float* __restrict__ meanb, const float* __restrict__ Wt,
    const float* __restrict__ bt, float* __restrict__ out)
{
  int idx = blockIdx.x*256 + threadIdx.x;
  if (idx >= 1200) return;
  int b = idx / 300, j = idx % 300;
  float acc = bt[j];
  #pragma unroll 4
  for (int k2 = 0; k2 < 128; k2++)
    acc += meanb[b*128 + k2] * Wt[k2*300 + j];
  out[32768 + idx] = acc;
}

// ---------------- launcher -------------------------------------------------
extern "C" void kernel_launch(void* const* d_in, const int* in_sizes, int n_in,
                              void* d_out, int out_size, void* d_ws, size_t ws_size,
                              hipStream_t stream)
{
  const float* x    = (const float*)d_in[0];
  const float* c1w  = (const float*)d_in[1];
  const float* c1b  = (const float*)d_in[2];
  const float* c2w  = (const float*)d_in[3];
  const float* c2b  = (const float*)d_in[4];
  const float* c3w  = (const float*)d_in[5];
  const float* c3b  = (const float*)d_in[6];
  const float* ln1s = (const float*)d_in[7];
  const float* ln1b = (const float*)d_in[8];
  const float* ln2s = (const float*)d_in[9];
  const float* ln2b = (const float*)d_in[10];
  const float* Wq   = (const float*)d_in[11];
  const float* bq   = (const float*)d_in[12];
  const float* Wk   = (const float*)d_in[13];
  const float* bk   = (const float*)d_in[14];
  const float* Wv   = (const float*)d_in[15];
  const float* bv   = (const float*)d_in[16];
  const float* Wo   = (const float*)d_in[17];
  const float* bo   = (const float*)d_in[18];
  const float* Er   = (const float*)d_in[19];
  const float* W1   = (const float*)d_in[20];
  const float* b1   = (const float*)d_in[21];
  const float* W2   = (const float*)d_in[22];
  const float* b2   = (const float*)d_in[23];
  const float* Wout = (const float*)d_in[24];
  const float* bout = (const float*)d_in[25];
  const float* Wt   = (const float*)d_in[26];
  const float* bt   = (const float*)d_in[27];

  char* W = (char*)d_ws;
  // region A (0 .. 33.5 MB): tmp1 (convs, per-b) then hid (FFN)
  u16* tmp1_h = (u16*)W;
  u16* tmp1_l = (u16*)(W + 11010048);
  u16* hid_h  = (u16*)W;
  u16* hid_l  = (u16*)(W + 16777216);
  // region B (33.5 .. 67 MB): c2out (convs, per-b) then qkv + x planes
  char* RB = W + 33554432;
  u16* c2o_h = (u16*)RB;
  u16* c2o_l = (u16*)(RB + 5242880);
  float* qb  = (float*)RB;
  float* kb  = qb + 2097152;
  float* vb2 = qb + 4194304;
  u16* xh    = (u16*)(RB + 25165824);
  u16* xlo   = (u16*)(RB + 29360128);
  // region C (67 MB ..): persistent
  char* RC = W + 67108864;
  float* hbuf = (float*)RC;
  float* ssum = (float*)(RC + 8388608);
  u16* wqkv_h = (u16*)(RC + 16777216);
  u16* wqkv_l = wqkv_h + 442368;
  u16* wo_h   = wqkv_l + 442368;
  u16* wo_l   = wo_h + 147456;
  u16* w1t_h  = wo_l + 147456;
  u16* w1t_l  = w1t_h + 589824;
  u16* w2t_h  = w1t_l + 589824;
  u16* w2t_l  = w2t_h + 589824;
  u16* wc2_h  = w2t_l + 589824;
  u16* wc2_l  = wc2_h + 24576;
  u16* wc3_h  = wc2_l + 24576;
  u16* wc3_l  = wc3_h + 147456;
  float* part  = (float*)(wc3_l + 147456);
  float* meanb = part + 16384;
  float* outf  = (float*)d_out;

  // weight prep
  k_wprep<<<576,  256, 0, stream>>>(Wq, wqkv_h,          wqkv_l,          128, 128, 9, 49152);
  k_wprep<<<576,  256, 0, stream>>>(Wk, wqkv_h + 16384,  wqkv_l + 16384,  128, 128, 9, 49152);
  k_wprep<<<576,  256, 0, stream>>>(Wv, wqkv_h + 32768,  wqkv_l + 32768,  128, 128, 9, 49152);
  k_wprep<<<576,  256, 0, stream>>>(Wo, wo_h,  wo_l,  128, 128, 9, 16384);
  k_wprep<<<2304, 256, 0, stream>>>(W1, w1t_h, w1t_l, 128, 512, 9, 65536);
  k_wprep<<<2304, 256, 0, stream>>>(W2, w2t_h, w2t_l, 512, 128, 9, 65536);
  k_wprep_c2<<<96,  256, 0, stream>>>(c2w, wc2_h, wc2_l);
  k_wprep_c3<<<576, 256, 0, stream>>>(c3w, wc3_h, wc3_l);

  // conv frontend, chunked per batch element
  for (int b = 0; b < B_; b++) {
    k_conv1<<<512, 256, 0, stream>>>(x + (size_t)b*T_*128, c1w, c1b, tmp1_h, tmp1_l);
    k_conv2m<<<512, 256, 0, stream>>>(tmp1_h, tmp1_l, wc2_h, wc2_l, c2b, c2o_h, c2o_l);
    k_conv3m<<<256, 256, 0, stream>>>(c2o_h, c2o_l, wc3_h, wc3_l, c3b,
                                      hbuf + (size_t)b*T_*128);
  }

  for (int l = 0; l < 9; l++) {
    k_ln<<<4096, 256, 0, stream>>>(hbuf, ln1s + l*128, ln1b + l*128, xh, xlo);
    k_gqkv<<<dim3(256, 2, 3), 256, 0, stream>>>(
        xh, xlo, wqkv_h + l*49152, wqkv_l + l*49152,
        bq + l*128, bk + l*128, bv + l*128, qb);
    k_attn<<<4096, 256, 0, stream>>>(qb, kb, vb2, Er + l*640, xh, xlo, 1 << l);
    k_gmm<128,3><<<dim3(256, 2), 256, 0, stream>>>(
        xh, xlo, wo_h + l*16384, wo_l + l*16384, bo + l*128, 128,
        hbuf, ssum, (l == 0) ? 1 : 0, nullptr, nullptr);
    k_ln<<<4096, 256, 0, stream>>>(hbuf, ln2s + l*128, ln2b + l*128, xh, xlo);
    k_gmm<128,1><<<dim3(256, 8), 256, 0, stream>>>(
        xh, xlo, w1t_h + l*65536, w1t_l + l*65536, b1 + l*512, 512,
        nullptr, nullptr, 0, hid_h, hid_l);
    k_gmm<512,2><<<dim3(256, 2), 256, 0, stream>>>(
        hid_h, hid_l, w2t_h + l*65536, w2t_l + l*65536, b2 + l*128, 128,
        hbuf, nullptr, 0, nullptr, nullptr);
  }

  k_out<<<128, 256, 0, stream>>>(hbuf, Wout, bout, outf);
  k_red1<<<128, 256, 0, stream>>>(ssum, part);
  k_red2<<<2, 256, 0, stream>>>(part, meanb);
  k_tproj<<<5, 256, 0, stream>>>(meanb, Wt, bt, outf);
}

// Round 4
// 1520.363 us; speedup vs baseline: 1.4993x; 1.0439x over previous
//
#include <hip/hip_runtime.h>

#define T_ 4096
#define B_ 4

typedef unsigned short u16;
typedef __bf16 bf16x8 __attribute__((ext_vector_type(8)));
typedef float f32x4 __attribute__((ext_vector_type(4)));

__device__ inline void splitbf(float v, u16& h, u16& l) {
  __bf16 hb = (__bf16)v;
  float r = v - (float)hb;
  __bf16 lb = (__bf16)r;
  h = __builtin_bit_cast(u16, hb);
  l = __builtin_bit_cast(u16, lb);
}

#define MFMA(a,b,c) __builtin_amdgcn_mfma_f32_16x16x32_bf16((a),(b),(c),0,0,0)

// ---------------- conv1 (5x3, pad_h=2) + pool3(W) + relu -------------------
__global__ __launch_bounds__(256) void k_conv1(
    const float* __restrict__ x, const float* __restrict__ w1,
    const float* __restrict__ b1, u16* __restrict__ th, u16* __restrict__ tl)
{
  __shared__ float sx[12][130];
  __shared__ float w1s[480];
  __shared__ float b1s[32];
  const int tid = threadIdx.x;
  const int t0 = blockIdx.x * 8;
  for (int i = tid; i < 1536; i += 256) {
    int r = i >> 7, c = i & 127;
    int t = t0 - 2 + r;
    sx[r][c] = (t >= 0 && t < T_) ? x[t*128 + c] : 0.f;
  }
  for (int i = tid; i < 480; i += 256) w1s[i] = w1[i];
  if (tid < 32) b1s[tid] = b1[tid];
  __syncthreads();
  for (int i = tid; i < 10752; i += 256) {
    int c1 = i & 31;
    int wp = (i >> 5) % 42;
    int tt = i / 1344;
    float m = -1e30f;
    #pragma unroll
    for (int j = 0; j < 3; j++) {
      float acc = 0.f;
      int wb = wp*3 + j;
      #pragma unroll
      for (int kh = 0; kh < 5; kh++)
        #pragma unroll
        for (int kw = 0; kw < 3; kw++)
          acc += sx[tt+kh][wb+kw] * w1s[c1*15 + kh*3 + kw];
      m = fmaxf(m, acc);
    }
    float v = fmaxf(m + b1s[c1], 0.f);
    u16 hh, ll; splitbf(v, hh, ll);
    int o = (t0 + tt)*1344 + wp*32 + c1;
    th[o] = hh; tl[o] = ll;
  }
}

// ---------------- conv2 (1x12) + pool3 + relu via MFMA ---------------------
__global__ __launch_bounds__(256) void k_conv2m(
    const u16* __restrict__ th, const u16* __restrict__ tl,
    const u16* __restrict__ wh, const u16* __restrict__ wl,
    const float* __restrict__ b2,
    u16* __restrict__ oh, u16* __restrict__ ol)
{
  __shared__ u16 sh[8*43*40];
  __shared__ u16 sl[8*43*40];
  __shared__ float dmp[4][15][66];
  const int tid = threadIdx.x;
  const int t0 = blockIdx.x * 8;
  for (int i = tid; i < 1344; i += 256) {
    int cg = i & 3;
    int w = (i >> 2) % 42;
    int tt = i / 168;
    int so = (t0 + tt)*1344 + w*32 + cg*8;
    int dd = (tt*43 + w)*40 + cg*8;
    *(ulonglong2*)&sh[dd] = *(const ulonglong2*)&th[so];
    *(ulonglong2*)&sl[dd] = *(const ulonglong2*)&tl[so];
  }
  for (int i = tid; i < 320; i += 256) {
    int tt = i / 40, c = i - tt*40;
    sh[(tt*43 + 42)*40 + c] = 0;
    sl[(tt*43 + 42)*40 + c] = 0;
  }
  __syncthreads();
  const int lane = tid & 63;
  const int wid = tid >> 6;
  const int lr = lane & 15;
  const int lk8 = (lane >> 4) * 8;
  f32x4 acc[2][2][4] = {};
  #pragma unroll 3
  for (int kw = 0; kw < 12; kw++) {
    bf16x8 bh[4], bl[4];
    #pragma unroll
    for (int nf = 0; nf < 4; nf++) {
      int go = (nf*16 + lr)*384 + kw*32 + lk8;
      bh[nf] = *(const bf16x8*)(wh + go);
      bl[nf] = *(const bf16x8*)(wl + go);
    }
    #pragma unroll
    for (int tp = 0; tp < 2; tp++) {
      int tloc = wid*2 + tp;
      #pragma unroll
      for (int mf = 0; mf < 2; mf++) {
        int lofs = (tloc*43 + mf*16 + lr + kw)*40 + lk8;
        bf16x8 ah = *(const bf16x8*)&sh[lofs];
        bf16x8 al = *(const bf16x8*)&sl[lofs];
        #pragma unroll
        for (int nf = 0; nf < 4; nf++) {
          acc[tp][mf][nf] = MFMA(ah, bl[nf], acc[tp][mf][nf]);
          acc[tp][mf][nf] = MFMA(al, bh[nf], acc[tp][mf][nf]);
          acc[tp][mf][nf] = MFMA(ah, bh[nf], acc[tp][mf][nf]);
        }
      }
    }
  }
  const int lg = lane >> 4;
  for (int tp = 0; tp < 2; tp++) {
    int t = t0 + wid*2 + tp;
    for (int half = 0; half < 2; half++) {
      #pragma unroll
      for (int mf = 0; mf < 2; mf++)
        #pragma unroll
        for (int r = 0; r < 4; r++) {
          int grow = mf*16 + lg*4 + r;
          int lrow = grow - half*15;
          if (lrow >= 0 && lrow < 15) {
            #pragma unroll
            for (int nf = 0; nf < 4; nf++)
              dmp[wid][lrow][nf*16 + lr] = acc[tp][mf][nf][r];
          }
        }
      asm volatile("s_waitcnt lgkmcnt(0)" ::: "memory");
      #pragma unroll
      for (int it = 0; it < 5; it++) {
        float v = fmaxf(fmaxf(dmp[wid][it*3][lane], dmp[wid][it*3+1][lane]),
                        dmp[wid][it*3+2][lane]);
        v = fmaxf(v + b2[lane], 0.f);
        u16 hh, ll; splitbf(v, hh, ll);
        int o = (t*10 + half*5 + it)*64 + lane;
        oh[o] = hh; ol[o] = ll;
      }
      asm volatile("s_waitcnt lgkmcnt(0)" ::: "memory");
    }
  }
}

// ---------------- conv3 (3x6, pad_h=1) + pool3 + relu via MFMA -------------
__global__ __launch_bounds__(256) void k_conv3m(
    const u16* __restrict__ ih, const u16* __restrict__ il,
    const u16* __restrict__ wh, const u16* __restrict__ wl,
    const float* __restrict__ b3, float* __restrict__ hout)
{
  __shared__ u16 sh[18*720];
  __shared__ u16 sl[18*720];
  __shared__ float dmp[48][132];
  const int tid = threadIdx.x;
  const int t0 = blockIdx.x * 16;
  for (int i = tid; i < 1440; i += 256) {
    int cg = i & 7;
    int w = (i >> 3) % 10;
    int tt = i / 80;
    int t = t0 - 1 + tt;
    int dd = tt*720 + w*72 + cg*8;
    if (t >= 0 && t < T_) {
      int so = (t*10 + w)*64 + cg*8;
      *(ulonglong2*)&sh[dd] = *(const ulonglong2*)&ih[so];
      *(ulonglong2*)&sl[dd] = *(const ulonglong2*)&il[so];
    } else {
      ulonglong2 z; z.x = 0; z.y = 0;
      *(ulonglong2*)&sh[dd] = z;
      *(ulonglong2*)&sl[dd] = z;
    }
  }
  __syncthreads();
  const int lane = tid & 63;
  const int wid = tid >> 6;
  const int lr = lane & 15;
  const int lk8 = (lane >> 4) * 8;
  int tlm[3], wom[3];
  #pragma unroll
  for (int mf = 0; mf < 3; mf++) {
    int r = mf*16 + lr;
    tlm[mf] = r / 3;
    wom[mf] = r - tlm[mf]*3;
  }
  f32x4 acc[3][2] = {};
  #pragma unroll 2
  for (int kh = 0; kh < 3; kh++) {
    #pragma unroll
    for (int kw = 0; kw < 6; kw++) {
      #pragma unroll
      for (int chh = 0; chh < 2; chh++) {
        int khkw = kh*6 + kw;
        int ch = chh*32;
        bf16x8 bh[2], bl[2];
        #pragma unroll
        for (int nfl = 0; nfl < 2; nfl++) {
          int go = ((wid*2 + nfl)*16 + lr)*1152 + khkw*64 + ch + lk8;
          bh[nfl] = *(const bf16x8*)(wh + go);
          bl[nfl] = *(const bf16x8*)(wl + go);
        }
        #pragma unroll
        for (int mf = 0; mf < 3; mf++) {
          int lofs = (tlm[mf] + kh)*720 + (wom[mf] + kw)*72 + ch + lk8;
          bf16x8 ah = *(const bf16x8*)&sh[lofs];
          bf16x8 al = *(const bf16x8*)&sl[lofs];
          #pragma unroll
          for (int nfl = 0; nfl < 2; nfl++) {
            acc[mf][nfl] = MFMA(ah, bl[nfl], acc[mf][nfl]);
            acc[mf][nfl] = MFMA(al, bh[nfl], acc[mf][nfl]);
            acc[mf][nfl] = MFMA(ah, bh[nfl], acc[mf][nfl]);
          }
        }
      }
    }
  }
  const int lg = lane >> 4;
  #pragma unroll
  for (int mf = 0; mf < 3; mf++)
    #pragma unroll
    for (int r = 0; r < 4; r++) {
      int row = mf*16 + lg*4 + r;
      #pragma unroll
      for (int nfl = 0; nfl < 2; nfl++)
        dmp[row][wid*32 + nfl*16 + lr] = acc[mf][nfl][r];
    }
  __syncthreads();
  for (int i = tid; i < 2048; i += 256) {
    int c3 = i & 127;
    int tt = i >> 7;
    float v = fmaxf(fmaxf(dmp[tt*3][c3], dmp[tt*3+1][c3]), dmp[tt*3+2][c3]);
    v = fmaxf(v + b3[c3], 0.f);
    hout[(t0 + tt)*128 + c3] = v;
  }
}

// ---------------- standalone LayerNorm (layer-0 LN1 only) ------------------
__device__ inline float wave_sum(float v) {
  #pragma unroll
  for (int m = 1; m < 64; m <<= 1) v += __shfl_xor(v, m, 64);
  return v;
}

__global__ __launch_bounds__(256) void k_ln(
    const float* __restrict__ in, const float* __restrict__ sc,
    const float* __restrict__ bi, u16* __restrict__ oh, u16* __restrict__ ol)
{
  const int lane = threadIdx.x & 63;
  const int row = blockIdx.x*4 + (threadIdx.x >> 6);
  float a = in[row*128 + lane];
  float c = in[row*128 + 64 + lane];
  float mean = wave_sum(a + c) * (1.f/128.f);
  float d0 = a - mean, d1 = c - mean;
  float var = wave_sum(d0*d0 + d1*d1) * (1.f/128.f);
  float rs = rsqrtf(var + 1e-5f);
  float v0 = d0*rs*sc[lane]    + bi[lane];
  float v1 = d1*rs*sc[64+lane] + bi[64+lane];
  u16 h0, l0, h1, l1;
  splitbf(v0, h0, l0); splitbf(v1, h1, l1);
  oh[row*128 + lane] = h0;      ol[row*128 + lane] = l0;
  oh[row*128 + 64 + lane] = h1; ol[row*128 + 64 + lane] = l1;
}

// ---------------- weight prep kernels --------------------------------------
__global__ __launch_bounds__(256) void k_wprep(
    const float* __restrict__ src, u16* __restrict__ dh, u16* __restrict__ dl,
    int K, int N, int nm, int dstMatStride)
{
  int idx = blockIdx.x*256 + threadIdx.x;
  int total = nm*K*N;
  if (idx >= total) return;
  int mat = idx / (K*N);
  int rem = idx - mat*(K*N);
  int n = rem / K;
  int k = rem - n*K;
  float v = src[(size_t)(mat*K + k)*N + n];
  u16 h, l; splitbf(v, h, l);
  size_t o = (size_t)mat*dstMatStride + (size_t)n*K + k;
  dh[o] = h; dl[o] = l;
}

__global__ __launch_bounds__(256) void k_wprep_c2(
    const float* __restrict__ w2, u16* __restrict__ dh, u16* __restrict__ dl)
{
  int idx = blockIdx.x*256 + threadIdx.x;
  if (idx >= 24576) return;
  int c2 = idx / 384;
  int rem = idx - c2*384;
  int kw = rem >> 5;
  int c1 = rem & 31;
  float v = w2[c2*384 + c1*12 + kw];
  u16 h, l; splitbf(v, h, l);
  dh[idx] = h; dl[idx] = l;
}

__global__ __launch_bounds__(256) void k_wprep_c3(
    const float* __restrict__ w3, u16* __restrict__ dh, u16* __restrict__ dl)
{
  int idx = blockIdx.x*256 + threadIdx.x;
  if (idx >= 147456) return;
  int c3 = idx / 1152;
  int rem = idx - c3*1152;
  int khkw = rem >> 6;
  int c2 = rem & 63;
  float v = w3[c3*1152 + c2*18 + khkw];
  u16 h, l; splitbf(v, h, l);
  dh[idx] = h; dl[idx] = l;
}

// ---------------- QKV GEMM (64x64 tiles, grid.z = q/k/v) -------------------
template<int KDIM>
__device__ inline void gemm_core(
    const u16* __restrict__ Ah, const u16* __restrict__ Al,
    const u16* __restrict__ Wh, const u16* __restrict__ Wl,
    int m0, int n0, int lane, f32x4 acc[2][2])
{
  const int lr = lane & 15, lk = (lane >> 4) * 8;
  const u16* a_h = Ah + (size_t)(m0 + lr)*KDIM + lk;
  const u16* a_l = Al + (size_t)(m0 + lr)*KDIM + lk;
  const u16* b_h = Wh + (size_t)(n0 + lr)*KDIM + lk;
  const u16* b_l = Wl + (size_t)(n0 + lr)*KDIM + lk;
  #pragma unroll
  for (int ks = 0; ks < KDIM/32; ks++) {
    bf16x8 ah0 = *(const bf16x8*)(a_h + ks*32);
    bf16x8 ah1 = *(const bf16x8*)(a_h + 16*KDIM + ks*32);
    bf16x8 al0 = *(const bf16x8*)(a_l + ks*32);
    bf16x8 al1 = *(const bf16x8*)(a_l + 16*KDIM + ks*32);
    bf16x8 bh0 = *(const bf16x8*)(b_h + ks*32);
    bf16x8 bh1 = *(const bf16x8*)(b_h + 16*KDIM + ks*32);
    bf16x8 bl0 = *(const bf16x8*)(b_l + ks*32);
    bf16x8 bl1 = *(const bf16x8*)(b_l + 16*KDIM + ks*32);
    acc[0][0] = MFMA(ah0, bl0, acc[0][0]);
    acc[0][0] = MFMA(al0, bh0, acc[0][0]);
    acc[0][0] = MFMA(ah0, bh0, acc[0][0]);
    acc[0][1] = MFMA(ah0, bl1, acc[0][1]);
    acc[0][1] = MFMA(al0, bh1, acc[0][1]);
    acc[0][1] = MFMA(ah0, bh1, acc[0][1]);
    acc[1][0] = MFMA(ah1, bl0, acc[1][0]);
    acc[1][0] = MFMA(al1, bh0, acc[1][0]);
    acc[1][0] = MFMA(ah1, bh0, acc[1][0]);
    acc[1][1] = MFMA(ah1, bl1, acc[1][1]);
    acc[1][1] = MFMA(al1, bh1, acc[1][1]);
    acc[1][1] = MFMA(ah1, bh1, acc[1][1]);
  }
}

__global__ __launch_bounds__(256) void k_gqkv(
    const u16* __restrict__ Ah, const u16* __restrict__ Al,
    const u16* __restrict__ Wh, const u16* __restrict__ Wl,
    const float* __restrict__ bq, const float* __restrict__ bk,
    const float* __restrict__ bv, float* __restrict__ outbase)
{
  const int z = blockIdx.z;
  const u16* wh = Wh + z*16384;
  const u16* wl = Wl + z*16384;
  const float* bias = (z == 0) ? bq : (z == 1) ? bk : bv;
  float* C = outbase + (size_t)z*2097152;
  const int lane = threadIdx.x & 63;
  const int wid = threadIdx.x >> 6;
  const int m0 = blockIdx.x*64 + (wid >> 1)*32;
  const int n0 = blockIdx.y*64 + (wid & 1)*32;
  f32x4 acc[2][2] = {};
  gemm_core<128>(Ah, Al, wh, wl, m0, n0, lane, acc);
  const int lr = lane & 15, lg = lane >> 4;
  #pragma unroll
  for (int mf = 0; mf < 2; mf++)
    #pragma unroll
    for (int nf = 0; nf < 2; nf++) {
      int col = n0 + nf*16 + lr;
      float bb = bias[col];
      #pragma unroll
      for (int r = 0; r < 4; r++) {
        int row = m0 + mf*16 + lg*4 + r;
        C[(size_t)row*128 + col] = acc[mf][nf][r] + bb;
      }
    }
}

// ---------------- Wo GEMM + residual + skip-acc + LN2, tile 32x128 ---------
__global__ __launch_bounds__(256) void k_wo_ln(
    const u16* __restrict__ Ah, const u16* __restrict__ Al,
    const u16* __restrict__ Wh, const u16* __restrict__ Wl,
    const float* __restrict__ bo, const float* __restrict__ sc,
    const float* __restrict__ bi,
    float* __restrict__ hbuf, float* __restrict__ ssum, int skip_init,
    u16* __restrict__ oh, u16* __restrict__ ol)
{
  __shared__ float dmp[32][132];
  const int tid = threadIdx.x, lane = tid & 63, wid = tid >> 6;
  const int m0 = blockIdx.x * 32;
  const int mq = wid >> 1, nq = wid & 1;
  const int lr = lane & 15, lg = lane >> 4, lk8 = lg * 8;
  const u16* a_h = Ah + (size_t)(m0 + mq*16 + lr)*128 + lk8;
  const u16* a_l = Al + (size_t)(m0 + mq*16 + lr)*128 + lk8;
  f32x4 acc[4] = {};
  #pragma unroll
  for (int ks = 0; ks < 4; ks++) {
    bf16x8 ah = *(const bf16x8*)(a_h + ks*32);
    bf16x8 al = *(const bf16x8*)(a_l + ks*32);
    #pragma unroll
    for (int nf = 0; nf < 4; nf++) {
      const u16* b_h = Wh + (size_t)(nq*64 + nf*16 + lr)*128 + ks*32 + lk8;
      const u16* b_l = Wl + (size_t)(nq*64 + nf*16 + lr)*128 + ks*32 + lk8;
      bf16x8 bh = *(const bf16x8*)b_h;
      bf16x8 bl = *(const bf16x8*)b_l;
      acc[nf] = MFMA(ah, bl, acc[nf]);
      acc[nf] = MFMA(al, bh, acc[nf]);
      acc[nf] = MFMA(ah, bh, acc[nf]);
    }
  }
  #pragma unroll
  for (int nf = 0; nf < 4; nf++) {
    int col = nq*64 + nf*16 + lr;
    float bb = bo[col];
    #pragma unroll
    for (int r = 0; r < 4; r++) {
      int lrow = mq*16 + lg*4 + r;
      size_t o = (size_t)(m0 + lrow)*128 + col;
      float val = acc[nf][r] + bb;
      if (skip_init) ssum[o] = val; else ssum[o] += val;
      float hn = hbuf[o] + val;
      hbuf[o] = hn;
      dmp[lrow][col] = hn;
    }
  }
  __syncthreads();
  const int row = tid >> 3, part = tid & 7;
  float xv[16], s = 0.f;
  const float* dp = &dmp[row][part*16];
  #pragma unroll
  for (int i = 0; i < 16; i++) { xv[i] = dp[i]; s += xv[i]; }
  s += __shfl_xor(s, 1); s += __shfl_xor(s, 2); s += __shfl_xor(s, 4);
  float mean = s * (1.f/128.f);
  float v = 0.f;
  #pragma unroll
  for (int i = 0; i < 16; i++) { float d = xv[i]-mean; v += d*d; }
  v += __shfl_xor(v, 1); v += __shfl_xor(v, 2); v += __shfl_xor(v, 4);
  float rs = rsqrtf(v*(1.f/128.f) + 1e-5f);
  size_t gro = (size_t)(m0 + row)*128;
  #pragma unroll
  for (int i = 0; i < 16; i++) {
    int c = part*16 + i;
    float y = (xv[i]-mean)*rs*sc[c] + bi[c];
    u16 hh, ll; splitbf(y, hh, ll);
    oh[gro + c] = hh; ol[gro + c] = ll;
  }
}

// ---------------- fused FFN: relu(x@W1+b1)@W2+b2 + residual + LN1(next) ----
__global__ __launch_bounds__(256) void k_ffn(
    const u16* __restrict__ Ah, const u16* __restrict__ Al,
    const u16* __restrict__ W1h, const u16* __restrict__ W1l,
    const float* __restrict__ b1,
    const u16* __restrict__ W2h, const u16* __restrict__ W2l,
    const float* __restrict__ b2,
    const float* __restrict__ sc, const float* __restrict__ bi, int do_ln,
    float* __restrict__ hbuf, u16* __restrict__ oh, u16* __restrict__ ol)
{
  __shared__ char smraw[17408];
  u16* hidH = (u16*)smraw;
  u16* hidL = hidH + 32*136;
  float (*dmp)[132] = (float(*)[132])smraw;
  const int tid = threadIdx.x, lane = tid & 63, wid = tid >> 6;
  const int m0 = blockIdx.x * 32;
  const int mq = wid >> 1, nq = wid & 1;
  const int lr = lane & 15, lg = lane >> 4, lk8 = lg * 8;
  const u16* a_h = Ah + (size_t)(m0 + mq*16 + lr)*128 + lk8;
  const u16* a_l = Al + (size_t)(m0 + mq*16 + lr)*128 + lk8;
  f32x4 acc2[4] = {};
  for (int c = 0; c < 4; c++) {
    f32x4 acc1[4] = {};
    #pragma unroll
    for (int ks = 0; ks < 4; ks++) {
      bf16x8 ah = *(const bf16x8*)(a_h + ks*32);
      bf16x8 al = *(const bf16x8*)(a_l + ks*32);
      #pragma unroll
      for (int nf = 0; nf < 4; nf++) {
        int n = c*128 + nq*64 + nf*16 + lr;
        const u16* b_h = W1h + (size_t)n*128 + ks*32 + lk8;
        const u16* b_l = W1l + (size_t)n*128 + ks*32 + lk8;
        bf16x8 bh = *(const bf16x8*)b_h;
        bf16x8 bl = *(const bf16x8*)b_l;
        acc1[nf] = MFMA(ah, bl, acc1[nf]);
        acc1[nf] = MFMA(al, bh, acc1[nf]);
        acc1[nf] = MFMA(ah, bh, acc1[nf]);
      }
    }
    __syncthreads();   // prev GEMM2 done reading hid
    #pragma unroll
    for (int nf = 0; nf < 4; nf++) {
      int lcol = nq*64 + nf*16 + lr;
      float bb = b1[c*128 + lcol];
      #pragma unroll
      for (int r = 0; r < 4; r++) {
        int lrow = mq*16 + lg*4 + r;
        float hv = fmaxf(acc1[nf][r] + bb, 0.f);
        u16 hh, ll; splitbf(hv, hh, ll);
        hidH[lrow*136 + lcol] = hh;
        hidL[lrow*136 + lcol] = ll;
      }
    }
    __syncthreads();
    #pragma unroll
    for (int ks = 0; ks < 4; ks++) {
      bf16x8 ah = *(const bf16x8*)&hidH[(mq*16 + lr)*136 + ks*32 + lk8];
      bf16x8 al = *(const bf16x8*)&hidL[(mq*16 + lr)*136 + ks*32 + lk8];
      #pragma unroll
      for (int nf = 0; nf < 4; nf++) {
        int n = nq*64 + nf*16 + lr;
        const u16* b_h = W2h + (size_t)n*512 + c*128 + ks*32 + lk8;
        const u16* b_l = W2l + (size_t)n*512 + c*128 + ks*32 + lk8;
        bf16x8 bh = *(const bf16x8*)b_h;
        bf16x8 bl = *(const bf16x8*)b_l;
        acc2[nf] = MFMA(ah, bl, acc2[nf]);
        acc2[nf] = MFMA(al, bh, acc2[nf]);
        acc2[nf] = MFMA(ah, bh, acc2[nf]);
      }
    }
  }
  __syncthreads();   // hid -> dmp alias
  #pragma unroll
  for (int nf = 0; nf < 4; nf++) {
    int col = nq*64 + nf*16 + lr;
    float bb = b2[col];
    #pragma unroll
    for (int r = 0; r < 4; r++) {
      int lrow = mq*16 + lg*4 + r;
      size_t o = (size_t)(m0 + lrow)*128 + col;
      float hn = hbuf[o] + acc2[nf][r] + bb;
      hbuf[o] = hn;
      dmp[lrow][col] = hn;
    }
  }
  if (!do_ln) return;
  __syncthreads();
  const int row = tid >> 3, part = tid & 7;
  float xv[16], s = 0.f;
  const float* dp = &dmp[row][part*16];
  #pragma unroll
  for (int i = 0; i < 16; i++) { xv[i] = dp[i]; s += xv[i]; }
  s += __shfl_xor(s, 1); s += __shfl_xor(s, 2); s += __shfl_xor(s, 4);
  float mean = s * (1.f/128.f);
  float v = 0.f;
  #pragma unroll
  for (int i = 0; i < 16; i++) { float d = xv[i]-mean; v += d*d; }
  v += __shfl_xor(v, 1); v += __shfl_xor(v, 2); v += __shfl_xor(v, 4);
  float rs = rsqrtf(v*(1.f/128.f) + 1e-5f);
  size_t gro = (size_t)(m0 + row)*128;
  #pragma unroll
  for (int i = 0; i < 16; i++) {
    int c2 = part*16 + i;
    float y = (xv[i]-mean)*rs*sc[c2] + bi[c2];
    u16 hh, ll; splitbf(y, hh, ll);
    oh[gro + c2] = hh; ol[gro + c2] = ll;
  }
}

// ---------------- dilated local attention -> packed hi/lo ------------------
__global__ __launch_bounds__(256) void k_attn(
    const float* __restrict__ q, const float* __restrict__ kk,
    const float* __restrict__ vv, const float* __restrict__ Er,
    u16* __restrict__ oh, u16* __restrict__ ol, int dil)
{
  const int w = threadIdx.x >> 6, lane = threadIdx.x & 63;
  const int bt = blockIdx.x * 4 + w;
  const int b = bt >> 12;
  const int t = bt & 4095;
  #pragma unroll
  for (int h = 0; h < 2; h++) {
    float qd = q[bt*128 + h*64 + lane];
    float s[5];
    int tpc_arr[5];
    #pragma unroll
    for (int a = 0; a < 5; a++) {
      int tp = t + (a-2)*dil;
      bool valid = (tp >= 0 && tp < T_);
      int tpc = tp < 0 ? 0 : (tp > T_-1 ? T_-1 : tp);
      tpc_arr[a] = tpc;
      float kd = kk[(b*T_ + tpc)*128 + h*64 + lane];
      float er = Er[(h*5 + a)*64 + lane];
      float p = qd * (kd + er);
      p = wave_sum(p);
      s[a] = valid ? p * 0.125f : -1e30f;
    }
    float mx = s[0];
    #pragma unroll
    for (int a = 1; a < 5; a++) mx = fmaxf(mx, s[a]);
    float p[5], psum = 0.f;
    #pragma unroll
    for (int a = 0; a < 5; a++) { p[a] = __expf(s[a]-mx); psum += p[a]; }
    float inv = 1.f/psum;
    float o = 0.f;
    #pragma unroll
    for (int a = 0; a < 5; a++)
      o += p[a] * vv[(b*T_ + tpc_arr[a])*128 + h*64 + lane];
    float vo = o * inv;
    u16 hh, ll;
    splitbf(vo, hh, ll);
    oh[bt*128 + h*64 + lane] = hh;
    ol[bt*128 + h*64 + lane] = ll;
  }
}

// ---------------- tail kernels --------------------------------------------
__global__ __launch_bounds__(256) void k_out(
    const float* __restrict__ h, const float* __restrict__ Wout,
    const float* __restrict__ bout, float* __restrict__ out)
{
  int idx = blockIdx.x*256 + threadIdx.x;
  int bt = idx >> 1, j = idx & 1;
  float acc = bout[j];
  const float* hp = &h[bt*128];
  #pragma unroll 4
  for (int k2 = 0; k2 < 128; k2++)
    acc += fmaxf(hp[k2], 0.f) * Wout[k2*2 + j];
  out[idx] = acc;
}

__global__ __launch_bounds__(256) void k_red1(
    const float* __restrict__ ss, float* __restrict__ part)
{
  __shared__ float red[256];
  int b = blockIdx.x >> 5, g = blockIdx.x & 31;
  int c = threadIdx.x & 127, hf = threadIdx.x >> 7;
  float acc = 0.f;
  for (int i2 = 0; i2 < 64; i2++) {
    int t = g*128 + i2*2 + hf;
    acc += fmaxf(ss[(b*T_ + t)*128 + c], 0.f);
  }
  red[threadIdx.x] = acc;
  __syncthreads();
  if (threadIdx.x < 128)
    part[(b*32+g)*128 + threadIdx.x] = red[threadIdx.x] + red[threadIdx.x+128];
}

__global__ __launch_bounds__(256) void k_red2(
    const float* __restrict__ part, float* __restrict__ meanb)
{
  int idx = blockIdx.x*256 + threadIdx.x;
  if (idx >= 512) return;
  int b = idx >> 7, c = idx & 127;
  float s = 0.f;
  for (int g = 0; g < 32; g++) s += part[(b*32+g)*128 + c];
  meanb[idx] = s * (1.f/4096.f);
}

__global__ __launch_bounds__(256) void k_tproj(
    const float* __restrict__ meanb, const float* __restrict__ Wt,
    const float* __restrict__ bt, float* __restrict__ out)
{
  int idx = blockIdx.x*256 + threadIdx.x;
  if (idx >= 1200) return;
  int b = idx / 300, j = idx % 300;
  float acc = bt[j];
  #pragma unroll 4
  for (int k2 = 0; k2 < 128; k2++)
    acc += meanb[b*128 + k2] * Wt[k2*300 + j];
  out[32768 + idx] = acc;
}

// ---------------- launcher -------------------------------------------------
extern "C" void kernel_launch(void* const* d_in, const int* in_sizes, int n_in,
                              void* d_out, int out_size, void* d_ws, size_t ws_size,
                              hipStream_t stream)
{
  const float* x    = (const float*)d_in[0];
  const float* c1w  = (const float*)d_in[1];
  const float* c1b  = (const float*)d_in[2];
  const float* c2w  = (const float*)d_in[3];
  const float* c2b  = (const float*)d_in[4];
  const float* c3w  = (const float*)d_in[5];
  const float* c3b  = (const float*)d_in[6];
  const float* ln1s = (const float*)d_in[7];
  const float* ln1b = (const float*)d_in[8];
  const float* ln2s = (const float*)d_in[9];
  const float* ln2b = (const float*)d_in[10];
  const float* Wq   = (const float*)d_in[11];
  const float* bq   = (const float*)d_in[12];
  const float* Wk   = (const float*)d_in[13];
  const float* bk   = (const float*)d_in[14];
  const float* Wv   = (const float*)d_in[15];
  const float* bv   = (const float*)d_in[16];
  const float* Wo   = (const float*)d_in[17];
  const float* bo   = (const float*)d_in[18];
  const float* Er   = (const float*)d_in[19];
  const float* W1   = (const float*)d_in[20];
  const float* b1   = (const float*)d_in[21];
  const float* W2   = (const float*)d_in[22];
  const float* b2   = (const float*)d_in[23];
  const float* Wout = (const float*)d_in[24];
  const float* bout = (const float*)d_in[25];
  const float* Wt   = (const float*)d_in[26];
  const float* bt   = (const float*)d_in[27];

  char* W = (char*)d_ws;
  // region A (0 .. 33.5 MB): tmp1 (convs, per-b)
  u16* tmp1_h = (u16*)W;
  u16* tmp1_l = (u16*)(W + 11010048);
  // region B (33.5 .. 67 MB): c2out (convs) then qkv + x planes
  char* RB = W + 33554432;
  u16* c2o_h = (u16*)RB;
  u16* c2o_l = (u16*)(RB + 5242880);
  float* qb  = (float*)RB;
  float* kb  = qb + 2097152;
  float* vb2 = qb + 4194304;
  u16* xh    = (u16*)(RB + 25165824);
  u16* xlo   = (u16*)(RB + 29360128);
  // region C (67 MB ..): persistent
  char* RC = W + 67108864;
  float* hbuf = (float*)RC;
  float* ssum = (float*)(RC + 8388608);
  u16* wqkv_h = (u16*)(RC + 16777216);
  u16* wqkv_l = wqkv_h + 442368;
  u16* wo_h   = wqkv_l + 442368;
  u16* wo_l   = wo_h + 147456;
  u16* w1t_h  = wo_l + 147456;
  u16* w1t_l  = w1t_h + 589824;
  u16* w2t_h  = w1t_l + 589824;
  u16* w2t_l  = w2t_h + 589824;
  u16* wc2_h  = w2t_l + 589824;
  u16* wc2_l  = wc2_h + 24576;
  u16* wc3_h  = wc2_l + 24576;
  u16* wc3_l  = wc3_h + 147456;
  float* part  = (float*)(wc3_l + 147456);
  float* meanb = part + 16384;
  float* outf  = (float*)d_out;

  // weight prep
  k_wprep<<<576,  256, 0, stream>>>(Wq, wqkv_h,          wqkv_l,          128, 128, 9, 49152);
  k_wprep<<<576,  256, 0, stream>>>(Wk, wqkv_h + 16384,  wqkv_l + 16384,  128, 128, 9, 49152);
  k_wprep<<<576,  256, 0, stream>>>(Wv, wqkv_h + 32768,  wqkv_l + 32768,  128, 128, 9, 49152);
  k_wprep<<<576,  256, 0, stream>>>(Wo, wo_h,  wo_l,  128, 128, 9, 16384);
  k_wprep<<<2304, 256, 0, stream>>>(W1, w1t_h, w1t_l, 128, 512, 9, 65536);
  k_wprep<<<2304, 256, 0, stream>>>(W2, w2t_h, w2t_l, 512, 128, 9, 65536);
  k_wprep_c2<<<96,  256, 0, stream>>>(c2w, wc2_h, wc2_l);
  k_wprep_c3<<<576, 256, 0, stream>>>(c3w, wc3_h, wc3_l);

  // conv frontend, chunked per batch element
  for (int b = 0; b < B_; b++) {
    k_conv1<<<512, 256, 0, stream>>>(x + (size_t)b*T_*128, c1w, c1b, tmp1_h, tmp1_l);
    k_conv2m<<<512, 256, 0, stream>>>(tmp1_h, tmp1_l, wc2_h, wc2_l, c2b, c2o_h, c2o_l);
    k_conv3m<<<256, 256, 0, stream>>>(c2o_h, c2o_l, wc3_h, wc3_l, c3b,
                                      hbuf + (size_t)b*T_*128);
  }

  // layer-0 LN1
  k_ln<<<4096, 256, 0, stream>>>(hbuf, ln1s, ln1b, xh, xlo);

  for (int l = 0; l < 9; l++) {
    k_gqkv<<<dim3(256, 2, 3), 256, 0, stream>>>(
        xh, xlo, wqkv_h + l*49152, wqkv_l + l*49152,
        bq + l*128, bk + l*128, bv + l*128, qb);
    k_attn<<<4096, 256, 0, stream>>>(qb, kb, vb2, Er + l*640, xh, xlo, 1 << l);
    k_wo_ln<<<512, 256, 0, stream>>>(
        xh, xlo, wo_h + l*16384, wo_l + l*16384, bo + l*128,
        ln2s + l*128, ln2b + l*128,
        hbuf, ssum, (l == 0) ? 1 : 0, xh, xlo);
    k_ffn<<<512, 256, 0, stream>>>(
        xh, xlo, w1t_h + l*65536, w1t_l + l*65536, b1 + l*512,
        w2t_h + l*65536, w2t_l + l*65536, b2 + l*128,
        ln1s + (l+1 < 9 ? (l+1)*128 : 0), ln1b + (l+1 < 9 ? (l+1)*128 : 0),
        (l < 8) ? 1 : 0,
        hbuf, xh, xlo);
  }

  k_out<<<128, 256, 0, stream>>>(hbuf, Wout, bout, outf);
  k_red1<<<128, 256, 0, stream>>>(ssum, part);
  k_red2<<<2, 256, 0, stream>>>(part, meanb);
  k_tproj<<<5, 256, 0, stream>>>(meanb, Wt, bt, outf);
}

// Round 5
// 880.302 us; speedup vs baseline: 2.5894x; 1.7271x over previous
//
#include <hip/hip_runtime.h>

#define T_ 4096
#define B_ 4

typedef unsigned short u16;
typedef __bf16 bf16x8 __attribute__((ext_vector_type(8)));
typedef float f32x4 __attribute__((ext_vector_type(4)));

__device__ inline void splitbf(float v, u16& h, u16& l) {
  __bf16 hb = (__bf16)v;
  float r = v - (float)hb;
  __bf16 lb = (__bf16)r;
  h = __builtin_bit_cast(u16, hb);
  l = __builtin_bit_cast(u16, lb);
}

#define MFMA(a,b,c) __builtin_amdgcn_mfma_f32_16x16x32_bf16((a),(b),(c),0,0,0)

// ---------------- conv1 (5x3, pad_h=2) + pool3(W) + relu -------------------
__global__ __launch_bounds__(256) void k_conv1(
    const float* __restrict__ x, const float* __restrict__ w1,
    const float* __restrict__ b1, u16* __restrict__ th, u16* __restrict__ tl)
{
  __shared__ float sx[12][130];
  __shared__ float w1s[480];
  __shared__ float b1s[32];
  const int tid = threadIdx.x;
  const int t0 = blockIdx.x * 8;
  for (int i = tid; i < 1536; i += 256) {
    int r = i >> 7, c = i & 127;
    int t = t0 - 2 + r;
    sx[r][c] = (t >= 0 && t < T_) ? x[t*128 + c] : 0.f;
  }
  for (int i = tid; i < 480; i += 256) w1s[i] = w1[i];
  if (tid < 32) b1s[tid] = b1[tid];
  __syncthreads();
  for (int i = tid; i < 10752; i += 256) {
    int c1 = i & 31;
    int wp = (i >> 5) % 42;
    int tt = i / 1344;
    float m = -1e30f;
    #pragma unroll
    for (int j = 0; j < 3; j++) {
      float acc = 0.f;
      int wb = wp*3 + j;
      #pragma unroll
      for (int kh = 0; kh < 5; kh++)
        #pragma unroll
        for (int kw = 0; kw < 3; kw++)
          acc += sx[tt+kh][wb+kw] * w1s[c1*15 + kh*3 + kw];
      m = fmaxf(m, acc);
    }
    float v = fmaxf(m + b1s[c1], 0.f);
    u16 hh, ll; splitbf(v, hh, ll);
    int o = (t0 + tt)*1344 + wp*32 + c1;
    th[o] = hh; tl[o] = ll;
  }
}

// ---------------- conv2 (1x12) + pool3 + relu via MFMA ---------------------
// weights frag-major: tile (nf<4, kw<12) -> 512 u16, lane-contiguous
__global__ __launch_bounds__(256) void k_conv2m(
    const u16* __restrict__ th, const u16* __restrict__ tl,
    const u16* __restrict__ wh, const u16* __restrict__ wl,
    const float* __restrict__ b2,
    u16* __restrict__ oh, u16* __restrict__ ol)
{
  __shared__ u16 sh[8*43*40];
  __shared__ u16 sl[8*43*40];
  __shared__ float dmp[4][15][66];
  const int tid = threadIdx.x;
  const int t0 = blockIdx.x * 8;
  for (int i = tid; i < 1344; i += 256) {
    int cg = i & 3;
    int w = (i >> 2) % 42;
    int tt = i / 168;
    int so = (t0 + tt)*1344 + w*32 + cg*8;
    int dd = (tt*43 + w)*40 + cg*8;
    *(ulonglong2*)&sh[dd] = *(const ulonglong2*)&th[so];
    *(ulonglong2*)&sl[dd] = *(const ulonglong2*)&tl[so];
  }
  for (int i = tid; i < 320; i += 256) {
    int tt = i / 40, c = i - tt*40;
    sh[(tt*43 + 42)*40 + c] = 0;
    sl[(tt*43 + 42)*40 + c] = 0;
  }
  __syncthreads();
  const int lane = tid & 63;
  const int wid = tid >> 6;
  const int lr = lane & 15;
  const int lk8 = (lane >> 4) * 8;
  f32x4 acc[2][2][4] = {};
  #pragma unroll 3
  for (int kw = 0; kw < 12; kw++) {
    bf16x8 bh[4], bl[4];
    #pragma unroll
    for (int nf = 0; nf < 4; nf++) {
      int go = ((nf*12 + kw) << 9) + (lane << 3);
      bh[nf] = *(const bf16x8*)(wh + go);
      bl[nf] = *(const bf16x8*)(wl + go);
    }
    #pragma unroll
    for (int tp = 0; tp < 2; tp++) {
      int tloc = wid*2 + tp;
      #pragma unroll
      for (int mf = 0; mf < 2; mf++) {
        int lofs = (tloc*43 + mf*16 + lr + kw)*40 + lk8;
        bf16x8 ah = *(const bf16x8*)&sh[lofs];
        bf16x8 al = *(const bf16x8*)&sl[lofs];
        #pragma unroll
        for (int nf = 0; nf < 4; nf++) {
          acc[tp][mf][nf] = MFMA(ah, bl[nf], acc[tp][mf][nf]);
          acc[tp][mf][nf] = MFMA(al, bh[nf], acc[tp][mf][nf]);
          acc[tp][mf][nf] = MFMA(ah, bh[nf], acc[tp][mf][nf]);
        }
      }
    }
  }
  const int lg = lane >> 4;
  for (int tp = 0; tp < 2; tp++) {
    int t = t0 + wid*2 + tp;
    for (int half = 0; half < 2; half++) {
      #pragma unroll
      for (int mf = 0; mf < 2; mf++)
        #pragma unroll
        for (int r = 0; r < 4; r++) {
          int grow = mf*16 + lg*4 + r;
          int lrow = grow - half*15;
          if (lrow >= 0 && lrow < 15) {
            #pragma unroll
            for (int nf = 0; nf < 4; nf++)
              dmp[wid][lrow][nf*16 + lr] = acc[tp][mf][nf][r];
          }
        }
      asm volatile("s_waitcnt lgkmcnt(0)" ::: "memory");
      #pragma unroll
      for (int it = 0; it < 5; it++) {
        float v = fmaxf(fmaxf(dmp[wid][it*3][lane], dmp[wid][it*3+1][lane]),
                        dmp[wid][it*3+2][lane]);
        v = fmaxf(v + b2[lane], 0.f);
        u16 hh, ll; splitbf(v, hh, ll);
        int o = (t*10 + half*5 + it)*64 + lane;
        oh[o] = hh; ol[o] = ll;
      }
      asm volatile("s_waitcnt lgkmcnt(0)" ::: "memory");
    }
  }
}

// ---------------- conv3 (3x6, pad_h=1) + pool3 + relu via MFMA -------------
// weights frag-major: tile (nt<8, s<36) where s = khkw*2 + chh
__global__ __launch_bounds__(256) void k_conv3m(
    const u16* __restrict__ ih, const u16* __restrict__ il,
    const u16* __restrict__ wh, const u16* __restrict__ wl,
    const float* __restrict__ b3, float* __restrict__ hout)
{
  __shared__ u16 sh[18*720];
  __shared__ u16 sl[18*720];
  __shared__ float dmp[48][132];
  const int tid = threadIdx.x;
  const int t0 = blockIdx.x * 16;
  for (int i = tid; i < 1440; i += 256) {
    int cg = i & 7;
    int w = (i >> 3) % 10;
    int tt = i / 80;
    int t = t0 - 1 + tt;
    int dd = tt*720 + w*72 + cg*8;
    if (t >= 0 && t < T_) {
      int so = (t*10 + w)*64 + cg*8;
      *(ulonglong2*)&sh[dd] = *(const ulonglong2*)&ih[so];
      *(ulonglong2*)&sl[dd] = *(const ulonglong2*)&il[so];
    } else {
      ulonglong2 z; z.x = 0; z.y = 0;
      *(ulonglong2*)&sh[dd] = z;
      *(ulonglong2*)&sl[dd] = z;
    }
  }
  __syncthreads();
  const int lane = tid & 63;
  const int wid = tid >> 6;
  const int lr = lane & 15;
  const int lk8 = (lane >> 4) * 8;
  int tlm[3], wom[3];
  #pragma unroll
  for (int mf = 0; mf < 3; mf++) {
    int r = mf*16 + lr;
    tlm[mf] = r / 3;
    wom[mf] = r - tlm[mf]*3;
  }
  f32x4 acc[3][2] = {};
  #pragma unroll 2
  for (int kh = 0; kh < 3; kh++) {
    #pragma unroll
    for (int kw = 0; kw < 6; kw++) {
      #pragma unroll
      for (int chh = 0; chh < 2; chh++) {
        int s = (kh*6 + kw)*2 + chh;
        int ch = chh*32;
        bf16x8 bh[2], bl[2];
        #pragma unroll
        for (int nfl = 0; nfl < 2; nfl++) {
          int go = (((wid*2 + nfl)*36 + s) << 9) + (lane << 3);
          bh[nfl] = *(const bf16x8*)(wh + go);
          bl[nfl] = *(const bf16x8*)(wl + go);
        }
        #pragma unroll
        for (int mf = 0; mf < 3; mf++) {
          int lofs = (tlm[mf] + kh)*720 + (wom[mf] + kw)*72 + ch + lk8;
          bf16x8 ah = *(const bf16x8*)&sh[lofs];
          bf16x8 al = *(const bf16x8*)&sl[lofs];
          #pragma unroll
          for (int nfl = 0; nfl < 2; nfl++) {
            acc[mf][nfl] = MFMA(ah, bl[nfl], acc[mf][nfl]);
            acc[mf][nfl] = MFMA(al, bh[nfl], acc[mf][nfl]);
            acc[mf][nfl] = MFMA(ah, bh[nfl], acc[mf][nfl]);
          }
        }
      }
    }
  }
  const int lg = lane >> 4;
  #pragma unroll
  for (int mf = 0; mf < 3; mf++)
    #pragma unroll
    for (int r = 0; r < 4; r++) {
      int row = mf*16 + lg*4 + r;
      #pragma unroll
      for (int nfl = 0; nfl < 2; nfl++)
        dmp[row][wid*32 + nfl*16 + lr] = acc[mf][nfl][r];
    }
  __syncthreads();
  for (int i = tid; i < 2048; i += 256) {
    int c3 = i & 127;
    int tt = i >> 7;
    float v = fmaxf(fmaxf(dmp[tt*3][c3], dmp[tt*3+1][c3]), dmp[tt*3+2][c3]);
    v = fmaxf(v + b3[c3], 0.f);
    hout[(t0 + tt)*128 + c3] = v;
  }
}

// ---------------- standalone LayerNorm (layer-0 LN1 only) ------------------
__device__ inline float wave_sum(float v) {
  #pragma unroll
  for (int m = 1; m < 64; m <<= 1) v += __shfl_xor(v, m, 64);
  return v;
}

__global__ __launch_bounds__(256) void k_ln(
    const float* __restrict__ in, const float* __restrict__ sc,
    const float* __restrict__ bi, u16* __restrict__ oh, u16* __restrict__ ol)
{
  const int lane = threadIdx.x & 63;
  const int row = blockIdx.x*4 + (threadIdx.x >> 6);
  float a = in[row*128 + lane];
  float c = in[row*128 + 64 + lane];
  float mean = wave_sum(a + c) * (1.f/128.f);
  float d0 = a - mean, d1 = c - mean;
  float var = wave_sum(d0*d0 + d1*d1) * (1.f/128.f);
  float rs = rsqrtf(var + 1e-5f);
  float v0 = d0*rs*sc[lane]    + bi[lane];
  float v1 = d1*rs*sc[64+lane] + bi[64+lane];
  u16 h0, l0, h1, l1;
  splitbf(v0, h0, l0); splitbf(v1, h1, l1);
  oh[row*128 + lane] = h0;      ol[row*128 + lane] = l0;
  oh[row*128 + 64 + lane] = h1; ol[row*128 + 64 + lane] = l1;
}

// ---------------- weight prep: fragment-major packing ----------------------
// dst tile (nt, ks): 512 u16; lane l holds k=ks*32+(l>>4)*8+j, n=nt*16+(l&15)
__global__ __launch_bounds__(256) void k_wprep_fr(
    const float* __restrict__ src, u16* __restrict__ dh, u16* __restrict__ dl,
    int K, int N, int nm, int matStride)
{
  int idx = blockIdx.x*256 + threadIdx.x;
  if (idx >= nm*K*N) return;
  int mat = idx / (K*N);
  int rem = idx - mat*(K*N);
  int k = rem / N;
  int n = rem - k*N;
  float v = src[idx];
  u16 h, l; splitbf(v, h, l);
  int nt = n >> 4, ks = k >> 5, ksub = k & 31;
  size_t o = (size_t)mat*matStride + (size_t)((nt*(K>>5) + ks) << 9)
           + (((ksub >> 3) << 4) + (n & 15))*8 + (ksub & 7);
  dh[o] = h; dl[o] = l;
}

__global__ __launch_bounds__(256) void k_wprep_c2(
    const float* __restrict__ w2, u16* __restrict__ dh, u16* __restrict__ dl)
{
  int idx = blockIdx.x*256 + threadIdx.x;
  if (idx >= 24576) return;
  int c2 = idx / 384;
  int rem = idx - c2*384;
  int c1 = rem / 12;
  int kw = rem - c1*12;
  float v = w2[idx];
  u16 h, l; splitbf(v, h, l);
  size_t o = (size_t)((((c2 >> 4)*12 + kw) << 9))
           + (((c1 >> 3) << 4) + (c2 & 15))*8 + (c1 & 7);
  dh[o] = h; dl[o] = l;
}

__global__ __launch_bounds__(256) void k_wprep_c3(
    const float* __restrict__ w3, u16* __restrict__ dh, u16* __restrict__ dl)
{
  int idx = blockIdx.x*256 + threadIdx.x;
  if (idx >= 147456) return;
  int c3 = idx / 1152;
  int rem = idx - c3*1152;
  int c2 = rem / 18;
  int khkw = rem - c2*18;
  float v = w3[idx];
  u16 h, l; splitbf(v, h, l);
  int s = khkw*2 + (c2 >> 5);
  int c = c2 & 31;
  size_t o = (size_t)((((c3 >> 4)*36 + s) << 9))
           + (((c >> 3) << 4) + (c3 & 15))*8 + (c & 7);
  dh[o] = h; dl[o] = l;
}

// ---------------- QKV GEMM: tile 16 x 128, grid (1024, 3) ------------------
__global__ __launch_bounds__(256) void k_gqkv(
    const u16* __restrict__ Ah, const u16* __restrict__ Al,
    const u16* __restrict__ Wh, const u16* __restrict__ Wl,
    const float* __restrict__ bq, const float* __restrict__ bk,
    const float* __restrict__ bv, float* __restrict__ outbase)
{
  __shared__ u16 sAh[16*136], sAl[16*136];
  const int tid = threadIdx.x;
  const int m0 = blockIdx.x * 16;
  const int z = blockIdx.y;
  const u16* wh = Wh + z*16384;
  const u16* wl = Wl + z*16384;
  const float* bias = (z == 0) ? bq : (z == 1) ? bk : bv;
  float* C = outbase + (size_t)z*2097152;
  {
    int row = tid >> 4, c8 = tid & 15;
    *(ulonglong2*)&sAh[row*136 + c8*8] = *(const ulonglong2*)&Ah[(size_t)(m0+row)*128 + c8*8];
    *(ulonglong2*)&sAl[row*136 + c8*8] = *(const ulonglong2*)&Al[(size_t)(m0+row)*128 + c8*8];
  }
  __syncthreads();
  const int lane = tid & 63, nq = tid >> 6;
  const int lr = lane & 15, lg = lane >> 4, l8 = lg*8;
  f32x4 acc[2] = {};
  #pragma unroll
  for (int ks = 0; ks < 4; ks++) {
    bf16x8 ah = *(const bf16x8*)&sAh[lr*136 + ks*32 + l8];
    bf16x8 al = *(const bf16x8*)&sAl[lr*136 + ks*32 + l8];
    #pragma unroll
    for (int nf = 0; nf < 2; nf++) {
      int go = (((nq*2 + nf)*4 + ks) << 9) + (lane << 3);
      bf16x8 bh = *(const bf16x8*)(wh + go);
      bf16x8 bl = *(const bf16x8*)(wl + go);
      acc[nf] = MFMA(ah, bl, acc[nf]);
      acc[nf] = MFMA(al, bh, acc[nf]);
      acc[nf] = MFMA(ah, bh, acc[nf]);
    }
  }
  #pragma unroll
  for (int nf = 0; nf < 2; nf++) {
    int col = nq*32 + nf*16 + lr;
    float bb = bias[col];
    #pragma unroll
    for (int r = 0; r < 4; r++)
      C[(size_t)(m0 + lg*4 + r)*128 + col] = acc[nf][r] + bb;
  }
}

// ---------------- Wo GEMM + residual + skip-acc + LN2: tile 16x128 ---------
__global__ __launch_bounds__(256) void k_wo_ln(
    const u16* __restrict__ Ah, const u16* __restrict__ Al,
    const u16* __restrict__ Wh, const u16* __restrict__ Wl,
    const float* __restrict__ bo, const float* __restrict__ sc,
    const float* __restrict__ bi,
    float* __restrict__ hbuf, float* __restrict__ ssum, int skip_init,
    u16* __restrict__ oh, u16* __restrict__ ol)
{
  __shared__ u16 sAh[16*136], sAl[16*136];
  __shared__ float dmp[16*132];
  const int tid = threadIdx.x;
  const int m0 = blockIdx.x * 16;
  {
    int row = tid >> 4, c8 = tid & 15;
    *(ulonglong2*)&sAh[row*136 + c8*8] = *(const ulonglong2*)&Ah[(size_t)(m0+row)*128 + c8*8];
    *(ulonglong2*)&sAl[row*136 + c8*8] = *(const ulonglong2*)&Al[(size_t)(m0+row)*128 + c8*8];
  }
  __syncthreads();
  const int lane = tid & 63, nq = tid >> 6;
  const int lr = lane & 15, lg = lane >> 4, l8 = lg*8;
  f32x4 acc[2] = {};
  #pragma unroll
  for (int ks = 0; ks < 4; ks++) {
    bf16x8 ah = *(const bf16x8*)&sAh[lr*136 + ks*32 + l8];
    bf16x8 al = *(const bf16x8*)&sAl[lr*136 + ks*32 + l8];
    #pragma unroll
    for (int nf = 0; nf < 2; nf++) {
      int go = (((nq*2 + nf)*4 + ks) << 9) + (lane << 3);
      bf16x8 bh = *(const bf16x8*)(Wh + go);
      bf16x8 bl = *(const bf16x8*)(Wl + go);
      acc[nf] = MFMA(ah, bl, acc[nf]);
      acc[nf] = MFMA(al, bh, acc[nf]);
      acc[nf] = MFMA(ah, bh, acc[nf]);
    }
  }
  #pragma unroll
  for (int nf = 0; nf < 2; nf++) {
    int col = nq*32 + nf*16 + lr;
    float bb = bo[col];
    #pragma unroll
    for (int r = 0; r < 4; r++) {
      int row = lg*4 + r;
      size_t o = (size_t)(m0 + row)*128 + col;
      float val = acc[nf][r] + bb;
      if (skip_init) ssum[o] = val; else ssum[o] += val;
      float hn = hbuf[o] + val;
      hbuf[o] = hn;
      dmp[row*132 + col] = hn;
    }
  }
  __syncthreads();
  const int row = tid >> 4, p = tid & 15;
  float xv[8], s = 0.f;
  const float* dp = &dmp[row*132 + p*8];
  #pragma unroll
  for (int i = 0; i < 8; i++) { xv[i] = dp[i]; s += xv[i]; }
  s += __shfl_xor(s, 1); s += __shfl_xor(s, 2);
  s += __shfl_xor(s, 4); s += __shfl_xor(s, 8);
  float mean = s * (1.f/128.f);
  float v = 0.f;
  #pragma unroll
  for (int i = 0; i < 8; i++) { float d = xv[i]-mean; v += d*d; }
  v += __shfl_xor(v, 1); v += __shfl_xor(v, 2);
  v += __shfl_xor(v, 4); v += __shfl_xor(v, 8);
  float rs = rsqrtf(v*(1.f/128.f) + 1e-5f);
  size_t gro = (size_t)(m0 + row)*128;
  #pragma unroll
  for (int i = 0; i < 8; i++) {
    int c = p*8 + i;
    float y = (xv[i]-mean)*rs*sc[c] + bi[c];
    u16 hh, ll; splitbf(y, hh, ll);
    oh[gro + c] = hh; ol[gro + c] = ll;
  }
}

// ---------------- fused FFN: tile 16 rows, hid in LDS, grid 1024 -----------
__global__ __launch_bounds__(256) void k_ffn(
    const u16* __restrict__ Ah, const u16* __restrict__ Al,
    const u16* __restrict__ W1h, const u16* __restrict__ W1l,
    const float* __restrict__ b1,
    const u16* __restrict__ W2h, const u16* __restrict__ W2l,
    const float* __restrict__ b2,
    const float* __restrict__ sc, const float* __restrict__ bi, int do_ln,
    float* __restrict__ hbuf, u16* __restrict__ oh, u16* __restrict__ ol)
{
  __shared__ u16 sAh[16*136], sAl[16*136];
  __shared__ u16 hidH[2][16*136], hidL[2][16*136];
  __shared__ float dmp[16*132];
  const int tid = threadIdx.x;
  const int m0 = blockIdx.x * 16;
  {
    int row = tid >> 4, c8 = tid & 15;
    *(ulonglong2*)&sAh[row*136 + c8*8] = *(const ulonglong2*)&Ah[(size_t)(m0+row)*128 + c8*8];
    *(ulonglong2*)&sAl[row*136 + c8*8] = *(const ulonglong2*)&Al[(size_t)(m0+row)*128 + c8*8];
  }
  __syncthreads();
  const int lane = tid & 63, nq = tid >> 6;
  const int lr = lane & 15, lg = lane >> 4, l8 = lg*8;
  f32x4 acc2[2] = {};
  for (int c = 0; c < 4; c++) {
    f32x4 acc1[2] = {};
    #pragma unroll
    for (int ks = 0; ks < 4; ks++) {
      bf16x8 ah = *(const bf16x8*)&sAh[lr*136 + ks*32 + l8];
      bf16x8 al = *(const bf16x8*)&sAl[lr*136 + ks*32 + l8];
      #pragma unroll
      for (int nf = 0; nf < 2; nf++) {
        int go = (((c*8 + nq*2 + nf)*4 + ks) << 9) + (lane << 3);
        bf16x8 bh = *(const bf16x8*)(W1h + go);
        bf16x8 bl = *(const bf16x8*)(W1l + go);
        acc1[nf] = MFMA(ah, bl, acc1[nf]);
        acc1[nf] = MFMA(al, bh, acc1[nf]);
        acc1[nf] = MFMA(ah, bh, acc1[nf]);
      }
    }
    __syncthreads();
    #pragma unroll
    for (int nf = 0; nf < 2; nf++) {
      int col = nq*32 + nf*16 + lr;
      float bb = b1[c*128 + col];
      #pragma unroll
      for (int r = 0; r < 4; r++) {
        int row = lg*4 + r;
        float hv = fmaxf(acc1[nf][r] + bb, 0.f);
        u16 hh, ll; splitbf(hv, hh, ll);
        hidH[c & 1][row*136 + col] = hh;
        hidL[c & 1][row*136 + col] = ll;
      }
    }
    __syncthreads();
    #pragma unroll
    for (int ks = 0; ks < 4; ks++) {
      bf16x8 ah = *(const bf16x8*)&hidH[c & 1][lr*136 + ks*32 + l8];
      bf16x8 al = *(const bf16x8*)&hidL[c & 1][lr*136 + ks*32 + l8];
      #pragma unroll
      for (int nf = 0; nf < 2; nf++) {
        int go = (((nq*2 + nf)*16 + c*4 + ks) << 9) + (lane << 3);
        bf16x8 bh = *(const bf16x8*)(W2h + go);
        bf16x8 bl = *(const bf16x8*)(W2l + go);
        acc2[nf] = MFMA(ah, bl, acc2[nf]);
        acc2[nf] = MFMA(al, bh, acc2[nf]);
        acc2[nf] = MFMA(ah, bh, acc2[nf]);
      }
    }
  }
  #pragma unroll
  for (int nf = 0; nf < 2; nf++) {
    int col = nq*32 + nf*16 + lr;
    float bb = b2[col];
    #pragma unroll
    for (int r = 0; r < 4; r++) {
      int row = lg*4 + r;
      size_t o = (size_t)(m0 + row)*128 + col;
      float hn = hbuf[o] + acc2[nf][r] + bb;
      hbuf[o] = hn;
      dmp[row*132 + col] = hn;
    }
  }
  if (!do_ln) return;
  __syncthreads();
  const int row = tid >> 4, p = tid & 15;
  float xv[8], s = 0.f;
  const float* dp = &dmp[row*132 + p*8];
  #pragma unroll
  for (int i = 0; i < 8; i++) { xv[i] = dp[i]; s += xv[i]; }
  s += __shfl_xor(s, 1); s += __shfl_xor(s, 2);
  s += __shfl_xor(s, 4); s += __shfl_xor(s, 8);
  float mean = s * (1.f/128.f);
  float v = 0.f;
  #pragma unroll
  for (int i = 0; i < 8; i++) { float d = xv[i]-mean; v += d*d; }
  v += __shfl_xor(v, 1); v += __shfl_xor(v, 2);
  v += __shfl_xor(v, 4); v += __shfl_xor(v, 8);
  float rs = rsqrtf(v*(1.f/128.f) + 1e-5f);
  size_t gro = (size_t)(m0 + row)*128;
  #pragma unroll
  for (int i = 0; i < 8; i++) {
    int c2 = p*8 + i;
    float y = (xv[i]-mean)*rs*sc[c2] + bi[c2];
    u16 hh, ll; splitbf(y, hh, ll);
    oh[gro + c2] = hh; ol[gro + c2] = ll;
  }
}

// ---------------- dilated local attention -> packed hi/lo ------------------
__global__ __launch_bounds__(256) void k_attn(
    const float* __restrict__ q, const float* __restrict__ kk,
    const float* __restrict__ vv, const float* __restrict__ Er,
    u16* __restrict__ oh, u16* __restrict__ ol, int dil)
{
  const int w = threadIdx.x >> 6, lane = threadIdx.x & 63;
  const int bt = blockIdx.x * 4 + w;
  const int b = bt >> 12;
  const int t = bt & 4095;
  #pragma unroll
  for (int h = 0; h < 2; h++) {
    float qd = q[bt*128 + h*64 + lane];
    float s[5];
    int tpc_arr[5];
    #pragma unroll
    for (int a = 0; a < 5; a++) {
      int tp = t + (a-2)*dil;
      bool valid = (tp >= 0 && tp < T_);
      int tpc = tp < 0 ? 0 : (tp > T_-1 ? T_-1 : tp);
      tpc_arr[a] = tpc;
      float kd = kk[(b*T_ + tpc)*128 + h*64 + lane];
      float er = Er[(h*5 + a)*64 + lane];
      float p = qd * (kd + er);
      p = wave_sum(p);
      s[a] = valid ? p * 0.125f : -1e30f;
    }
    float mx = s[0];
    #pragma unroll
    for (int a = 1; a < 5; a++) mx = fmaxf(mx, s[a]);
    float p[5], psum = 0.f;
    #pragma unroll
    for (int a = 0; a < 5; a++) { p[a] = __expf(s[a]-mx); psum += p[a]; }
    float inv = 1.f/psum;
    float o = 0.f;
    #pragma unroll
    for (int a = 0; a < 5; a++)
      o += p[a] * vv[(b*T_ + tpc_arr[a])*128 + h*64 + lane];
    float vo = o * inv;
    u16 hh, ll;
    splitbf(vo, hh, ll);
    oh[bt*128 + h*64 + lane] = hh;
    ol[bt*128 + h*64 + lane] = ll;
  }
}

// ---------------- tail kernels --------------------------------------------
__global__ __launch_bounds__(256) void k_out(
    const float* __restrict__ h, const float* __restrict__ Wout,
    const float* __restrict__ bout, float* __restrict__ out)
{
  int idx = blockIdx.x*256 + threadIdx.x;
  int bt = idx >> 1, j = idx & 1;
  float acc = bout[j];
  const float* hp = &h[bt*128];
  #pragma unroll 4
  for (int k2 = 0; k2 < 128; k2++)
    acc += fmaxf(hp[k2], 0.f) * Wout[k2*2 + j];
  out[idx] = acc;
}

__global__ __launch_bounds__(256) void k_red1(
    const float* __restrict__ ss, float* __restrict__ part)
{
  __shared__ float red[256];
  int b = blockIdx.x >> 5, g = blockIdx.x & 31;
  int c = threadIdx.x & 127, hf = threadIdx.x >> 7;
  float acc = 0.f;
  for (int i2 = 0; i2 < 64; i2++) {
    int t = g*128 + i2*2 + hf;
    acc += fmaxf(ss[(b*T_ + t)*128 + c], 0.f);
  }
  red[threadIdx.x] = acc;
  __syncthreads();
  if (threadIdx.x < 128)
    part[(b*32+g)*128 + threadIdx.x] = red[threadIdx.x] + red[threadIdx.x+128];
}

__global__ __launch_bounds__(256) void k_red2(
    const float* __restrict__ part, float* __restrict__ meanb)
{
  int idx = blockIdx.x*256 + threadIdx.x;
  if (idx >= 512) return;
  int b = idx >> 7, c = idx & 127;
  float s = 0.f;
  for (int g = 0; g < 32; g++) s += part[(b*32+g)*128 + c];
  meanb[idx] = s * (1.f/4096.f);
}

__global__ __launch_bounds__(256) void k_tproj(
    const float* __restrict__ meanb, const float* __restrict__ Wt,
    const float* __restrict__ bt, float* __restrict__ out)
{
  int idx = blockIdx.x*256 + threadIdx.x;
  if (idx >= 1200) return;
  int b = idx / 300, j = idx % 300;
  float acc = bt[j];
  #pragma unroll 4
  for (int k2 = 0; k2 < 128; k2++)
    acc += meanb[b*128 + k2] * Wt[k2*300 + j];
  out[32768 + idx] = acc;
}

// ---------------- launcher -------------------------------------------------
extern "C" void kernel_launch(void* const* d_in, const int* in_sizes, int n_in,
                              void* d_out, int out_size, void* d_ws, size_t ws_size,
                              hipStream_t stream)
{
  const float* x    = (const float*)d_in[0];
  const float* c1w  = (const float*)d_in[1];
  const float* c1b  = (const float*)d_in[2];
  const float* c2w  = (const float*)d_in[3];
  const float* c2b  = (const float*)d_in[4];
  const float* c3w  = (const float*)d_in[5];
  const float* c3b  = (const float*)d_in[6];
  const float* ln1s = (const float*)d_in[7];
  const float* ln1b = (const float*)d_in[8];
  const float* ln2s = (const float*)d_in[9];
  const float* ln2b = (const float*)d_in[10];
  const float* Wq   = (const float*)d_in[11];
  const float* bq   = (const float*)d_in[12];
  const float* Wk   = (const float*)d_in[13];
  const float* bk   = (const float*)d_in[14];
  const float* Wv   = (const float*)d_in[15];
  const float* bv   = (const float*)d_in[16];
  const float* Wo   = (const float*)d_in[17];
  const float* bo   = (const float*)d_in[18];
  const float* Er   = (const float*)d_in[19];
  const float* W1   = (const float*)d_in[20];
  const float* b1   = (const float*)d_in[21];
  const float* W2   = (const float*)d_in[22];
  const float* b2   = (const float*)d_in[23];
  const float* Wout = (const float*)d_in[24];
  const float* bout = (const float*)d_in[25];
  const float* Wt   = (const float*)d_in[26];
  const float* bt   = (const float*)d_in[27];

  char* W = (char*)d_ws;
  // region A (0 .. 33.5 MB): tmp1 (convs, per-b)
  u16* tmp1_h = (u16*)W;
  u16* tmp1_l = (u16*)(W + 11010048);
  // region B (33.5 .. 67 MB): c2out (convs) then qkv + x planes
  char* RB = W + 33554432;
  u16* c2o_h = (u16*)RB;
  u16* c2o_l = (u16*)(RB + 5242880);
  float* qb  = (float*)RB;
  float* kb  = qb + 2097152;
  float* vb2 = qb + 4194304;
  u16* xh    = (u16*)(RB + 25165824);
  u16* xlo   = (u16*)(RB + 29360128);
  // region C (67 MB ..): persistent
  char* RC = W + 67108864;
  float* hbuf = (float*)RC;
  float* ssum = (float*)(RC + 8388608);
  u16* wqkv_h = (u16*)(RC + 16777216);
  u16* wqkv_l = wqkv_h + 442368;
  u16* wo_h   = wqkv_l + 442368;
  u16* wo_l   = wo_h + 147456;
  u16* w1t_h  = wo_l + 147456;
  u16* w1t_l  = w1t_h + 589824;
  u16* w2t_h  = w1t_l + 589824;
  u16* w2t_l  = w2t_h + 589824;
  u16* wc2_h  = w2t_l + 589824;
  u16* wc2_l  = wc2_h + 24576;
  u16* wc3_h  = wc2_l + 24576;
  u16* wc3_l  = wc3_h + 147456;
  float* part  = (float*)(wc3_l + 147456);
  float* meanb = part + 16384;
  float* outf  = (float*)d_out;

  // weight prep (fragment-major)
  k_wprep_fr<<<576,  256, 0, stream>>>(Wq, wqkv_h,          wqkv_l,          128, 128, 9, 49152);
  k_wprep_fr<<<576,  256, 0, stream>>>(Wk, wqkv_h + 16384,  wqkv_l + 16384,  128, 128, 9, 49152);
  k_wprep_fr<<<576,  256, 0, stream>>>(Wv, wqkv_h + 32768,  wqkv_l + 32768,  128, 128, 9, 49152);
  k_wprep_fr<<<576,  256, 0, stream>>>(Wo, wo_h,  wo_l,  128, 128, 9, 16384);
  k_wprep_fr<<<2304, 256, 0, stream>>>(W1, w1t_h, w1t_l, 128, 512, 9, 65536);
  k_wprep_fr<<<2304, 256, 0, stream>>>(W2, w2t_h, w2t_l, 512, 128, 9, 65536);
  k_wprep_c2<<<96,  256, 0, stream>>>(c2w, wc2_h, wc2_l);
  k_wprep_c3<<<576, 256, 0, stream>>>(c3w, wc3_h, wc3_l);

  // conv frontend, chunked per batch element
  for (int b = 0; b < B_; b++) {
    k_conv1<<<512, 256, 0, stream>>>(x + (size_t)b*T_*128, c1w, c1b, tmp1_h, tmp1_l);
    k_conv2m<<<512, 256, 0, stream>>>(tmp1_h, tmp1_l, wc2_h, wc2_l, c2b, c2o_h, c2o_l);
    k_conv3m<<<256, 256, 0, stream>>>(c2o_h, c2o_l, wc3_h, wc3_l, c3b,
                                      hbuf + (size_t)b*T_*128);
  }

  // layer-0 LN1
  k_ln<<<4096, 256, 0, stream>>>(hbuf, ln1s, ln1b, xh, xlo);

  for (int l = 0; l < 9; l++) {
    k_gqkv<<<dim3(1024, 3), 256, 0, stream>>>(
        xh, xlo, wqkv_h + l*49152, wqkv_l + l*49152,
        bq + l*128, bk + l*128, bv + l*128, qb);
    k_attn<<<4096, 256, 0, stream>>>(qb, kb, vb2, Er + l*640, xh, xlo, 1 << l);
    k_wo_ln<<<1024, 256, 0, stream>>>(
        xh, xlo, wo_h + l*16384, wo_l + l*16384, bo + l*128,
        ln2s + l*128, ln2b + l*128,
        hbuf, ssum, (l == 0) ? 1 : 0, xh, xlo);
    k_ffn<<<1024, 256, 0, stream>>>(
        xh, xlo, w1t_h + l*65536, w1t_l + l*65536, b1 + l*512,
        w2t_h + l*65536, w2t_l + l*65536, b2 + l*128,
        ln1s + (l+1 < 9 ? (l+1)*128 : 0), ln1b + (l+1 < 9 ? (l+1)*128 : 0),
        (l < 8) ? 1 : 0,
        hbuf, xh, xlo);
  }

  k_out<<<128, 256, 0, stream>>>(hbuf, Wout, bout, outf);
  k_red1<<<128, 256, 0, stream>>>(ssum, part);
  k_red2<<<2, 256, 0, stream>>>(part, meanb);
  k_tproj<<<5, 256, 0, stream>>>(meanb, Wt, bt, outf);
}

// Round 6
// 763.773 us; speedup vs baseline: 2.9844x; 1.1526x over previous
//
#include <hip/hip_runtime.h>

#define T_ 4096
#define B_ 4

typedef unsigned short u16;
typedef __bf16 bf16x8 __attribute__((ext_vector_type(8)));
typedef float f32x4 __attribute__((ext_vector_type(4)));

__device__ inline void splitbf(float v, u16& h, u16& l) {
  __bf16 hb = (__bf16)v;
  float r = v - (float)hb;
  __bf16 lb = (__bf16)r;
  h = __builtin_bit_cast(u16, hb);
  l = __builtin_bit_cast(u16, lb);
}

#define MFMA(a,b,c) __builtin_amdgcn_mfma_f32_16x16x32_bf16((a),(b),(c),0,0,0)

// ---------------- fused conv1(5x3,pad2)+pool3+relu + conv2(1x12)+pool3+relu
// x:(B,T,128) -> c2out hi/lo (B,T,10,64).  8 t per block, grid (512, B).
__global__ __launch_bounds__(256) void k_conv12m(
    const float* __restrict__ x, const float* __restrict__ w1,
    const float* __restrict__ b1,
    const u16* __restrict__ wh, const u16* __restrict__ wl,
    const float* __restrict__ b2,
    u16* __restrict__ oh, u16* __restrict__ ol)
{
  __shared__ float sx[12][130];
  __shared__ float w1s[480];
  __shared__ float b1s[32];
  __shared__ u16 sh[8*43*40];
  __shared__ u16 sl[8*43*40];
  __shared__ float dmp[4][15][66];
  const int tid = threadIdx.x;
  const int t0 = blockIdx.x * 8;
  const int b = blockIdx.y;
  const float* xb = x + (size_t)b*T_*128;
  for (int i = tid; i < 1536; i += 256) {
    int r = i >> 7, c = i & 127;
    int t = t0 - 2 + r;
    sx[r][c] = (t >= 0 && t < T_) ? xb[t*128 + c] : 0.f;
  }
  for (int i = tid; i < 480; i += 256) w1s[i] = w1[i];
  if (tid < 32) b1s[tid] = b1[tid];
  for (int i = tid; i < 320; i += 256) {   // zero pad cell w=42
    int tt = i / 40, c = i - tt*40;
    sh[(tt*43 + 42)*40 + c] = 0;
    sl[(tt*43 + 42)*40 + c] = 0;
  }
  __syncthreads();
  // conv1 + pool3 + relu -> LDS hi/lo (8t x 42w x 32c)
  for (int i = tid; i < 10752; i += 256) {
    int c1 = i & 31;
    int wp = (i >> 5) % 42;
    int tt = i / 1344;
    float m = -1e30f;
    #pragma unroll
    for (int j = 0; j < 3; j++) {
      float acc = 0.f;
      int wb = wp*3 + j;
      #pragma unroll
      for (int kh = 0; kh < 5; kh++)
        #pragma unroll
        for (int kw = 0; kw < 3; kw++)
          acc += sx[tt+kh][wb+kw] * w1s[c1*15 + kh*3 + kw];
      m = fmaxf(m, acc);
    }
    float v = fmaxf(m + b1s[c1], 0.f);
    u16 hh, ll; splitbf(v, hh, ll);
    int dd = (tt*43 + wp)*40 + c1;
    sh[dd] = hh; sl[dd] = ll;
  }
  __syncthreads();
  // conv2 via MFMA (weights frag-major)
  const int lane = tid & 63;
  const int wid = tid >> 6;
  const int lr = lane & 15;
  const int lk8 = (lane >> 4) * 8;
  f32x4 acc[2][2][4] = {};
  #pragma unroll 3
  for (int kw = 0; kw < 12; kw++) {
    bf16x8 bh[4], bl[4];
    #pragma unroll
    for (int nf = 0; nf < 4; nf++) {
      int go = ((nf*12 + kw) << 9) + (lane << 3);
      bh[nf] = *(const bf16x8*)(wh + go);
      bl[nf] = *(const bf16x8*)(wl + go);
    }
    #pragma unroll
    for (int tp = 0; tp < 2; tp++) {
      int tloc = wid*2 + tp;
      #pragma unroll
      for (int mf = 0; mf < 2; mf++) {
        int lofs = (tloc*43 + mf*16 + lr + kw)*40 + lk8;
        bf16x8 ah = *(const bf16x8*)&sh[lofs];
        bf16x8 al = *(const bf16x8*)&sl[lofs];
        #pragma unroll
        for (int nf = 0; nf < 4; nf++) {
          acc[tp][mf][nf] = MFMA(ah, bl[nf], acc[tp][mf][nf]);
          acc[tp][mf][nf] = MFMA(al, bh[nf], acc[tp][mf][nf]);
          acc[tp][mf][nf] = MFMA(ah, bh[nf], acc[tp][mf][nf]);
        }
      }
    }
  }
  const int lg = lane >> 4;
  for (int tp = 0; tp < 2; tp++) {
    int t = t0 + wid*2 + tp;
    for (int half = 0; half < 2; half++) {
      #pragma unroll
      for (int mf = 0; mf < 2; mf++)
        #pragma unroll
        for (int r = 0; r < 4; r++) {
          int grow = mf*16 + lg*4 + r;
          int lrow = grow - half*15;
          if (lrow >= 0 && lrow < 15) {
            #pragma unroll
            for (int nf = 0; nf < 4; nf++)
              dmp[wid][lrow][nf*16 + lr] = acc[tp][mf][nf][r];
          }
        }
      asm volatile("s_waitcnt lgkmcnt(0)" ::: "memory");
      #pragma unroll
      for (int it = 0; it < 5; it++) {
        float v = fmaxf(fmaxf(dmp[wid][it*3][lane], dmp[wid][it*3+1][lane]),
                        dmp[wid][it*3+2][lane]);
        v = fmaxf(v + b2[lane], 0.f);
        u16 hh, ll; splitbf(v, hh, ll);
        size_t o = (size_t)((b*T_ + t)*10 + half*5 + it)*64 + lane;
        oh[o] = hh; ol[o] = ll;
      }
      asm volatile("s_waitcnt lgkmcnt(0)" ::: "memory");
    }
  }
}

// ---------------- conv3 (3x6, pad_h=1) + pool3 + relu via MFMA -------------
__global__ __launch_bounds__(256) void k_conv3m(
    const u16* __restrict__ ih, const u16* __restrict__ il,
    const u16* __restrict__ wh, const u16* __restrict__ wl,
    const float* __restrict__ b3, float* __restrict__ hout)
{
  __shared__ u16 sh[18*720];
  __shared__ u16 sl[18*720];
  __shared__ float dmp[48][132];
  const int tid = threadIdx.x;
  const int t0 = (blockIdx.x & 255) * 16;
  const int b = blockIdx.y;
  for (int i = tid; i < 1440; i += 256) {
    int cg = i & 7;
    int w = (i >> 3) % 10;
    int tt = i / 80;
    int t = t0 - 1 + tt;
    int dd = tt*720 + w*72 + cg*8;
    if (t >= 0 && t < T_) {
      size_t so = (size_t)((b*T_ + t)*10 + w)*64 + cg*8;
      *(ulonglong2*)&sh[dd] = *(const ulonglong2*)&ih[so];
      *(ulonglong2*)&sl[dd] = *(const ulonglong2*)&il[so];
    } else {
      ulonglong2 z; z.x = 0; z.y = 0;
      *(ulonglong2*)&sh[dd] = z;
      *(ulonglong2*)&sl[dd] = z;
    }
  }
  __syncthreads();
  const int lane = tid & 63;
  const int wid = tid >> 6;
  const int lr = lane & 15;
  const int lk8 = (lane >> 4) * 8;
  int tlm[3], wom[3];
  #pragma unroll
  for (int mf = 0; mf < 3; mf++) {
    int r = mf*16 + lr;
    tlm[mf] = r / 3;
    wom[mf] = r - tlm[mf]*3;
  }
  f32x4 acc[3][2] = {};
  #pragma unroll 2
  for (int kh = 0; kh < 3; kh++) {
    #pragma unroll
    for (int kw = 0; kw < 6; kw++) {
      #pragma unroll
      for (int chh = 0; chh < 2; chh++) {
        int s = (kh*6 + kw)*2 + chh;
        int ch = chh*32;
        bf16x8 bh[2], bl[2];
        #pragma unroll
        for (int nfl = 0; nfl < 2; nfl++) {
          int go = (((wid*2 + nfl)*36 + s) << 9) + (lane << 3);
          bh[nfl] = *(const bf16x8*)(wh + go);
          bl[nfl] = *(const bf16x8*)(wl + go);
        }
        #pragma unroll
        for (int mf = 0; mf < 3; mf++) {
          int lofs = (tlm[mf] + kh)*720 + (wom[mf] + kw)*72 + ch + lk8;
          bf16x8 ah = *(const bf16x8*)&sh[lofs];
          bf16x8 al = *(const bf16x8*)&sl[lofs];
          #pragma unroll
          for (int nfl = 0; nfl < 2; nfl++) {
            acc[mf][nfl] = MFMA(ah, bl[nfl], acc[mf][nfl]);
            acc[mf][nfl] = MFMA(al, bh[nfl], acc[mf][nfl]);
            acc[mf][nfl] = MFMA(ah, bh[nfl], acc[mf][nfl]);
          }
        }
      }
    }
  }
  const int lg = lane >> 4;
  #pragma unroll
  for (int mf = 0; mf < 3; mf++)
    #pragma unroll
    for (int r = 0; r < 4; r++) {
      int row = mf*16 + lg*4 + r;
      #pragma unroll
      for (int nfl = 0; nfl < 2; nfl++)
        dmp[row][wid*32 + nfl*16 + lr] = acc[mf][nfl][r];
    }
  __syncthreads();
  for (int i = tid; i < 2048; i += 256) {
    int c3 = i & 127;
    int tt = i >> 7;
    float v = fmaxf(fmaxf(dmp[tt*3][c3], dmp[tt*3+1][c3]), dmp[tt*3+2][c3]);
    v = fmaxf(v + b3[c3], 0.f);
    hout[(size_t)(b*T_ + t0 + tt)*128 + c3] = v;
  }
}

// ---------------- standalone LayerNorm (layer-0 LN1 only) ------------------
__device__ inline float wave_sum(float v) {
  #pragma unroll
  for (int m = 1; m < 64; m <<= 1) v += __shfl_xor(v, m, 64);
  return v;
}

__global__ __launch_bounds__(256) void k_ln(
    const float* __restrict__ in, const float* __restrict__ sc,
    const float* __restrict__ bi, u16* __restrict__ oh, u16* __restrict__ ol)
{
  const int lane = threadIdx.x & 63;
  const int row = blockIdx.x*4 + (threadIdx.x >> 6);
  float a = in[row*128 + lane];
  float c = in[row*128 + 64 + lane];
  float mean = wave_sum(a + c) * (1.f/128.f);
  float d0 = a - mean, d1 = c - mean;
  float var = wave_sum(d0*d0 + d1*d1) * (1.f/128.f);
  float rs = rsqrtf(var + 1e-5f);
  float v0 = d0*rs*sc[lane]    + bi[lane];
  float v1 = d1*rs*sc[64+lane] + bi[64+lane];
  u16 h0, l0, h1, l1;
  splitbf(v0, h0, l0); splitbf(v1, h1, l1);
  oh[row*128 + lane] = h0;      ol[row*128 + lane] = l0;
  oh[row*128 + 64 + lane] = h1; ol[row*128 + 64 + lane] = l1;
}

// ---------------- weight prep (single launch, block-uniform segments) ------
__device__ inline void prep_fr(const float* __restrict__ src,
                               u16* __restrict__ dh, u16* __restrict__ dl,
                               int K, int N, int matStride, int idx)
{
  int mat = idx / (K*N);
  int rem = idx - mat*(K*N);
  int k = rem / N;
  int n = rem - k*N;
  float v = src[idx];
  u16 h, l; splitbf(v, h, l);
  int nt = n >> 4, ks = k >> 5, ksub = k & 31;
  size_t o = (size_t)mat*matStride + (size_t)((nt*(K>>5) + ks) << 9)
           + (((ksub >> 3) << 4) + (n & 15))*8 + (ksub & 7);
  dh[o] = h; dl[o] = l;
}

__global__ __launch_bounds__(256) void k_wprep_all(
    const float* __restrict__ Wq, const float* __restrict__ Wk,
    const float* __restrict__ Wv, const float* __restrict__ Wo,
    const float* __restrict__ W1, const float* __restrict__ W2,
    const float* __restrict__ c2w, const float* __restrict__ c3w,
    u16* wqkv_h, u16* wqkv_l, u16* wo_h, u16* wo_l,
    u16* w1t_h, u16* w1t_l, u16* w2t_h, u16* w2t_l,
    u16* wc2_h, u16* wc2_l, u16* wc3_h, u16* wc3_l)
{
  const int bid = blockIdx.x;
  const int tid = threadIdx.x;
  if (bid < 576) {
    prep_fr(Wq, wqkv_h, wqkv_l, 128, 128, 49152, bid*256 + tid);
  } else if (bid < 1152) {
    prep_fr(Wk, wqkv_h + 16384, wqkv_l + 16384, 128, 128, 49152, (bid-576)*256 + tid);
  } else if (bid < 1728) {
    prep_fr(Wv, wqkv_h + 32768, wqkv_l + 32768, 128, 128, 49152, (bid-1152)*256 + tid);
  } else if (bid < 2304) {
    prep_fr(Wo, wo_h, wo_l, 128, 128, 16384, (bid-1728)*256 + tid);
  } else if (bid < 4608) {
    prep_fr(W1, w1t_h, w1t_l, 128, 512, 65536, (bid-2304)*256 + tid);
  } else if (bid < 6912) {
    prep_fr(W2, w2t_h, w2t_l, 512, 128, 65536, (bid-4608)*256 + tid);
  } else if (bid < 7008) {
    int idx = (bid-6912)*256 + tid;
    int c2 = idx / 384;
    int rem = idx - c2*384;
    int c1 = rem / 12;
    int kw = rem - c1*12;
    float v = c2w[idx];
    u16 h, l; splitbf(v, h, l);
    size_t o = (size_t)((((c2 >> 4)*12 + kw) << 9))
             + (((c1 >> 3) << 4) + (c2 & 15))*8 + (c1 & 7);
    wc2_h[o] = h; wc2_l[o] = l;
  } else {
    int idx = (bid-7008)*256 + tid;
    int c3 = idx / 1152;
    int rem = idx - c3*1152;
    int c2 = rem / 18;
    int khkw = rem - c2*18;
    float v = c3w[idx];
    u16 h, l; splitbf(v, h, l);
    int s = khkw*2 + (c2 >> 5);
    int c = c2 & 31;
    size_t o = (size_t)((((c3 >> 4)*36 + s) << 9))
             + (((c >> 3) << 4) + (c3 & 15))*8 + (c & 7);
    wc3_h[o] = h; wc3_l[o] = l;
  }
}

// ---------------- QKV GEMM: tile 16 x 128, grid (1024, 3) ------------------
__global__ __launch_bounds__(256) void k_gqkv(
    const u16* __restrict__ Ah, const u16* __restrict__ Al,
    const u16* __restrict__ Wh, const u16* __restrict__ Wl,
    const float* __restrict__ bq, const float* __restrict__ bk,
    const float* __restrict__ bv, float* __restrict__ outbase)
{
  __shared__ u16 sAh[16*136], sAl[16*136];
  const int tid = threadIdx.x;
  const int m0 = blockIdx.x * 16;
  const int z = blockIdx.y;
  const u16* wh = Wh + z*16384;
  const u16* wl = Wl + z*16384;
  const float* bias = (z == 0) ? bq : (z == 1) ? bk : bv;
  float* C = outbase + (size_t)z*2097152;
  {
    int row = tid >> 4, c8 = tid & 15;
    *(ulonglong2*)&sAh[row*136 + c8*8] = *(const ulonglong2*)&Ah[(size_t)(m0+row)*128 + c8*8];
    *(ulonglong2*)&sAl[row*136 + c8*8] = *(const ulonglong2*)&Al[(size_t)(m0+row)*128 + c8*8];
  }
  __syncthreads();
  const int lane = tid & 63, nq = tid >> 6;
  const int lr = lane & 15, lg = lane >> 4, l8 = lg*8;
  f32x4 acc[2] = {};
  #pragma unroll
  for (int ks = 0; ks < 4; ks++) {
    bf16x8 ah = *(const bf16x8*)&sAh[lr*136 + ks*32 + l8];
    bf16x8 al = *(const bf16x8*)&sAl[lr*136 + ks*32 + l8];
    #pragma unroll
    for (int nf = 0; nf < 2; nf++) {
      int go = (((nq*2 + nf)*4 + ks) << 9) + (lane << 3);
      bf16x8 bh = *(const bf16x8*)(wh + go);
      bf16x8 bl = *(const bf16x8*)(wl + go);
      acc[nf] = MFMA(ah, bl, acc[nf]);
      acc[nf] = MFMA(al, bh, acc[nf]);
      acc[nf] = MFMA(ah, bh, acc[nf]);
    }
  }
  #pragma unroll
  for (int nf = 0; nf < 2; nf++) {
    int col = nq*32 + nf*16 + lr;
    float bb = bias[col];
    #pragma unroll
    for (int r = 0; r < 4; r++)
      C[(size_t)(m0 + lg*4 + r)*128 + col] = acc[nf][r] + bb;
  }
}

// ------- fused attention + Wo GEMM + residual + skip-acc + LN2 -------------
__global__ __launch_bounds__(256) void k_attnwo(
    const float* __restrict__ qb, const float* __restrict__ kb,
    const float* __restrict__ vb, const float* __restrict__ Er,
    const u16* __restrict__ Wh, const u16* __restrict__ Wl,
    const float* __restrict__ bo, const float* __restrict__ sc,
    const float* __restrict__ bi,
    float* __restrict__ hbuf, float* __restrict__ ssum, int skip_init,
    u16* __restrict__ oh, u16* __restrict__ ol, int dil)
{
  __shared__ u16 sAh[16*136], sAl[16*136];
  __shared__ float dmp[16*132];
  const int tid = threadIdx.x, lane = tid & 63, wv = tid >> 6;
  const int m0 = blockIdx.x * 16;
  const int b = m0 >> 12;
  const int t0 = m0 & 4095;
  // ---- attention phase: wave wv owns rows wv*4 .. wv*4+3
  for (int rr = 0; rr < 4; rr++) {
    int r = wv*4 + rr;
    int t = t0 + r;
    int bt = m0 + r;
    #pragma unroll
    for (int h = 0; h < 2; h++) {
      float qd = qb[(size_t)bt*128 + h*64 + lane];
      float s[5];
      int tpc_arr[5];
      #pragma unroll
      for (int a = 0; a < 5; a++) {
        int tp = t + (a-2)*dil;
        bool valid = (tp >= 0 && tp < T_);
        int tpc = tp < 0 ? 0 : (tp > T_-1 ? T_-1 : tp);
        tpc_arr[a] = tpc;
        float kd = kb[(size_t)(b*T_ + tpc)*128 + h*64 + lane];
        float er = Er[(h*5 + a)*64 + lane];
        float p = qd * (kd + er);
        p = wave_sum(p);
        s[a] = valid ? p * 0.125f : -1e30f;
      }
      float mx = s[0];
      #pragma unroll
      for (int a = 1; a < 5; a++) mx = fmaxf(mx, s[a]);
      float p[5], psum = 0.f;
      #pragma unroll
      for (int a = 0; a < 5; a++) { p[a] = __expf(s[a]-mx); psum += p[a]; }
      float inv = 1.f/psum;
      float o = 0.f;
      #pragma unroll
      for (int a = 0; a < 5; a++)
        o += p[a] * vb[(size_t)(b*T_ + tpc_arr[a])*128 + h*64 + lane];
      float vo = o * inv;
      u16 hh, ll; splitbf(vo, hh, ll);
      sAh[r*136 + h*64 + lane] = hh;
      sAl[r*136 + h*64 + lane] = ll;
    }
  }
  __syncthreads();
  // ---- Wo GEMM phase
  const int lr = lane & 15, lg = lane >> 4, l8 = lg*8;
  const int nq = wv;
  f32x4 acc[2] = {};
  #pragma unroll
  for (int ks = 0; ks < 4; ks++) {
    bf16x8 ah = *(const bf16x8*)&sAh[lr*136 + ks*32 + l8];
    bf16x8 al = *(const bf16x8*)&sAl[lr*136 + ks*32 + l8];
    #pragma unroll
    for (int nf = 0; nf < 2; nf++) {
      int go = (((nq*2 + nf)*4 + ks) << 9) + (lane << 3);
      bf16x8 bh = *(const bf16x8*)(Wh + go);
      bf16x8 bl = *(const bf16x8*)(Wl + go);
      acc[nf] = MFMA(ah, bl, acc[nf]);
      acc[nf] = MFMA(al, bh, acc[nf]);
      acc[nf] = MFMA(ah, bh, acc[nf]);
    }
  }
  #pragma unroll
  for (int nf = 0; nf < 2; nf++) {
    int col = nq*32 + nf*16 + lr;
    float bb = bo[col];
    #pragma unroll
    for (int r = 0; r < 4; r++) {
      int row = lg*4 + r;
      size_t o = (size_t)(m0 + row)*128 + col;
      float val = acc[nf][r] + bb;
      if (skip_init) ssum[o] = val; else ssum[o] += val;
      float hn = hbuf[o] + val;
      hbuf[o] = hn;
      dmp[row*132 + col] = hn;
    }
  }
  __syncthreads();
  // ---- LN2 phase
  const int row = tid >> 4, p = tid & 15;
  float xv[8], s = 0.f;
  const float* dp = &dmp[row*132 + p*8];
  #pragma unroll
  for (int i = 0; i < 8; i++) { xv[i] = dp[i]; s += xv[i]; }
  s += __shfl_xor(s, 1); s += __shfl_xor(s, 2);
  s += __shfl_xor(s, 4); s += __shfl_xor(s, 8);
  float mean = s * (1.f/128.f);
  float v = 0.f;
  #pragma unroll
  for (int i = 0; i < 8; i++) { float d = xv[i]-mean; v += d*d; }
  v += __shfl_xor(v, 1); v += __shfl_xor(v, 2);
  v += __shfl_xor(v, 4); v += __shfl_xor(v, 8);
  float rs = rsqrtf(v*(1.f/128.f) + 1e-5f);
  size_t gro = (size_t)(m0 + row)*128;
  #pragma unroll
  for (int i = 0; i < 8; i++) {
    int c = p*8 + i;
    float y = (xv[i]-mean)*rs*sc[c] + bi[c];
    u16 hh, ll; splitbf(y, hh, ll);
    oh[gro + c] = hh; ol[gro + c] = ll;
  }
}

// ---------------- fused FFN: tile 16 rows, hid in LDS, grid 1024 -----------
__global__ __launch_bounds__(256) void k_ffn(
    const u16* __restrict__ Ah, const u16* __restrict__ Al,
    const u16* __restrict__ W1h, const u16* __restrict__ W1l,
    const float* __restrict__ b1,
    const u16* __restrict__ W2h, const u16* __restrict__ W2l,
    const float* __restrict__ b2,
    const float* __restrict__ sc, const float* __restrict__ bi, int do_ln,
    float* __restrict__ hbuf, u16* __restrict__ oh, u16* __restrict__ ol)
{
  __shared__ u16 sAh[16*136], sAl[16*136];
  __shared__ u16 hidH[2][16*136], hidL[2][16*136];
  __shared__ float dmp[16*132];
  const int tid = threadIdx.x;
  const int m0 = blockIdx.x * 16;
  {
    int row = tid >> 4, c8 = tid & 15;
    *(ulonglong2*)&sAh[row*136 + c8*8] = *(const ulonglong2*)&Ah[(size_t)(m0+row)*128 + c8*8];
    *(ulonglong2*)&sAl[row*136 + c8*8] = *(const ulonglong2*)&Al[(size_t)(m0+row)*128 + c8*8];
  }
  __syncthreads();
  const int lane = tid & 63, nq = tid >> 6;
  const int lr = lane & 15, lg = lane >> 4, l8 = lg*8;
  f32x4 acc2[2] = {};
  for (int c = 0; c < 4; c++) {
    f32x4 acc1[2] = {};
    #pragma unroll
    for (int ks = 0; ks < 4; ks++) {
      bf16x8 ah = *(const bf16x8*)&sAh[lr*136 + ks*32 + l8];
      bf16x8 al = *(const bf16x8*)&sAl[lr*136 + ks*32 + l8];
      #pragma unroll
      for (int nf = 0; nf < 2; nf++) {
        int go = (((c*8 + nq*2 + nf)*4 + ks) << 9) + (lane << 3);
        bf16x8 bh = *(const bf16x8*)(W1h + go);
        bf16x8 bl = *(const bf16x8*)(W1l + go);
        acc1[nf] = MFMA(ah, bl, acc1[nf]);
        acc1[nf] = MFMA(al, bh, acc1[nf]);
        acc1[nf] = MFMA(ah, bh, acc1[nf]);
      }
    }
    __syncthreads();
    #pragma unroll
    for (int nf = 0; nf < 2; nf++) {
      int col = nq*32 + nf*16 + lr;
      float bb = b1[c*128 + col];
      #pragma unroll
      for (int r = 0; r < 4; r++) {
        int row = lg*4 + r;
        float hv = fmaxf(acc1[nf][r] + bb, 0.f);
        u16 hh, ll; splitbf(hv, hh, ll);
        hidH[c & 1][row*136 + col] = hh;
        hidL[c & 1][row*136 + col] = ll;
      }
    }
    __syncthreads();
    #pragma unroll
    for (int ks = 0; ks < 4; ks++) {
      bf16x8 ah = *(const bf16x8*)&hidH[c & 1][lr*136 + ks*32 + l8];
      bf16x8 al = *(const bf16x8*)&hidL[c & 1][lr*136 + ks*32 + l8];
      #pragma unroll
      for (int nf = 0; nf < 2; nf++) {
        int go = (((nq*2 + nf)*16 + c*4 + ks) << 9) + (lane << 3);
        bf16x8 bh = *(const bf16x8*)(W2h + go);
        bf16x8 bl = *(const bf16x8*)(W2l + go);
        acc2[nf] = MFMA(ah, bl, acc2[nf]);
        acc2[nf] = MFMA(al, bh, acc2[nf]);
        acc2[nf] = MFMA(ah, bh, acc2[nf]);
      }
    }
  }
  #pragma unroll
  for (int nf = 0; nf < 2; nf++) {
    int col = nq*32 + nf*16 + lr;
    float bb = b2[col];
    #pragma unroll
    for (int r = 0; r < 4; r++) {
      int row = lg*4 + r;
      size_t o = (size_t)(m0 + row)*128 + col;
      float hn = hbuf[o] + acc2[nf][r] + bb;
      hbuf[o] = hn;
      dmp[row*132 + col] = hn;
    }
  }
  if (!do_ln) return;
  __syncthreads();
  const int row = tid >> 4, p = tid & 15;
  float xv[8], s = 0.f;
  const float* dp = &dmp[row*132 + p*8];
  #pragma unroll
  for (int i = 0; i < 8; i++) { xv[i] = dp[i]; s += xv[i]; }
  s += __shfl_xor(s, 1); s += __shfl_xor(s, 2);
  s += __shfl_xor(s, 4); s += __shfl_xor(s, 8);
  float mean = s * (1.f/128.f);
  float v = 0.f;
  #pragma unroll
  for (int i = 0; i < 8; i++) { float d = xv[i]-mean; v += d*d; }
  v += __shfl_xor(v, 1); v += __shfl_xor(v, 2);
  v += __shfl_xor(v, 4); v += __shfl_xor(v, 8);
  float rs = rsqrtf(v*(1.f/128.f) + 1e-5f);
  size_t gro = (size_t)(m0 + row)*128;
  #pragma unroll
  for (int i = 0; i < 8; i++) {
    int c2 = p*8 + i;
    float y = (xv[i]-mean)*rs*sc[c2] + bi[c2];
    u16 hh, ll; splitbf(y, hh, ll);
    oh[gro + c2] = hh; ol[gro + c2] = ll;
  }
}

// ---------------- tail kernels --------------------------------------------
__global__ __launch_bounds__(256) void k_out(
    const float* __restrict__ h, const float* __restrict__ Wout,
    const float* __restrict__ bout, float* __restrict__ out)
{
  int idx = blockIdx.x*256 + threadIdx.x;
  int bt = idx >> 1, j = idx & 1;
  float acc = bout[j];
  const float* hp = &h[bt*128];
  #pragma unroll 4
  for (int k2 = 0; k2 < 128; k2++)
    acc += fmaxf(hp[k2], 0.f) * Wout[k2*2 + j];
  out[idx] = acc;
}

__global__ __launch_bounds__(256) void k_red1(
    const float* __restrict__ ss, float* __restrict__ part)
{
  __shared__ float red[256];
  int b = blockIdx.x >> 5, g = blockIdx.x & 31;
  int c = threadIdx.x & 127, hf = threadIdx.x >> 7;
  float acc = 0.f;
  for (int i2 = 0; i2 < 64; i2++) {
    int t = g*128 + i2*2 + hf;
    acc += fmaxf(ss[(b*T_ + t)*128 + c], 0.f);
  }
  red[threadIdx.x] = acc;
  __syncthreads();
  if (threadIdx.x < 128)
    part[(b*32+g)*128 + threadIdx.x] = red[threadIdx.x] + red[threadIdx.x+128];
}

__global__ __launch_bounds__(512) void k_tail2(
    const float* __restrict__ part, const float* __restrict__ Wt,
    const float* __restrict__ btb, float* __restrict__ out)
{
  __shared__ float mb[512];
  const int tid = threadIdx.x;
  int b = tid >> 7, c = tid & 127;
  float s = 0.f;
  for (int g = 0; g < 32; g++) s += part[(b*32+g)*128 + c];
  mb[tid] = s * (1.f/4096.f);
  __syncthreads();
  for (int i = tid; i < 1200; i += 512) {
    int bb = i / 300, j = i - bb*300;
    float acc = btb[j];
    #pragma unroll 4
    for (int k2 = 0; k2 < 128; k2++)
      acc += mb[bb*128 + k2] * Wt[k2*300 + j];
    out[32768 + i] = acc;
  }
}

// ---------------- launcher -------------------------------------------------
extern "C" void kernel_launch(void* const* d_in, const int* in_sizes, int n_in,
                              void* d_out, int out_size, void* d_ws, size_t ws_size,
                              hipStream_t stream)
{
  const float* x    = (const float*)d_in[0];
  const float* c1w  = (const float*)d_in[1];
  const float* c1b  = (const float*)d_in[2];
  const float* c2w  = (const float*)d_in[3];
  const float* c2b  = (const float*)d_in[4];
  const float* c3w  = (const float*)d_in[5];
  const float* c3b  = (const float*)d_in[6];
  const float* ln1s = (const float*)d_in[7];
  const float* ln1b = (const float*)d_in[8];
  const float* ln2s = (const float*)d_in[9];
  const float* ln2b = (const float*)d_in[10];
  const float* Wq   = (const float*)d_in[11];
  const float* bq   = (const float*)d_in[12];
  const float* Wk   = (const float*)d_in[13];
  const float* bk   = (const float*)d_in[14];
  const float* Wv   = (const float*)d_in[15];
  const float* bv   = (const float*)d_in[16];
  const float* Wo   = (const float*)d_in[17];
  const float* bo   = (const float*)d_in[18];
  const float* Er   = (const float*)d_in[19];
  const float* W1   = (const float*)d_in[20];
  const float* b1   = (const float*)d_in[21];
  const float* W2   = (const float*)d_in[22];
  const float* b2   = (const float*)d_in[23];
  const float* Wout = (const float*)d_in[24];
  const float* bout = (const float*)d_in[25];
  const float* Wt   = (const float*)d_in[26];
  const float* bt   = (const float*)d_in[27];

  char* W = (char*)d_ws;
  // conv region (0 .. 42 MB): full-batch c2out hi/lo (transient)
  u16* c2o_h = (u16*)W;
  u16* c2o_l = (u16*)(W + 20971520);
  // region B (33.5 .. 67 MB): qkv + x planes (used after convs complete)
  char* RB = W + 33554432;
  float* qb  = (float*)RB;
  float* kb  = qb + 2097152;
  float* vb2 = qb + 4194304;
  u16* xh    = (u16*)(RB + 25165824);
  u16* xlo   = (u16*)(RB + 29360128);
  // region C (67 MB ..): persistent
  char* RC = W + 67108864;
  float* hbuf = (float*)RC;
  float* ssum = (float*)(RC + 8388608);
  u16* wqkv_h = (u16*)(RC + 16777216);
  u16* wqkv_l = wqkv_h + 442368;
  u16* wo_h   = wqkv_l + 442368;
  u16* wo_l   = wo_h + 147456;
  u16* w1t_h  = wo_l + 147456;
  u16* w1t_l  = w1t_h + 589824;
  u16* w2t_h  = w1t_l + 589824;
  u16* w2t_l  = w2t_h + 589824;
  u16* wc2_h  = w2t_l + 589824;
  u16* wc2_l  = wc2_h + 24576;
  u16* wc3_h  = wc2_l + 24576;
  u16* wc3_l  = wc3_h + 147456;
  float* part  = (float*)(wc3_l + 147456);
  float* meanb = part + 16384;
  float* outf  = (float*)d_out;
  (void)meanb;

  // one-launch weight prep
  k_wprep_all<<<7584, 256, 0, stream>>>(
      Wq, Wk, Wv, Wo, W1, W2, c2w, c3w,
      wqkv_h, wqkv_l, wo_h, wo_l, w1t_h, w1t_l, w2t_h, w2t_l,
      wc2_h, wc2_l, wc3_h, wc3_l);

  // conv frontend, full batch
  k_conv12m<<<dim3(512, B_), 256, 0, stream>>>(x, c1w, c1b, wc2_h, wc2_l, c2b,
                                               c2o_h, c2o_l);
  k_conv3m<<<dim3(256, B_), 256, 0, stream>>>(c2o_h, c2o_l, wc3_h, wc3_l, c3b, hbuf);

  // layer-0 LN1
  k_ln<<<4096, 256, 0, stream>>>(hbuf, ln1s, ln1b, xh, xlo);

  for (int l = 0; l < 9; l++) {
    k_gqkv<<<dim3(1024, 3), 256, 0, stream>>>(
        xh, xlo, wqkv_h + l*49152, wqkv_l + l*49152,
        bq + l*128, bk + l*128, bv + l*128, qb);
    k_attnwo<<<1024, 256, 0, stream>>>(
        qb, kb, vb2, Er + l*640,
        wo_h + l*16384, wo_l + l*16384, bo + l*128,
        ln2s + l*128, ln2b + l*128,
        hbuf, ssum, (l == 0) ? 1 : 0, xh, xlo, 1 << l);
    k_ffn<<<1024, 256, 0, stream>>>(
        xh, xlo, w1t_h + l*65536, w1t_l + l*65536, b1 + l*512,
        w2t_h + l*65536, w2t_l + l*65536, b2 + l*128,
        ln1s + (l+1 < 9 ? (l+1)*128 : 0), ln1b + (l+1 < 9 ? (l+1)*128 : 0),
        (l < 8) ? 1 : 0,
        hbuf, xh, xlo);
  }

  k_out<<<128, 256, 0, stream>>>(hbuf, Wout, bout, outf);
  k_red1<<<128, 256, 0, stream>>>(ssum, part);
  k_tail2<<<1, 512, 0, stream>>>(part, Wt, bt, outf);
}

// Round 7
// 712.574 us; speedup vs baseline: 3.1989x; 1.0719x over previous
//
#include <hip/hip_runtime.h>

#define T_ 4096
#define B_ 4

typedef unsigned short u16;
typedef __bf16 bf16x8 __attribute__((ext_vector_type(8)));
typedef float f32x4 __attribute__((ext_vector_type(4)));

__device__ inline void splitbf(float v, u16& h, u16& l) {
  __bf16 hb = (__bf16)v;
  float r = v - (float)hb;
  __bf16 lb = (__bf16)r;
  h = __builtin_bit_cast(u16, hb);
  l = __builtin_bit_cast(u16, lb);
}

#define MFMA(a,b,c) __builtin_amdgcn_mfma_f32_16x16x32_bf16((a),(b),(c),0,0,0)

// ---------------- fused conv1(5x3,pad2)+pool3+relu + conv2(1x12)+pool3+relu
__global__ __launch_bounds__(256) void k_conv12m(
    const float* __restrict__ x, const float* __restrict__ w1,
    const float* __restrict__ b1,
    const u16* __restrict__ wh, const u16* __restrict__ wl,
    const float* __restrict__ b2,
    u16* __restrict__ oh, u16* __restrict__ ol)
{
  __shared__ float sx[12][130];
  __shared__ float w1s[480];
  __shared__ float b1s[32];
  __shared__ u16 sh[8*43*40];
  __shared__ u16 sl[8*43*40];
  __shared__ float dmp[4][15][66];
  const int tid = threadIdx.x;
  const int t0 = blockIdx.x * 8;
  const int b = blockIdx.y;
  const float* xb = x + (size_t)b*T_*128;
  for (int i = tid; i < 1536; i += 256) {
    int r = i >> 7, c = i & 127;
    int t = t0 - 2 + r;
    sx[r][c] = (t >= 0 && t < T_) ? xb[t*128 + c] : 0.f;
  }
  for (int i = tid; i < 480; i += 256) w1s[i] = w1[i];
  if (tid < 32) b1s[tid] = b1[tid];
  for (int i = tid; i < 320; i += 256) {
    int tt = i / 40, c = i - tt*40;
    sh[(tt*43 + 42)*40 + c] = 0;
    sl[(tt*43 + 42)*40 + c] = 0;
  }
  __syncthreads();
  for (int i = tid; i < 10752; i += 256) {
    int c1 = i & 31;
    int wp = (i >> 5) % 42;
    int tt = i / 1344;
    float m = -1e30f;
    #pragma unroll
    for (int j = 0; j < 3; j++) {
      float acc = 0.f;
      int wb = wp*3 + j;
      #pragma unroll
      for (int kh = 0; kh < 5; kh++)
        #pragma unroll
        for (int kw = 0; kw < 3; kw++)
          acc += sx[tt+kh][wb+kw] * w1s[c1*15 + kh*3 + kw];
      m = fmaxf(m, acc);
    }
    float v = fmaxf(m + b1s[c1], 0.f);
    u16 hh, ll; splitbf(v, hh, ll);
    int dd = (tt*43 + wp)*40 + c1;
    sh[dd] = hh; sl[dd] = ll;
  }
  __syncthreads();
  const int lane = tid & 63;
  const int wid = tid >> 6;
  const int lr = lane & 15;
  const int lk8 = (lane >> 4) * 8;
  f32x4 acc[2][2][4] = {};
  #pragma unroll 3
  for (int kw = 0; kw < 12; kw++) {
    bf16x8 bh[4], bl[4];
    #pragma unroll
    for (int nf = 0; nf < 4; nf++) {
      int go = ((nf*12 + kw) << 9) + (lane << 3);
      bh[nf] = *(const bf16x8*)(wh + go);
      bl[nf] = *(const bf16x8*)(wl + go);
    }
    #pragma unroll
    for (int tp = 0; tp < 2; tp++) {
      int tloc = wid*2 + tp;
      #pragma unroll
      for (int mf = 0; mf < 2; mf++) {
        int lofs = (tloc*43 + mf*16 + lr + kw)*40 + lk8;
        bf16x8 ah = *(const bf16x8*)&sh[lofs];
        bf16x8 al = *(const bf16x8*)&sl[lofs];
        #pragma unroll
        for (int nf = 0; nf < 4; nf++) {
          acc[tp][mf][nf] = MFMA(ah, bl[nf], acc[tp][mf][nf]);
          acc[tp][mf][nf] = MFMA(al, bh[nf], acc[tp][mf][nf]);
          acc[tp][mf][nf] = MFMA(ah, bh[nf], acc[tp][mf][nf]);
        }
      }
    }
  }
  const int lg = lane >> 4;
  for (int tp = 0; tp < 2; tp++) {
    int t = t0 + wid*2 + tp;
    for (int half = 0; half < 2; half++) {
      #pragma unroll
      for (int mf = 0; mf < 2; mf++)
        #pragma unroll
        for (int r = 0; r < 4; r++) {
          int grow = mf*16 + lg*4 + r;
          int lrow = grow - half*15;
          if (lrow >= 0 && lrow < 15) {
            #pragma unroll
            for (int nf = 0; nf < 4; nf++)
              dmp[wid][lrow][nf*16 + lr] = acc[tp][mf][nf][r];
          }
        }
      asm volatile("s_waitcnt lgkmcnt(0)" ::: "memory");
      #pragma unroll
      for (int it = 0; it < 5; it++) {
        float v = fmaxf(fmaxf(dmp[wid][it*3][lane], dmp[wid][it*3+1][lane]),
                        dmp[wid][it*3+2][lane]);
        v = fmaxf(v + b2[lane], 0.f);
        u16 hh, ll; splitbf(v, hh, ll);
        size_t o = (size_t)((b*T_ + t)*10 + half*5 + it)*64 + lane;
        oh[o] = hh; ol[o] = ll;
      }
      asm volatile("s_waitcnt lgkmcnt(0)" ::: "memory");
    }
  }
}

// ---------------- conv3 (3x6, pad_h=1) + pool3 + relu via MFMA -------------
__global__ __launch_bounds__(256) void k_conv3m(
    const u16* __restrict__ ih, const u16* __restrict__ il,
    const u16* __restrict__ wh, const u16* __restrict__ wl,
    const float* __restrict__ b3, float* __restrict__ hout)
{
  __shared__ u16 sh[18*720];
  __shared__ u16 sl[18*720];
  __shared__ float dmp[48][132];
  const int tid = threadIdx.x;
  const int t0 = (blockIdx.x & 255) * 16;
  const int b = blockIdx.y;
  for (int i = tid; i < 1440; i += 256) {
    int cg = i & 7;
    int w = (i >> 3) % 10;
    int tt = i / 80;
    int t = t0 - 1 + tt;
    int dd = tt*720 + w*72 + cg*8;
    if (t >= 0 && t < T_) {
      size_t so = (size_t)((b*T_ + t)*10 + w)*64 + cg*8;
      *(ulonglong2*)&sh[dd] = *(const ulonglong2*)&ih[so];
      *(ulonglong2*)&sl[dd] = *(const ulonglong2*)&il[so];
    } else {
      ulonglong2 z; z.x = 0; z.y = 0;
      *(ulonglong2*)&sh[dd] = z;
      *(ulonglong2*)&sl[dd] = z;
    }
  }
  __syncthreads();
  const int lane = tid & 63;
  const int wid = tid >> 6;
  const int lr = lane & 15;
  const int lk8 = (lane >> 4) * 8;
  int tlm[3], wom[3];
  #pragma unroll
  for (int mf = 0; mf < 3; mf++) {
    int r = mf*16 + lr;
    tlm[mf] = r / 3;
    wom[mf] = r - tlm[mf]*3;
  }
  f32x4 acc[3][2] = {};
  #pragma unroll 2
  for (int kh = 0; kh < 3; kh++) {
    #pragma unroll
    for (int kw = 0; kw < 6; kw++) {
      #pragma unroll
      for (int chh = 0; chh < 2; chh++) {
        int s = (kh*6 + kw)*2 + chh;
        int ch = chh*32;
        bf16x8 bh[2], bl[2];
        #pragma unroll
        for (int nfl = 0; nfl < 2; nfl++) {
          int go = (((wid*2 + nfl)*36 + s) << 9) + (lane << 3);
          bh[nfl] = *(const bf16x8*)(wh + go);
          bl[nfl] = *(const bf16x8*)(wl + go);
        }
        #pragma unroll
        for (int mf = 0; mf < 3; mf++) {
          int lofs = (tlm[mf] + kh)*720 + (wom[mf] + kw)*72 + ch + lk8;
          bf16x8 ah = *(const bf16x8*)&sh[lofs];
          bf16x8 al = *(const bf16x8*)&sl[lofs];
          #pragma unroll
          for (int nfl = 0; nfl < 2; nfl++) {
            acc[mf][nfl] = MFMA(ah, bl[nfl], acc[mf][nfl]);
            acc[mf][nfl] = MFMA(al, bh[nfl], acc[mf][nfl]);
            acc[mf][nfl] = MFMA(ah, bh[nfl], acc[mf][nfl]);
          }
        }
      }
    }
  }
  const int lg = lane >> 4;
  #pragma unroll
  for (int mf = 0; mf < 3; mf++)
    #pragma unroll
    for (int r = 0; r < 4; r++) {
      int row = mf*16 + lg*4 + r;
      #pragma unroll
      for (int nfl = 0; nfl < 2; nfl++)
        dmp[row][wid*32 + nfl*16 + lr] = acc[mf][nfl][r];
    }
  __syncthreads();
  for (int i = tid; i < 2048; i += 256) {
    int c3 = i & 127;
    int tt = i >> 7;
    float v = fmaxf(fmaxf(dmp[tt*3][c3], dmp[tt*3+1][c3]), dmp[tt*3+2][c3]);
    v = fmaxf(v + b3[c3], 0.f);
    hout[(size_t)(b*T_ + t0 + tt)*128 + c3] = v;
  }
}

// ---------------- standalone LayerNorm (layer-0 LN1 only) ------------------
__device__ inline float wave_sum(float v) {
  #pragma unroll
  for (int m = 1; m < 64; m <<= 1) v += __shfl_xor(v, m, 64);
  return v;
}

__global__ __launch_bounds__(256) void k_ln(
    const float* __restrict__ in, const float* __restrict__ sc,
    const float* __restrict__ bi, u16* __restrict__ oh, u16* __restrict__ ol)
{
  const int lane = threadIdx.x & 63;
  const int row = blockIdx.x*4 + (threadIdx.x >> 6);
  float a = in[row*128 + lane];
  float c = in[row*128 + 64 + lane];
  float mean = wave_sum(a + c) * (1.f/128.f);
  float d0 = a - mean, d1 = c - mean;
  float var = wave_sum(d0*d0 + d1*d1) * (1.f/128.f);
  float rs = rsqrtf(var + 1e-5f);
  float v0 = d0*rs*sc[lane]    + bi[lane];
  float v1 = d1*rs*sc[64+lane] + bi[64+lane];
  u16 h0, l0, h1, l1;
  splitbf(v0, h0, l0); splitbf(v1, h1, l1);
  oh[row*128 + lane] = h0;      ol[row*128 + lane] = l0;
  oh[row*128 + 64 + lane] = h1; ol[row*128 + 64 + lane] = l1;
}

// ---------------- weight prep (single launch, block-uniform segments) ------
__device__ inline void prep_fr(const float* __restrict__ src,
                               u16* __restrict__ dh, u16* __restrict__ dl,
                               int K, int N, int matStride, int idx)
{
  int mat = idx / (K*N);
  int rem = idx - mat*(K*N);
  int k = rem / N;
  int n = rem - k*N;
  float v = src[idx];
  u16 h, l; splitbf(v, h, l);
  int nt = n >> 4, ks = k >> 5, ksub = k & 31;
  size_t o = (size_t)mat*matStride + (size_t)((nt*(K>>5) + ks) << 9)
           + (((ksub >> 3) << 4) + (n & 15))*8 + (ksub & 7);
  dh[o] = h; dl[o] = l;
}

__global__ __launch_bounds__(256) void k_wprep_all(
    const float* __restrict__ Wq, const float* __restrict__ Wk,
    const float* __restrict__ Wv, const float* __restrict__ Wo,
    const float* __restrict__ W1, const float* __restrict__ W2,
    const float* __restrict__ c2w, const float* __restrict__ c3w,
    u16* wqkv_h, u16* wqkv_l, u16* wo_h, u16* wo_l,
    u16* w1t_h, u16* w1t_l, u16* w2t_h, u16* w2t_l,
    u16* wc2_h, u16* wc2_l, u16* wc3_h, u16* wc3_l)
{
  const int bid = blockIdx.x;
  const int tid = threadIdx.x;
  if (bid < 576) {
    prep_fr(Wq, wqkv_h, wqkv_l, 128, 128, 49152, bid*256 + tid);
  } else if (bid < 1152) {
    prep_fr(Wk, wqkv_h + 16384, wqkv_l + 16384, 128, 128, 49152, (bid-576)*256 + tid);
  } else if (bid < 1728) {
    prep_fr(Wv, wqkv_h + 32768, wqkv_l + 32768, 128, 128, 49152, (bid-1152)*256 + tid);
  } else if (bid < 2304) {
    prep_fr(Wo, wo_h, wo_l, 128, 128, 16384, (bid-1728)*256 + tid);
  } else if (bid < 4608) {
    prep_fr(W1, w1t_h, w1t_l, 128, 512, 65536, (bid-2304)*256 + tid);
  } else if (bid < 6912) {
    prep_fr(W2, w2t_h, w2t_l, 512, 128, 65536, (bid-4608)*256 + tid);
  } else if (bid < 7008) {
    int idx = (bid-6912)*256 + tid;
    int c2 = idx / 384;
    int rem = idx - c2*384;
    int c1 = rem / 12;
    int kw = rem - c1*12;
    float v = c2w[idx];
    u16 h, l; splitbf(v, h, l);
    size_t o = (size_t)((((c2 >> 4)*12 + kw) << 9))
             + (((c1 >> 3) << 4) + (c2 & 15))*8 + (c1 & 7);
    wc2_h[o] = h; wc2_l[o] = l;
  } else {
    int idx = (bid-7008)*256 + tid;
    int c3 = idx / 1152;
    int rem = idx - c3*1152;
    int c2 = rem / 18;
    int khkw = rem - c2*18;
    float v = c3w[idx];
    u16 h, l; splitbf(v, h, l);
    int s = khkw*2 + (c2 >> 5);
    int c = c2 & 31;
    size_t o = (size_t)((((c3 >> 4)*36 + s) << 9))
             + (((c >> 3) << 4) + (c3 & 15))*8 + (c & 7);
    wc3_h[o] = h; wc3_l[o] = l;
  }
}

// ---------------- QKV GEMM (layer 0 only): tile 16 x 128 -------------------
__global__ __launch_bounds__(256) void k_gqkv(
    const u16* __restrict__ Ah, const u16* __restrict__ Al,
    const u16* __restrict__ Wh, const u16* __restrict__ Wl,
    const float* __restrict__ bq, const float* __restrict__ bk,
    const float* __restrict__ bv, float* __restrict__ outbase)
{
  __shared__ u16 sAh[16*136], sAl[16*136];
  const int tid = threadIdx.x;
  const int m0 = blockIdx.x * 16;
  const int z = blockIdx.y;
  const u16* wh = Wh + z*16384;
  const u16* wl = Wl + z*16384;
  const float* bias = (z == 0) ? bq : (z == 1) ? bk : bv;
  float* C = outbase + (size_t)z*2097152;
  {
    int row = tid >> 4, c8 = tid & 15;
    *(ulonglong2*)&sAh[row*136 + c8*8] = *(const ulonglong2*)&Ah[(size_t)(m0+row)*128 + c8*8];
    *(ulonglong2*)&sAl[row*136 + c8*8] = *(const ulonglong2*)&Al[(size_t)(m0+row)*128 + c8*8];
  }
  __syncthreads();
  const int lane = tid & 63, nq = tid >> 6;
  const int lr = lane & 15, lg = lane >> 4, l8 = lg*8;
  f32x4 acc[2] = {};
  #pragma unroll
  for (int ks = 0; ks < 4; ks++) {
    bf16x8 ah = *(const bf16x8*)&sAh[lr*136 + ks*32 + l8];
    bf16x8 al = *(const bf16x8*)&sAl[lr*136 + ks*32 + l8];
    #pragma unroll
    for (int nf = 0; nf < 2; nf++) {
      int go = (((nq*2 + nf)*4 + ks) << 9) + (lane << 3);
      bf16x8 bh = *(const bf16x8*)(wh + go);
      bf16x8 bl = *(const bf16x8*)(wl + go);
      acc[nf] = MFMA(ah, bl, acc[nf]);
      acc[nf] = MFMA(al, bh, acc[nf]);
      acc[nf] = MFMA(ah, bh, acc[nf]);
    }
  }
  #pragma unroll
  for (int nf = 0; nf < 2; nf++) {
    int col = nq*32 + nf*16 + lr;
    float bb = bias[col];
    #pragma unroll
    for (int r = 0; r < 4; r++)
      C[(size_t)(m0 + lg*4 + r)*128 + col] = acc[nf][r] + bb;
  }
}

// ------- fused attention + Wo GEMM + residual + skip-acc + LN2 (M=32) ------
__global__ __launch_bounds__(512) void k_attnwo(
    const float* __restrict__ qb, const float* __restrict__ kb,
    const float* __restrict__ vb, const float* __restrict__ Er,
    const u16* __restrict__ Wh, const u16* __restrict__ Wl,
    const float* __restrict__ bo, const float* __restrict__ sc,
    const float* __restrict__ bi,
    float* __restrict__ hbuf, float* __restrict__ ssum, int skip_init,
    u16* __restrict__ oh, u16* __restrict__ ol, int dil)
{
  __shared__ u16 sAh[32*136], sAl[32*136];
  __shared__ float dmp[32*132];
  const int tid = threadIdx.x, lane = tid & 63, wv = tid >> 6;
  const int m0 = blockIdx.x * 32;
  const int b = m0 >> 12;
  const int t0 = m0 & 4095;
  // ---- attention: 8 waves x 4 rows
  for (int rr = 0; rr < 4; rr++) {
    int r = wv*4 + rr;
    int t = t0 + r;
    int bt = m0 + r;
    #pragma unroll
    for (int h = 0; h < 2; h++) {
      float qd = qb[(size_t)bt*128 + h*64 + lane];
      float s[5];
      int tpc_arr[5];
      #pragma unroll
      for (int a = 0; a < 5; a++) {
        int tp = t + (a-2)*dil;
        bool valid = (tp >= 0 && tp < T_);
        int tpc = tp < 0 ? 0 : (tp > T_-1 ? T_-1 : tp);
        tpc_arr[a] = tpc;
        float kd = kb[(size_t)(b*T_ + tpc)*128 + h*64 + lane];
        float er = Er[(h*5 + a)*64 + lane];
        float p = qd * (kd + er);
        p = wave_sum(p);
        s[a] = valid ? p * 0.125f : -1e30f;
      }
      float mx = s[0];
      #pragma unroll
      for (int a = 1; a < 5; a++) mx = fmaxf(mx, s[a]);
      float p[5], psum = 0.f;
      #pragma unroll
      for (int a = 0; a < 5; a++) { p[a] = __expf(s[a]-mx); psum += p[a]; }
      float inv = 1.f/psum;
      float o = 0.f;
      #pragma unroll
      for (int a = 0; a < 5; a++)
        o += p[a] * vb[(size_t)(b*T_ + tpc_arr[a])*128 + h*64 + lane];
      float vo = o * inv;
      u16 hh, ll; splitbf(vo, hh, ll);
      sAh[r*136 + h*64 + lane] = hh;
      sAl[r*136 + h*64 + lane] = ll;
    }
  }
  __syncthreads();
  // ---- Wo GEMM: waves (mq = wv>>2, nq = wv&3)
  const int lr = lane & 15, lg = lane >> 4, l8 = lg*8;
  const int mq = wv >> 2, nq = wv & 3;
  f32x4 acc[2] = {};
  #pragma unroll
  for (int ks = 0; ks < 4; ks++) {
    bf16x8 ah = *(const bf16x8*)&sAh[(mq*16 + lr)*136 + ks*32 + l8];
    bf16x8 al = *(const bf16x8*)&sAl[(mq*16 + lr)*136 + ks*32 + l8];
    #pragma unroll
    for (int nf = 0; nf < 2; nf++) {
      int go = (((nq*2 + nf)*4 + ks) << 9) + (lane << 3);
      bf16x8 bh = *(const bf16x8*)(Wh + go);
      bf16x8 bl = *(const bf16x8*)(Wl + go);
      acc[nf] = MFMA(ah, bl, acc[nf]);
      acc[nf] = MFMA(al, bh, acc[nf]);
      acc[nf] = MFMA(ah, bh, acc[nf]);
    }
  }
  #pragma unroll
  for (int nf = 0; nf < 2; nf++) {
    int col = nq*32 + nf*16 + lr;
    float bb = bo[col];
    #pragma unroll
    for (int r = 0; r < 4; r++) {
      int row = mq*16 + lg*4 + r;
      size_t o = (size_t)(m0 + row)*128 + col;
      float val = acc[nf][r] + bb;
      if (skip_init) ssum[o] = val; else ssum[o] += val;
      float hn = hbuf[o] + val;
      hbuf[o] = hn;
      dmp[row*132 + col] = hn;
    }
  }
  __syncthreads();
  // ---- LN2: 512 thr, 32 rows x 16 threads
  const int row = tid >> 4, p = tid & 15;
  float xv[8], s = 0.f;
  const float* dp = &dmp[row*132 + p*8];
  #pragma unroll
  for (int i = 0; i < 8; i++) { xv[i] = dp[i]; s += xv[i]; }
  s += __shfl_xor(s, 1); s += __shfl_xor(s, 2);
  s += __shfl_xor(s, 4); s += __shfl_xor(s, 8);
  float mean = s * (1.f/128.f);
  float v = 0.f;
  #pragma unroll
  for (int i = 0; i < 8; i++) { float d = xv[i]-mean; v += d*d; }
  v += __shfl_xor(v, 1); v += __shfl_xor(v, 2);
  v += __shfl_xor(v, 4); v += __shfl_xor(v, 8);
  float rs = rsqrtf(v*(1.f/128.f) + 1e-5f);
  size_t gro = (size_t)(m0 + row)*128;
  #pragma unroll
  for (int i = 0; i < 8; i++) {
    int c = p*8 + i;
    float y = (xv[i]-mean)*rs*sc[c] + bi[c];
    u16 hh, ll; splitbf(y, hh, ll);
    oh[gro + c] = hh; ol[gro + c] = ll;
  }
}

// ------- fused FFN + residual + LN1(next) + QKV(next), M=32, 512 thr -------
__global__ __launch_bounds__(512) void k_ffnqkv(
    const u16* __restrict__ Ah, const u16* __restrict__ Al,
    const u16* __restrict__ W1h, const u16* __restrict__ W1l,
    const float* __restrict__ b1,
    const u16* __restrict__ W2h, const u16* __restrict__ W2l,
    const float* __restrict__ b2,
    float* __restrict__ hbuf, int do_qkv,
    const float* __restrict__ sc, const float* __restrict__ bi,
    const u16* __restrict__ Qh, const u16* __restrict__ Ql,
    const float* __restrict__ bq, const float* __restrict__ bk,
    const float* __restrict__ bv, float* __restrict__ qkvout)
{
  __shared__ u16 sAh[32*136], sAl[32*136];
  __shared__ u16 hidH[2][32*136], hidL[2][32*136];
  __shared__ float dmp[32*132];
  const int tid = threadIdx.x, lane = tid & 63;
  const int m0 = blockIdx.x * 32;
  {
    int row = tid >> 4, c8 = tid & 15;
    *(ulonglong2*)&sAh[row*136 + c8*8] = *(const ulonglong2*)&Ah[(size_t)(m0+row)*128 + c8*8];
    *(ulonglong2*)&sAl[row*136 + c8*8] = *(const ulonglong2*)&Al[(size_t)(m0+row)*128 + c8*8];
  }
  __syncthreads();
  const int wv = tid >> 6, mq = wv >> 2, nq = wv & 3;
  const int lr = lane & 15, lg = lane >> 4, l8 = lg*8;
  f32x4 acc2[2] = {};
  for (int c = 0; c < 4; c++) {
    f32x4 acc1[2] = {};
    #pragma unroll
    for (int ks = 0; ks < 4; ks++) {
      bf16x8 ah = *(const bf16x8*)&sAh[(mq*16 + lr)*136 + ks*32 + l8];
      bf16x8 al = *(const bf16x8*)&sAl[(mq*16 + lr)*136 + ks*32 + l8];
      #pragma unroll
      for (int nf = 0; nf < 2; nf++) {
        int go = (((c*8 + nq*2 + nf)*4 + ks) << 9) + (lane << 3);
        bf16x8 bh = *(const bf16x8*)(W1h + go);
        bf16x8 bl = *(const bf16x8*)(W1l + go);
        acc1[nf] = MFMA(ah, bl, acc1[nf]);
        acc1[nf] = MFMA(al, bh, acc1[nf]);
        acc1[nf] = MFMA(ah, bh, acc1[nf]);
      }
    }
    __syncthreads();
    #pragma unroll
    for (int nf = 0; nf < 2; nf++) {
      int col = nq*32 + nf*16 + lr;
      float bb = b1[c*128 + col];
      #pragma unroll
      for (int r = 0; r < 4; r++) {
        int row = mq*16 + lg*4 + r;
        float hv = fmaxf(acc1[nf][r] + bb, 0.f);
        u16 hh, ll; splitbf(hv, hh, ll);
        hidH[c & 1][row*136 + col] = hh;
        hidL[c & 1][row*136 + col] = ll;
      }
    }
    __syncthreads();
    #pragma unroll
    for (int ks = 0; ks < 4; ks++) {
      bf16x8 ah = *(const bf16x8*)&hidH[c & 1][(mq*16 + lr)*136 + ks*32 + l8];
      bf16x8 al = *(const bf16x8*)&hidL[c & 1][(mq*16 + lr)*136 + ks*32 + l8];
      #pragma unroll
      for (int nf = 0; nf < 2; nf++) {
        int go = (((nq*2 + nf)*16 + c*4 + ks) << 9) + (lane << 3);
        bf16x8 bh = *(const bf16x8*)(W2h + go);
        bf16x8 bl = *(const bf16x8*)(W2l + go);
        acc2[nf] = MFMA(ah, bl, acc2[nf]);
        acc2[nf] = MFMA(al, bh, acc2[nf]);
        acc2[nf] = MFMA(ah, bh, acc2[nf]);
      }
    }
  }
  #pragma unroll
  for (int nf = 0; nf < 2; nf++) {
    int col = nq*32 + nf*16 + lr;
    float bb = b2[col];
    #pragma unroll
    for (int r = 0; r < 4; r++) {
      int row = mq*16 + lg*4 + r;
      size_t o = (size_t)(m0 + row)*128 + col;
      float hn = hbuf[o] + acc2[nf][r] + bb;
      hbuf[o] = hn;
      dmp[row*132 + col] = hn;
    }
  }
  if (!do_qkv) return;
  __syncthreads();
  // ---- LN1(next) -> back into sA (in LDS only)
  {
    const int row = tid >> 4, p = tid & 15;
    float xv[8], s = 0.f;
    const float* dp = &dmp[row*132 + p*8];
    #pragma unroll
    for (int i = 0; i < 8; i++) { xv[i] = dp[i]; s += xv[i]; }
    s += __shfl_xor(s, 1); s += __shfl_xor(s, 2);
    s += __shfl_xor(s, 4); s += __shfl_xor(s, 8);
    float mean = s * (1.f/128.f);
    float v = 0.f;
    #pragma unroll
    for (int i = 0; i < 8; i++) { float d = xv[i]-mean; v += d*d; }
    v += __shfl_xor(v, 1); v += __shfl_xor(v, 2);
    v += __shfl_xor(v, 4); v += __shfl_xor(v, 8);
    float rs = rsqrtf(v*(1.f/128.f) + 1e-5f);
    #pragma unroll
    for (int i = 0; i < 8; i++) {
      int cc = p*8 + i;
      float y = (xv[i]-mean)*rs*sc[cc] + bi[cc];
      u16 hh, ll; splitbf(y, hh, ll);
      sAh[row*136 + cc] = hh; sAl[row*136 + cc] = ll;
    }
  }
  __syncthreads();
  // ---- QKV(next) from LDS
  for (int z = 0; z < 3; z++) {
    const u16* wh = Qh + z*16384;
    const u16* wl = Ql + z*16384;
    const float* bias = (z == 0) ? bq : (z == 1) ? bk : bv;
    float* C = qkvout + (size_t)z*2097152;
    f32x4 acc[2] = {};
    #pragma unroll
    for (int ks = 0; ks < 4; ks++) {
      bf16x8 ah = *(const bf16x8*)&sAh[(mq*16 + lr)*136 + ks*32 + l8];
      bf16x8 al = *(const bf16x8*)&sAl[(mq*16 + lr)*136 + ks*32 + l8];
      #pragma unroll
      for (int nf = 0; nf < 2; nf++) {
        int go = (((nq*2 + nf)*4 + ks) << 9) + (lane << 3);
        bf16x8 bh = *(const bf16x8*)(wh + go);
        bf16x8 bl = *(const bf16x8*)(wl + go);
        acc[nf] = MFMA(ah, bl, acc[nf]);
        acc[nf] = MFMA(al, bh, acc[nf]);
        acc[nf] = MFMA(ah, bh, acc[nf]);
      }
    }
    #pragma unroll
    for (int nf = 0; nf < 2; nf++) {
      int col = nq*32 + nf*16 + lr;
      float bb = bias[col];
      #pragma unroll
      for (int r = 0; r < 4; r++)
        C[(size_t)(m0 + mq*16 + lg*4 + r)*128 + col] = acc[nf][r] + bb;
    }
  }
}

// ---------------- tail kernels --------------------------------------------
__global__ __launch_bounds__(256) void k_out(
    const float* __restrict__ h, const float* __restrict__ Wout,
    const float* __restrict__ bout, float* __restrict__ out)
{
  int idx = blockIdx.x*256 + threadIdx.x;
  int bt = idx >> 1, j = idx & 1;
  float acc = bout[j];
  const float* hp = &h[bt*128];
  #pragma unroll 4
  for (int k2 = 0; k2 < 128; k2++)
    acc += fmaxf(hp[k2], 0.f) * Wout[k2*2 + j];
  out[idx] = acc;
}

__global__ __launch_bounds__(256) void k_red1(
    const float* __restrict__ ss, float* __restrict__ part)
{
  __shared__ float red[256];
  int b = blockIdx.x >> 5, g = blockIdx.x & 31;
  int c = threadIdx.x & 127, hf = threadIdx.x >> 7;
  float acc = 0.f;
  for (int i2 = 0; i2 < 64; i2++) {
    int t = g*128 + i2*2 + hf;
    acc += fmaxf(ss[(b*T_ + t)*128 + c], 0.f);
  }
  red[threadIdx.x] = acc;
  __syncthreads();
  if (threadIdx.x < 128)
    part[(b*32+g)*128 + threadIdx.x] = red[threadIdx.x] + red[threadIdx.x+128];
}

__global__ __launch_bounds__(512) void k_tail2(
    const float* __restrict__ part, const float* __restrict__ Wt,
    const float* __restrict__ btb, float* __restrict__ out)
{
  __shared__ float mb[512];
  const int tid = threadIdx.x;
  int b = tid >> 7, c = tid & 127;
  float s = 0.f;
  for (int g = 0; g < 32; g++) s += part[(b*32+g)*128 + c];
  mb[tid] = s * (1.f/4096.f);
  __syncthreads();
  for (int i = tid; i < 1200; i += 512) {
    int bb = i / 300, j = i - bb*300;
    float acc = btb[j];
    #pragma unroll 4
    for (int k2 = 0; k2 < 128; k2++)
      acc += mb[bb*128 + k2] * Wt[k2*300 + j];
    out[32768 + i] = acc;
  }
}

// ---------------- launcher -------------------------------------------------
extern "C" void kernel_launch(void* const* d_in, const int* in_sizes, int n_in,
                              void* d_out, int out_size, void* d_ws, size_t ws_size,
                              hipStream_t stream)
{
  const float* x    = (const float*)d_in[0];
  const float* c1w  = (const float*)d_in[1];
  const float* c1b  = (const float*)d_in[2];
  const float* c2w  = (const float*)d_in[3];
  const float* c2b  = (const float*)d_in[4];
  const float* c3w  = (const float*)d_in[5];
  const float* c3b  = (const float*)d_in[6];
  const float* ln1s = (const float*)d_in[7];
  const float* ln1b = (const float*)d_in[8];
  const float* ln2s = (const float*)d_in[9];
  const float* ln2b = (const float*)d_in[10];
  const float* Wq   = (const float*)d_in[11];
  const float* bq   = (const float*)d_in[12];
  const float* Wk   = (const float*)d_in[13];
  const float* bk   = (const float*)d_in[14];
  const float* Wv   = (const float*)d_in[15];
  const float* bv   = (const float*)d_in[16];
  const float* Wo   = (const float*)d_in[17];
  const float* bo   = (const float*)d_in[18];
  const float* Er   = (const float*)d_in[19];
  const float* W1   = (const float*)d_in[20];
  const float* b1   = (const float*)d_in[21];
  const float* W2   = (const float*)d_in[22];
  const float* b2   = (const float*)d_in[23];
  const float* Wout = (const float*)d_in[24];
  const float* bout = (const float*)d_in[25];
  const float* Wt   = (const float*)d_in[26];
  const float* bt   = (const float*)d_in[27];

  char* W = (char*)d_ws;
  u16* c2o_h = (u16*)W;
  u16* c2o_l = (u16*)(W + 20971520);
  char* RB = W + 33554432;
  float* qb  = (float*)RB;
  float* kb  = qb + 2097152;
  float* vb2 = qb + 4194304;
  u16* xh    = (u16*)(RB + 25165824);
  u16* xlo   = (u16*)(RB + 29360128);
  char* RC = W + 67108864;
  float* hbuf = (float*)RC;
  float* ssum = (float*)(RC + 8388608);
  u16* wqkv_h = (u16*)(RC + 16777216);
  u16* wqkv_l = wqkv_h + 442368;
  u16* wo_h   = wqkv_l + 442368;
  u16* wo_l   = wo_h + 147456;
  u16* w1t_h  = wo_l + 147456;
  u16* w1t_l  = w1t_h + 589824;
  u16* w2t_h  = w1t_l + 589824;
  u16* w2t_l  = w2t_h + 589824;
  u16* wc2_h  = w2t_l + 589824;
  u16* wc2_l  = wc2_h + 24576;
  u16* wc3_h  = wc2_l + 24576;
  u16* wc3_l  = wc3_h + 147456;
  float* part  = (float*)(wc3_l + 147456);
  float* outf  = (float*)d_out;

  k_wprep_all<<<7584, 256, 0, stream>>>(
      Wq, Wk, Wv, Wo, W1, W2, c2w, c3w,
      wqkv_h, wqkv_l, wo_h, wo_l, w1t_h, w1t_l, w2t_h, w2t_l,
      wc2_h, wc2_l, wc3_h, wc3_l);

  k_conv12m<<<dim3(512, B_), 256, 0, stream>>>(x, c1w, c1b, wc2_h, wc2_l, c2b,
                                               c2o_h, c2o_l);
  k_conv3m<<<dim3(256, B_), 256, 0, stream>>>(c2o_h, c2o_l, wc3_h, wc3_l, c3b, hbuf);

  // layer-0 LN1 + QKV
  k_ln<<<4096, 256, 0, stream>>>(hbuf, ln1s, ln1b, xh, xlo);
  k_gqkv<<<dim3(1024, 3), 256, 0, stream>>>(
      xh, xlo, wqkv_h, wqkv_l, bq, bk, bv, qb);

  for (int l = 0; l < 9; l++) {
    int ln = (l < 8) ? (l + 1) : 0;   // next-layer idx (unused when do_qkv=0)
    k_attnwo<<<512, 512, 0, stream>>>(
        qb, kb, vb2, Er + l*640,
        wo_h + l*16384, wo_l + l*16384, bo + l*128,
        ln2s + l*128, ln2b + l*128,
        hbuf, ssum, (l == 0) ? 1 : 0, xh, xlo, 1 << l);
    k_ffnqkv<<<512, 512, 0, stream>>>(
        xh, xlo, w1t_h + l*65536, w1t_l + l*65536, b1 + l*512,
        w2t_h + l*65536, w2t_l + l*65536, b2 + l*128,
        hbuf, (l < 8) ? 1 : 0,
        ln1s + ln*128, ln1b + ln*128,
        wqkv_h + ln*49152, wqkv_l + ln*49152,
        bq + ln*128, bk + ln*128, bv + ln*128, qb);
  }

  k_out<<<128, 256, 0, stream>>>(hbuf, Wout, bout, outf);
  k_red1<<<128, 256, 0, stream>>>(ssum, part);
  k_tail2<<<1, 512, 0, stream>>>(part, Wt, bt, outf);
}

// Round 8
// 671.464 us; speedup vs baseline: 3.3947x; 1.0612x over previous
//
#include <hip/hip_runtime.h>

#define T_ 4096
#define B_ 4

typedef unsigned short u16;
typedef __bf16 bf16x8 __attribute__((ext_vector_type(8)));
typedef float f32x4 __attribute__((ext_vector_type(4)));

__device__ inline void splitbf(float v, u16& h, u16& l) {
  __bf16 hb = (__bf16)v;
  float r = v - (float)hb;
  __bf16 lb = (__bf16)r;
  h = __builtin_bit_cast(u16, hb);
  l = __builtin_bit_cast(u16, lb);
}

#define MFMA(a,b,c) __builtin_amdgcn_mfma_f32_16x16x32_bf16((a),(b),(c),0,0,0)

// ---------------- fused conv1(5x3,pad2)+pool3+relu + conv2(1x12)+pool3+relu
__global__ __launch_bounds__(256) void k_conv12m(
    const float* __restrict__ x, const float* __restrict__ w1,
    const float* __restrict__ b1,
    const u16* __restrict__ wh, const u16* __restrict__ wl,
    const float* __restrict__ b2,
    u16* __restrict__ oh, u16* __restrict__ ol)
{
  __shared__ float sx[12][130];
  __shared__ float w1s[480];
  __shared__ float b1s[32];
  __shared__ u16 sh[8*43*40];
  __shared__ u16 sl[8*43*40];
  __shared__ float dmp[4][15][66];
  const int tid = threadIdx.x;
  const int t0 = blockIdx.x * 8;
  const int b = blockIdx.y;
  const float* xb = x + (size_t)b*T_*128;
  for (int i = tid; i < 1536; i += 256) {
    int r = i >> 7, c = i & 127;
    int t = t0 - 2 + r;
    sx[r][c] = (t >= 0 && t < T_) ? xb[t*128 + c] : 0.f;
  }
  for (int i = tid; i < 480; i += 256) w1s[i] = w1[i];
  if (tid < 32) b1s[tid] = b1[tid];
  for (int i = tid; i < 320; i += 256) {
    int tt = i / 40, c = i - tt*40;
    sh[(tt*43 + 42)*40 + c] = 0;
    sl[(tt*43 + 42)*40 + c] = 0;
  }
  __syncthreads();
  // conv1 + pool3 + relu: thread = (c1, tt); w1 in regs, 5-col window
  {
    const int c1 = tid & 31, tt = tid >> 5;
    float w1r[15];
    #pragma unroll
    for (int i = 0; i < 15; i++) w1r[i] = w1s[c1*15 + i];
    float bb1 = b1s[c1];
    for (int wp = 0; wp < 42; wp++) {
      int c0 = wp*3;
      float s0 = 0.f, s1 = 0.f, s2 = 0.f;
      #pragma unroll
      for (int kh = 0; kh < 5; kh++) {
        float x0 = sx[tt+kh][c0],   x1 = sx[tt+kh][c0+1];
        float x2 = sx[tt+kh][c0+2], x3 = sx[tt+kh][c0+3];
        float x4 = sx[tt+kh][c0+4];
        float wA = w1r[kh*3], wB = w1r[kh*3+1], wC = w1r[kh*3+2];
        s0 += x0*wA + x1*wB + x2*wC;
        s1 += x1*wA + x2*wB + x3*wC;
        s2 += x2*wA + x3*wB + x4*wC;
      }
      float v = fmaxf(fmaxf(fmaxf(s0, s1), s2) + bb1, 0.f);
      u16 hh, ll; splitbf(v, hh, ll);
      int dd = (tt*43 + wp)*40 + c1;
      sh[dd] = hh; sl[dd] = ll;
    }
  }
  __syncthreads();
  const int lane = tid & 63;
  const int wid = tid >> 6;
  const int lr = lane & 15;
  const int lk8 = (lane >> 4) * 8;
  f32x4 acc[2][2][4] = {};
  #pragma unroll 3
  for (int kw = 0; kw < 12; kw++) {
    bf16x8 bh[4], bl[4];
    #pragma unroll
    for (int nf = 0; nf < 4; nf++) {
      int go = ((nf*12 + kw) << 9) + (lane << 3);
      bh[nf] = *(const bf16x8*)(wh + go);
      bl[nf] = *(const bf16x8*)(wl + go);
    }
    #pragma unroll
    for (int tp = 0; tp < 2; tp++) {
      int tloc = wid*2 + tp;
      #pragma unroll
      for (int mf = 0; mf < 2; mf++) {
        int lofs = (tloc*43 + mf*16 + lr + kw)*40 + lk8;
        bf16x8 ah = *(const bf16x8*)&sh[lofs];
        bf16x8 al = *(const bf16x8*)&sl[lofs];
        #pragma unroll
        for (int nf = 0; nf < 4; nf++) {
          acc[tp][mf][nf] = MFMA(ah, bl[nf], acc[tp][mf][nf]);
          acc[tp][mf][nf] = MFMA(al, bh[nf], acc[tp][mf][nf]);
          acc[tp][mf][nf] = MFMA(ah, bh[nf], acc[tp][mf][nf]);
        }
      }
    }
  }
  const int lg = lane >> 4;
  for (int tp = 0; tp < 2; tp++) {
    int t = t0 + wid*2 + tp;
    for (int half = 0; half < 2; half++) {
      #pragma unroll
      for (int mf = 0; mf < 2; mf++)
        #pragma unroll
        for (int r = 0; r < 4; r++) {
          int grow = mf*16 + lg*4 + r;
          int lrow = grow - half*15;
          if (lrow >= 0 && lrow < 15) {
            #pragma unroll
            for (int nf = 0; nf < 4; nf++)
              dmp[wid][lrow][nf*16 + lr] = acc[tp][mf][nf][r];
          }
        }
      asm volatile("s_waitcnt lgkmcnt(0)" ::: "memory");
      #pragma unroll
      for (int it = 0; it < 5; it++) {
        float v = fmaxf(fmaxf(dmp[wid][it*3][lane], dmp[wid][it*3+1][lane]),
                        dmp[wid][it*3+2][lane]);
        v = fmaxf(v + b2[lane], 0.f);
        u16 hh, ll; splitbf(v, hh, ll);
        size_t o = (size_t)((b*T_ + t)*10 + half*5 + it)*64 + lane;
        oh[o] = hh; ol[o] = ll;
      }
      asm volatile("s_waitcnt lgkmcnt(0)" ::: "memory");
    }
  }
}

// ---------------- conv3 (3x6, pad_h=1) + pool3 + relu via MFMA -------------
__global__ __launch_bounds__(256) void k_conv3m(
    const u16* __restrict__ ih, const u16* __restrict__ il,
    const u16* __restrict__ wh, const u16* __restrict__ wl,
    const float* __restrict__ b3, float* __restrict__ hout)
{
  __shared__ u16 sh[18*720];
  __shared__ u16 sl[18*720];
  __shared__ float dmp[48][132];
  const int tid = threadIdx.x;
  const int t0 = (blockIdx.x & 255) * 16;
  const int b = blockIdx.y;
  for (int i = tid; i < 1440; i += 256) {
    int cg = i & 7;
    int w = (i >> 3) % 10;
    int tt = i / 80;
    int t = t0 - 1 + tt;
    int dd = tt*720 + w*72 + cg*8;
    if (t >= 0 && t < T_) {
      size_t so = (size_t)((b*T_ + t)*10 + w)*64 + cg*8;
      *(ulonglong2*)&sh[dd] = *(const ulonglong2*)&ih[so];
      *(ulonglong2*)&sl[dd] = *(const ulonglong2*)&il[so];
    } else {
      ulonglong2 z; z.x = 0; z.y = 0;
      *(ulonglong2*)&sh[dd] = z;
      *(ulonglong2*)&sl[dd] = z;
    }
  }
  __syncthreads();
  const int lane = tid & 63;
  const int wid = tid >> 6;
  const int lr = lane & 15;
  const int lk8 = (lane >> 4) * 8;
  int tlm[3], wom[3];
  #pragma unroll
  for (int mf = 0; mf < 3; mf++) {
    int r = mf*16 + lr;
    tlm[mf] = r / 3;
    wom[mf] = r - tlm[mf]*3;
  }
  f32x4 acc[3][2] = {};
  #pragma unroll 2
  for (int kh = 0; kh < 3; kh++) {
    #pragma unroll
    for (int kw = 0; kw < 6; kw++) {
      #pragma unroll
      for (int chh = 0; chh < 2; chh++) {
        int s = (kh*6 + kw)*2 + chh;
        int ch = chh*32;
        bf16x8 bh[2], bl[2];
        #pragma unroll
        for (int nfl = 0; nfl < 2; nfl++) {
          int go = (((wid*2 + nfl)*36 + s) << 9) + (lane << 3);
          bh[nfl] = *(const bf16x8*)(wh + go);
          bl[nfl] = *(const bf16x8*)(wl + go);
        }
        #pragma unroll
        for (int mf = 0; mf < 3; mf++) {
          int lofs = (tlm[mf] + kh)*720 + (wom[mf] + kw)*72 + ch + lk8;
          bf16x8 ah = *(const bf16x8*)&sh[lofs];
          bf16x8 al = *(const bf16x8*)&sl[lofs];
          #pragma unroll
          for (int nfl = 0; nfl < 2; nfl++) {
            acc[mf][nfl] = MFMA(ah, bl[nfl], acc[mf][nfl]);
            acc[mf][nfl] = MFMA(al, bh[nfl], acc[mf][nfl]);
            acc[mf][nfl] = MFMA(ah, bh[nfl], acc[mf][nfl]);
          }
        }
      }
    }
  }
  const int lg = lane >> 4;
  #pragma unroll
  for (int mf = 0; mf < 3; mf++)
    #pragma unroll
    for (int r = 0; r < 4; r++) {
      int row = mf*16 + lg*4 + r;
      #pragma unroll
      for (int nfl = 0; nfl < 2; nfl++)
        dmp[row][wid*32 + nfl*16 + lr] = acc[mf][nfl][r];
    }
  __syncthreads();
  for (int i = tid; i < 2048; i += 256) {
    int c3 = i & 127;
    int tt = i >> 7;
    float v = fmaxf(fmaxf(dmp[tt*3][c3], dmp[tt*3+1][c3]), dmp[tt*3+2][c3]);
    v = fmaxf(v + b3[c3], 0.f);
    hout[(size_t)(b*T_ + t0 + tt)*128 + c3] = v;
  }
}

// ---------------- standalone LayerNorm (layer-0 LN1 only) ------------------
__device__ inline float wave_sum(float v) {
  #pragma unroll
  for (int m = 1; m < 64; m <<= 1) v += __shfl_xor(v, m, 64);
  return v;
}

__global__ __launch_bounds__(256) void k_ln(
    const float* __restrict__ in, const float* __restrict__ sc,
    const float* __restrict__ bi, u16* __restrict__ oh, u16* __restrict__ ol)
{
  const int lane = threadIdx.x & 63;
  const int row = blockIdx.x*4 + (threadIdx.x >> 6);
  float a = in[row*128 + lane];
  float c = in[row*128 + 64 + lane];
  float mean = wave_sum(a + c) * (1.f/128.f);
  float d0 = a - mean, d1 = c - mean;
  float var = wave_sum(d0*d0 + d1*d1) * (1.f/128.f);
  float rs = rsqrtf(var + 1e-5f);
  float v0 = d0*rs*sc[lane]    + bi[lane];
  float v1 = d1*rs*sc[64+lane] + bi[64+lane];
  u16 h0, l0, h1, l1;
  splitbf(v0, h0, l0); splitbf(v1, h1, l1);
  oh[row*128 + lane] = h0;      ol[row*128 + lane] = l0;
  oh[row*128 + 64 + lane] = h1; ol[row*128 + 64 + lane] = l1;
}

// ---------------- weight prep (single launch, block-uniform segments) ------
__device__ inline void prep_fr(const float* __restrict__ src,
                               u16* __restrict__ dh, u16* __restrict__ dl,
                               int K, int N, int matStride, int idx)
{
  int mat = idx / (K*N);
  int rem = idx - mat*(K*N);
  int k = rem / N;
  int n = rem - k*N;
  float v = src[idx];
  u16 h, l; splitbf(v, h, l);
  int nt = n >> 4, ks = k >> 5, ksub = k & 31;
  size_t o = (size_t)mat*matStride + (size_t)((nt*(K>>5) + ks) << 9)
           + (((ksub >> 3) << 4) + (n & 15))*8 + (ksub & 7);
  dh[o] = h; dl[o] = l;
}

__global__ __launch_bounds__(256) void k_wprep_all(
    const float* __restrict__ Wq, const float* __restrict__ Wk,
    const float* __restrict__ Wv, const float* __restrict__ Wo,
    const float* __restrict__ W1, const float* __restrict__ W2,
    const float* __restrict__ c2w, const float* __restrict__ c3w,
    u16* wqkv_h, u16* wqkv_l, u16* wo_h, u16* wo_l,
    u16* w1t_h, u16* w1t_l, u16* w2t_h, u16* w2t_l,
    u16* wc2_h, u16* wc2_l, u16* wc3_h, u16* wc3_l)
{
  const int bid = blockIdx.x;
  const int tid = threadIdx.x;
  if (bid < 576) {
    prep_fr(Wq, wqkv_h, wqkv_l, 128, 128, 49152, bid*256 + tid);
  } else if (bid < 1152) {
    prep_fr(Wk, wqkv_h + 16384, wqkv_l + 16384, 128, 128, 49152, (bid-576)*256 + tid);
  } else if (bid < 1728) {
    prep_fr(Wv, wqkv_h + 32768, wqkv_l + 32768, 128, 128, 49152, (bid-1152)*256 + tid);
  } else if (bid < 2304) {
    prep_fr(Wo, wo_h, wo_l, 128, 128, 16384, (bid-1728)*256 + tid);
  } else if (bid < 4608) {
    prep_fr(W1, w1t_h, w1t_l, 128, 512, 65536, (bid-2304)*256 + tid);
  } else if (bid < 6912) {
    prep_fr(W2, w2t_h, w2t_l, 512, 128, 65536, (bid-4608)*256 + tid);
  } else if (bid < 7008) {
    int idx = (bid-6912)*256 + tid;
    int c2 = idx / 384;
    int rem = idx - c2*384;
    int c1 = rem / 12;
    int kw = rem - c1*12;
    float v = c2w[idx];
    u16 h, l; splitbf(v, h, l);
    size_t o = (size_t)((((c2 >> 4)*12 + kw) << 9))
             + (((c1 >> 3) << 4) + (c2 & 15))*8 + (c1 & 7);
    wc2_h[o] = h; wc2_l[o] = l;
  } else {
    int idx = (bid-7008)*256 + tid;
    int c3 = idx / 1152;
    int rem = idx - c3*1152;
    int c2 = rem / 18;
    int khkw = rem - c2*18;
    float v = c3w[idx];
    u16 h, l; splitbf(v, h, l);
    int s = khkw*2 + (c2 >> 5);
    int c = c2 & 31;
    size_t o = (size_t)((((c3 >> 4)*36 + s) << 9))
             + (((c >> 3) << 4) + (c3 & 15))*8 + (c & 7);
    wc3_h[o] = h; wc3_l[o] = l;
  }
}

// ---------------- QKV GEMM (layer 0 only): tile 16 x 128 -------------------
__global__ __launch_bounds__(256) void k_gqkv(
    const u16* __restrict__ Ah, const u16* __restrict__ Al,
    const u16* __restrict__ Wh, const u16* __restrict__ Wl,
    const float* __restrict__ bq, const float* __restrict__ bk,
    const float* __restrict__ bv, float* __restrict__ outbase)
{
  __shared__ u16 sAh[16*136], sAl[16*136];
  const int tid = threadIdx.x;
  const int m0 = blockIdx.x * 16;
  const int z = blockIdx.y;
  const u16* wh = Wh + z*16384;
  const u16* wl = Wl + z*16384;
  const float* bias = (z == 0) ? bq : (z == 1) ? bk : bv;
  float* C = outbase + (size_t)z*2097152;
  {
    int row = tid >> 4, c8 = tid & 15;
    *(ulonglong2*)&sAh[row*136 + c8*8] = *(const ulonglong2*)&Ah[(size_t)(m0+row)*128 + c8*8];
    *(ulonglong2*)&sAl[row*136 + c8*8] = *(const ulonglong2*)&Al[(size_t)(m0+row)*128 + c8*8];
  }
  __syncthreads();
  const int lane = tid & 63, nq = tid >> 6;
  const int lr = lane & 15, lg = lane >> 4, l8 = lg*8;
  f32x4 acc[2] = {};
  #pragma unroll
  for (int ks = 0; ks < 4; ks++) {
    bf16x8 ah = *(const bf16x8*)&sAh[lr*136 + ks*32 + l8];
    bf16x8 al = *(const bf16x8*)&sAl[lr*136 + ks*32 + l8];
    #pragma unroll
    for (int nf = 0; nf < 2; nf++) {
      int go = (((nq*2 + nf)*4 + ks) << 9) + (lane << 3);
      bf16x8 bh = *(const bf16x8*)(wh + go);
      bf16x8 bl = *(const bf16x8*)(wl + go);
      acc[nf] = MFMA(ah, bl, acc[nf]);
      acc[nf] = MFMA(al, bh, acc[nf]);
      acc[nf] = MFMA(ah, bh, acc[nf]);
    }
  }
  #pragma unroll
  for (int nf = 0; nf < 2; nf++) {
    int col = nq*32 + nf*16 + lr;
    float bb = bias[col];
    #pragma unroll
    for (int r = 0; r < 4; r++)
      C[(size_t)(m0 + lg*4 + r)*128 + col] = acc[nf][r] + bb;
  }
}

// ------- FULL LAYER: attn + Wo + res/skip + LN2 + FFN + res + LN1' + QKV' --
// qkv in/out ping-pong (qin read, qout written) -> safe single kernel.
__global__ __launch_bounds__(512) void k_layer(
    const float* __restrict__ qin,           // q,k,v contiguous (3 x 2M fl)
    const float* __restrict__ Er,
    const u16* __restrict__ Woh, const u16* __restrict__ Wol,
    const float* __restrict__ bo,
    const float* __restrict__ sc2, const float* __restrict__ bi2,
    const u16* __restrict__ W1h, const u16* __restrict__ W1l,
    const float* __restrict__ b1,
    const u16* __restrict__ W2h, const u16* __restrict__ W2l,
    const float* __restrict__ b2,
    float* __restrict__ hbuf, float* __restrict__ ssum, int skip_init,
    int do_qkv,
    const float* __restrict__ sc1, const float* __restrict__ bi1,
    const u16* __restrict__ Qh, const u16* __restrict__ Ql,
    const float* __restrict__ bq, const float* __restrict__ bk,
    const float* __restrict__ bv, float* __restrict__ qout, int dil)
{
  __shared__ u16 sAh[32*136], sAl[32*136];
  __shared__ u16 hidH[2][32*136], hidL[2][32*136];
  __shared__ float dmp[32*132];
  const int tid = threadIdx.x, lane = tid & 63, wv = tid >> 6;
  const int m0 = blockIdx.x * 32;
  const int b = m0 >> 12;
  const int t0 = m0 & 4095;
  const float* qb = qin;
  const float* kb = qin + 2097152;
  const float* vb = qin + 4194304;
  // ---- Phase A: attention (8 waves x 4 rows) -> sA
  for (int rr = 0; rr < 4; rr++) {
    int r = wv*4 + rr;
    int t = t0 + r;
    int bt = m0 + r;
    #pragma unroll
    for (int h = 0; h < 2; h++) {
      float qd = qb[(size_t)bt*128 + h*64 + lane];
      float s[5];
      int tpc_arr[5];
      #pragma unroll
      for (int a = 0; a < 5; a++) {
        int tp = t + (a-2)*dil;
        bool valid = (tp >= 0 && tp < T_);
        int tpc = tp < 0 ? 0 : (tp > T_-1 ? T_-1 : tp);
        tpc_arr[a] = tpc;
        float kd = kb[(size_t)(b*T_ + tpc)*128 + h*64 + lane];
        float er = Er[(h*5 + a)*64 + lane];
        float p = qd * (kd + er);
        p = wave_sum(p);
        s[a] = valid ? p * 0.125f : -1e30f;
      }
      float mx = s[0];
      #pragma unroll
      for (int a = 1; a < 5; a++) mx = fmaxf(mx, s[a]);
      float p[5], psum = 0.f;
      #pragma unroll
      for (int a = 0; a < 5; a++) { p[a] = __expf(s[a]-mx); psum += p[a]; }
      float inv = 1.f/psum;
      float o = 0.f;
      #pragma unroll
      for (int a = 0; a < 5; a++)
        o += p[a] * vb[(size_t)(b*T_ + tpc_arr[a])*128 + h*64 + lane];
      float vo = o * inv;
      u16 hh, ll; splitbf(vo, hh, ll);
      sAh[r*136 + h*64 + lane] = hh;
      sAl[r*136 + h*64 + lane] = ll;
    }
  }
  __syncthreads();
  // ---- Phase B: Wo GEMM + residual + skip-acc
  const int lr = lane & 15, lg = lane >> 4, l8 = lg*8;
  const int mq = wv >> 2, nq = wv & 3;
  {
    f32x4 acc[2] = {};
    #pragma unroll
    for (int ks = 0; ks < 4; ks++) {
      bf16x8 ah = *(const bf16x8*)&sAh[(mq*16 + lr)*136 + ks*32 + l8];
      bf16x8 al = *(const bf16x8*)&sAl[(mq*16 + lr)*136 + ks*32 + l8];
      #pragma unroll
      for (int nf = 0; nf < 2; nf++) {
        int go = (((nq*2 + nf)*4 + ks) << 9) + (lane << 3);
        bf16x8 bh = *(const bf16x8*)(Woh + go);
        bf16x8 bl = *(const bf16x8*)(Wol + go);
        acc[nf] = MFMA(ah, bl, acc[nf]);
        acc[nf] = MFMA(al, bh, acc[nf]);
        acc[nf] = MFMA(ah, bh, acc[nf]);
      }
    }
    #pragma unroll
    for (int nf = 0; nf < 2; nf++) {
      int col = nq*32 + nf*16 + lr;
      float bb = bo[col];
      #pragma unroll
      for (int r = 0; r < 4; r++) {
        int row = mq*16 + lg*4 + r;
        size_t o = (size_t)(m0 + row)*128 + col;
        float val = acc[nf][r] + bb;
        if (skip_init) ssum[o] = val; else ssum[o] += val;
        float hn = hbuf[o] + val;
        hbuf[o] = hn;
        dmp[row*132 + col] = hn;
      }
    }
  }
  __syncthreads();
  // ---- Phase C: LN2 -> sA
  {
    const int row = tid >> 4, p = tid & 15;
    float xv[8], s = 0.f;
    const float* dp = &dmp[row*132 + p*8];
    #pragma unroll
    for (int i = 0; i < 8; i++) { xv[i] = dp[i]; s += xv[i]; }
    s += __shfl_xor(s, 1); s += __shfl_xor(s, 2);
    s += __shfl_xor(s, 4); s += __shfl_xor(s, 8);
    float mean = s * (1.f/128.f);
    float v = 0.f;
    #pragma unroll
    for (int i = 0; i < 8; i++) { float d = xv[i]-mean; v += d*d; }
    v += __shfl_xor(v, 1); v += __shfl_xor(v, 2);
    v += __shfl_xor(v, 4); v += __shfl_xor(v, 8);
    float rs = rsqrtf(v*(1.f/128.f) + 1e-5f);
    #pragma unroll
    for (int i = 0; i < 8; i++) {
      int cc = p*8 + i;
      float y = (xv[i]-mean)*rs*sc2[cc] + bi2[cc];
      u16 hh, ll; splitbf(y, hh, ll);
      sAh[row*136 + cc] = hh; sAl[row*136 + cc] = ll;
    }
  }
  __syncthreads();
  // ---- Phase D: FFN (hid in LDS, 4 chunks of 128)
  f32x4 acc2[2] = {};
  for (int c = 0; c < 4; c++) {
    f32x4 acc1[2] = {};
    #pragma unroll
    for (int ks = 0; ks < 4; ks++) {
      bf16x8 ah = *(const bf16x8*)&sAh[(mq*16 + lr)*136 + ks*32 + l8];
      bf16x8 al = *(const bf16x8*)&sAl[(mq*16 + lr)*136 + ks*32 + l8];
      #pragma unroll
      for (int nf = 0; nf < 2; nf++) {
        int go = (((c*8 + nq*2 + nf)*4 + ks) << 9) + (lane << 3);
        bf16x8 bh = *(const bf16x8*)(W1h + go);
        bf16x8 bl = *(const bf16x8*)(W1l + go);
        acc1[nf] = MFMA(ah, bl, acc1[nf]);
        acc1[nf] = MFMA(al, bh, acc1[nf]);
        acc1[nf] = MFMA(ah, bh, acc1[nf]);
      }
    }
    __syncthreads();
    #pragma unroll
    for (int nf = 0; nf < 2; nf++) {
      int col = nq*32 + nf*16 + lr;
      float bb = b1[c*128 + col];
      #pragma unroll
      for (int r = 0; r < 4; r++) {
        int row = mq*16 + lg*4 + r;
        float hv = fmaxf(acc1[nf][r] + bb, 0.f);
        u16 hh, ll; splitbf(hv, hh, ll);
        hidH[c & 1][row*136 + col] = hh;
        hidL[c & 1][row*136 + col] = ll;
      }
    }
    __syncthreads();
    #pragma unroll
    for (int ks = 0; ks < 4; ks++) {
      bf16x8 ah = *(const bf16x8*)&hidH[c & 1][(mq*16 + lr)*136 + ks*32 + l8];
      bf16x8 al = *(const bf16x8*)&hidL[c & 1][(mq*16 + lr)*136 + ks*32 + l8];
      #pragma unroll
      for (int nf = 0; nf < 2; nf++) {
        int go = (((nq*2 + nf)*16 + c*4 + ks) << 9) + (lane << 3);
        bf16x8 bh = *(const bf16x8*)(W2h + go);
        bf16x8 bl = *(const bf16x8*)(W2l + go);
        acc2[nf] = MFMA(ah, bl, acc2[nf]);
        acc2[nf] = MFMA(al, bh, acc2[nf]);
        acc2[nf] = MFMA(ah, bh, acc2[nf]);
      }
    }
  }
  // ---- Phase E: FFN residual
  #pragma unroll
  for (int nf = 0; nf < 2; nf++) {
    int col = nq*32 + nf*16 + lr;
    float bb = b2[col];
    #pragma unroll
    for (int r = 0; r < 4; r++) {
      int row = mq*16 + lg*4 + r;
      size_t o = (size_t)(m0 + row)*128 + col;
      float hn = hbuf[o] + acc2[nf][r] + bb;
      hbuf[o] = hn;
      dmp[row*132 + col] = hn;
    }
  }
  if (!do_qkv) return;
  __syncthreads();
  // ---- Phase F: LN1(next) -> sA, then QKV(next) -> qout
  {
    const int row = tid >> 4, p = tid & 15;
    float xv[8], s = 0.f;
    const float* dp = &dmp[row*132 + p*8];
    #pragma unroll
    for (int i = 0; i < 8; i++) { xv[i] = dp[i]; s += xv[i]; }
    s += __shfl_xor(s, 1); s += __shfl_xor(s, 2);
    s += __shfl_xor(s, 4); s += __shfl_xor(s, 8);
    float mean = s * (1.f/128.f);
    float v = 0.f;
    #pragma unroll
    for (int i = 0; i < 8; i++) { float d = xv[i]-mean; v += d*d; }
    v += __shfl_xor(v, 1); v += __shfl_xor(v, 2);
    v += __shfl_xor(v, 4); v += __shfl_xor(v, 8);
    float rs = rsqrtf(v*(1.f/128.f) + 1e-5f);
    #pragma unroll
    for (int i = 0; i < 8; i++) {
      int cc = p*8 + i;
      float y = (xv[i]-mean)*rs*sc1[cc] + bi1[cc];
      u16 hh, ll; splitbf(y, hh, ll);
      sAh[row*136 + cc] = hh; sAl[row*136 + cc] = ll;
    }
  }
  __syncthreads();
  for (int z = 0; z < 3; z++) {
    const u16* wh = Qh + z*16384;
    const u16* wl = Ql + z*16384;
    const float* bias = (z == 0) ? bq : (z == 1) ? bk : bv;
    float* C = qout + (size_t)z*2097152;
    f32x4 acc[2] = {};
    #pragma unroll
    for (int ks = 0; ks < 4; ks++) {
      bf16x8 ah = *(const bf16x8*)&sAh[(mq*16 + lr)*136 + ks*32 + l8];
      bf16x8 al = *(const bf16x8*)&sAl[(mq*16 + lr)*136 + ks*32 + l8];
      #pragma unroll
      for (int nf = 0; nf < 2; nf++) {
        int go = (((nq*2 + nf)*4 + ks) << 9) + (lane << 3);
        bf16x8 bh = *(const bf16x8*)(wh + go);
        bf16x8 bl = *(const bf16x8*)(wl + go);
        acc[nf] = MFMA(ah, bl, acc[nf]);
        acc[nf] = MFMA(al, bh, acc[nf]);
        acc[nf] = MFMA(ah, bh, acc[nf]);
      }
    }
    #pragma unroll
    for (int nf = 0; nf < 2; nf++) {
      int col = nq*32 + nf*16 + lr;
      float bb = bias[col];
      #pragma unroll
      for (int r = 0; r < 4; r++)
        C[(size_t)(m0 + mq*16 + lg*4 + r)*128 + col] = acc[nf][r] + bb;
    }
  }
}

// ---------------- tail kernels --------------------------------------------
__global__ __launch_bounds__(256) void k_out(
    const float* __restrict__ h, const float* __restrict__ Wout,
    const float* __restrict__ bout, float* __restrict__ out)
{
  int idx = blockIdx.x*256 + threadIdx.x;
  int bt = idx >> 1, j = idx & 1;
  float acc = bout[j];
  const float* hp = &h[bt*128];
  #pragma unroll 4
  for (int k2 = 0; k2 < 128; k2++)
    acc += fmaxf(hp[k2], 0.f) * Wout[k2*2 + j];
  out[idx] = acc;
}

__global__ __launch_bounds__(256) void k_red1(
    const float* __restrict__ ss, float* __restrict__ part)
{
  __shared__ float red[256];
  int b = blockIdx.x >> 5, g = blockIdx.x & 31;
  int c = threadIdx.x & 127, hf = threadIdx.x >> 7;
  float acc = 0.f;
  for (int i2 = 0; i2 < 64; i2++) {
    int t = g*128 + i2*2 + hf;
    acc += fmaxf(ss[(b*T_ + t)*128 + c], 0.f);
  }
  red[threadIdx.x] = acc;
  __syncthreads();
  if (threadIdx.x < 128)
    part[(b*32+g)*128 + threadIdx.x] = red[threadIdx.x] + red[threadIdx.x+128];
}

__global__ __launch_bounds__(512) void k_tail2(
    const float* __restrict__ part, const float* __restrict__ Wt,
    const float* __restrict__ btb, float* __restrict__ out)
{
  __shared__ float mb[512];
  const int tid = threadIdx.x;
  int b = tid >> 7, c = tid & 127;
  float s = 0.f;
  for (int g = 0; g < 32; g++) s += part[(b*32+g)*128 + c];
  mb[tid] = s * (1.f/4096.f);
  __syncthreads();
  for (int i = tid; i < 1200; i += 512) {
    int bb = i / 300, j = i - bb*300;
    float acc = btb[j];
    #pragma unroll 4
    for (int k2 = 0; k2 < 128; k2++)
      acc += mb[bb*128 + k2] * Wt[k2*300 + j];
    out[32768 + i] = acc;
  }
}

// ---------------- launcher -------------------------------------------------
extern "C" void kernel_launch(void* const* d_in, const int* in_sizes, int n_in,
                              void* d_out, int out_size, void* d_ws, size_t ws_size,
                              hipStream_t stream)
{
  const float* x    = (const float*)d_in[0];
  const float* c1w  = (const float*)d_in[1];
  const float* c1b  = (const float*)d_in[2];
  const float* c2w  = (const float*)d_in[3];
  const float* c2b  = (const float*)d_in[4];
  const float* c3w  = (const float*)d_in[5];
  const float* c3b  = (const float*)d_in[6];
  const float* ln1s = (const float*)d_in[7];
  const float* ln1b = (const float*)d_in[8];
  const float* ln2s = (const float*)d_in[9];
  const float* ln2b = (const float*)d_in[10];
  const float* Wq   = (const float*)d_in[11];
  const float* bq   = (const float*)d_in[12];
  const float* Wk   = (const float*)d_in[13];
  const float* bk   = (const float*)d_in[14];
  const float* Wv   = (const float*)d_in[15];
  const float* bv   = (const float*)d_in[16];
  const float* Wo   = (const float*)d_in[17];
  const float* bo   = (const float*)d_in[18];
  const float* Er   = (const float*)d_in[19];
  const float* W1   = (const float*)d_in[20];
  const float* b1   = (const float*)d_in[21];
  const float* W2   = (const float*)d_in[22];
  const float* b2   = (const float*)d_in[23];
  const float* Wout = (const float*)d_in[24];
  const float* bout = (const float*)d_in[25];
  const float* Wt   = (const float*)d_in[26];
  const float* bt   = (const float*)d_in[27];

  char* W = (char*)d_ws;
  u16* c2o_h = (u16*)W;                      // conv transient (0..42MB)
  u16* c2o_l = (u16*)(W + 20971520);
  char* RB = W + 41943040;
  float* qbuf0 = (float*)RB;                 // qkv ping (25.2 MB)
  float* qbuf1 = (float*)(RB + 25165824);    // qkv pong (25.2 MB)
  u16* xh    = (u16*)(RB + 50331648);        // layer-0 LN1 out
  u16* xlo   = (u16*)(RB + 54525952);
  char* RC = W + 100663296;
  float* hbuf = (float*)RC;
  float* ssum = (float*)(RC + 8388608);
  u16* wqkv_h = (u16*)(RC + 16777216);
  u16* wqkv_l = wqkv_h + 442368;
  u16* wo_h   = wqkv_l + 442368;
  u16* wo_l   = wo_h + 147456;
  u16* w1t_h  = wo_l + 147456;
  u16* w1t_l  = w1t_h + 589824;
  u16* w2t_h  = w1t_l + 589824;
  u16* w2t_h2 = w2t_h;  (void)w2t_h2;
  u16* w2t_l  = w2t_h + 589824;
  u16* wc2_h  = w2t_l + 589824;
  u16* wc2_l  = wc2_h + 24576;
  u16* wc3_h  = wc2_l + 24576;
  u16* wc3_l  = wc3_h + 147456;
  float* part  = (float*)(wc3_l + 147456);
  float* outf  = (float*)d_out;

  k_wprep_all<<<7584, 256, 0, stream>>>(
      Wq, Wk, Wv, Wo, W1, W2, c2w, c3w,
      wqkv_h, wqkv_l, wo_h, wo_l, w1t_h, w1t_l, w2t_h, w2t_l,
      wc2_h, wc2_l, wc3_h, wc3_l);

  k_conv12m<<<dim3(512, B_), 256, 0, stream>>>(x, c1w, c1b, wc2_h, wc2_l, c2b,
                                               c2o_h, c2o_l);
  k_conv3m<<<dim3(256, B_), 256, 0, stream>>>(c2o_h, c2o_l, wc3_h, wc3_l, c3b, hbuf);

  // layer-0 LN1 + QKV into qbuf0
  k_ln<<<4096, 256, 0, stream>>>(hbuf, ln1s, ln1b, xh, xlo);
  k_gqkv<<<dim3(1024, 3), 256, 0, stream>>>(
      xh, xlo, wqkv_h, wqkv_l, bq, bk, bv, qbuf0);

  for (int l = 0; l < 9; l++) {
    int ln = (l < 8) ? (l + 1) : 0;
    float* qin  = (l & 1) ? qbuf1 : qbuf0;
    float* qout = (l & 1) ? qbuf0 : qbuf1;
    k_layer<<<512, 512, 0, stream>>>(
        qin, Er + l*640,
        wo_h + l*16384, wo_l + l*16384, bo + l*128,
        ln2s + l*128, ln2b + l*128,
        w1t_h + l*65536, w1t_l + l*65536, b1 + l*512,
        w2t_h + l*65536, w2t_l + l*65536, b2 + l*128,
        hbuf, ssum, (l == 0) ? 1 : 0,
        (l < 8) ? 1 : 0,
        ln1s + ln*128, ln1b + ln*128,
        wqkv_h + ln*49152, wqkv_l + ln*49152,
        bq + ln*128, bk + ln*128, bv + ln*128, qout, 1 << l);
  }

  k_out<<<128, 256, 0, stream>>>(hbuf, Wout, bout, outf);
  k_red1<<<128, 256, 0, stream>>>(ssum, part);
  k_tail2<<<1, 512, 0, stream>>>(part, Wt, bt, outf);
}

// Round 9
// 669.396 us; speedup vs baseline: 3.4052x; 1.0031x over previous
//
#include <hip/hip_runtime.h>

#define T_ 4096
#define B_ 4

typedef unsigned short u16;
typedef __bf16 bf16x8 __attribute__((ext_vector_type(8)));
typedef float f32x4 __attribute__((ext_vector_type(4)));

__device__ inline void splitbf(float v, u16& h, u16& l) {
  __bf16 hb = (__bf16)v;
  float r = v - (float)hb;
  __bf16 lb = (__bf16)r;
  h = __builtin_bit_cast(u16, hb);
  l = __builtin_bit_cast(u16, lb);
}

#define MFMA(a,b,c) __builtin_amdgcn_mfma_f32_16x16x32_bf16((a),(b),(c),0,0,0)

// ---- fused conv1(5x3,pad2)+pool3+relu + conv2(1x12)+pool3+relu, t=4/block
__global__ __launch_bounds__(256) void k_conv12m(
    const float* __restrict__ x, const float* __restrict__ w1,
    const float* __restrict__ b1,
    const u16* __restrict__ wh, const u16* __restrict__ wl,
    const float* __restrict__ b2,
    u16* __restrict__ oh, u16* __restrict__ ol)
{
  __shared__ float sx[8][130];
  __shared__ float w1s[480];
  __shared__ float b1s[32];
  __shared__ u16 sh[4*43*40];
  __shared__ u16 sl[4*43*40];
  __shared__ float dmp[4][15][66];
  const int tid = threadIdx.x;
  const int t0 = blockIdx.x * 4;
  const int b = blockIdx.y;
  const float* xb = x + (size_t)b*T_*128;
  for (int i = tid; i < 1024; i += 256) {
    int r = i >> 7, c = i & 127;
    int t = t0 - 2 + r;
    sx[r][c] = (t >= 0 && t < T_) ? xb[t*128 + c] : 0.f;
  }
  for (int i = tid; i < 480; i += 256) w1s[i] = w1[i];
  if (tid < 32) b1s[tid] = b1[tid];
  for (int i = tid; i < 160; i += 256) {   // zero pad cell w=42
    int tt = i / 40, c = i - tt*40;
    sh[(tt*43 + 42)*40 + c] = 0;
    sl[(tt*43 + 42)*40 + c] = 0;
  }
  __syncthreads();
  // conv1: thread = (c1, tt, half); 21 wp per thread; w1 in regs
  {
    const int c1 = tid & 31, tt = (tid >> 5) & 3, hf = tid >> 7;
    float w1r[15];
    #pragma unroll
    for (int i = 0; i < 15; i++) w1r[i] = w1s[c1*15 + i];
    float bb1 = b1s[c1];
    for (int wp = hf*21; wp < hf*21 + 21; wp++) {
      int c0 = wp*3;
      float s0 = 0.f, s1 = 0.f, s2 = 0.f;
      #pragma unroll
      for (int kh = 0; kh < 5; kh++) {
        float x0 = sx[tt+kh][c0],   x1 = sx[tt+kh][c0+1];
        float x2 = sx[tt+kh][c0+2], x3 = sx[tt+kh][c0+3];
        float x4 = sx[tt+kh][c0+4];
        float wA = w1r[kh*3], wB = w1r[kh*3+1], wC = w1r[kh*3+2];
        s0 += x0*wA + x1*wB + x2*wC;
        s1 += x1*wA + x2*wB + x3*wC;
        s2 += x2*wA + x3*wB + x4*wC;
      }
      float v = fmaxf(fmaxf(fmaxf(s0, s1), s2) + bb1, 0.f);
      u16 hh, ll; splitbf(v, hh, ll);
      int dd = (tt*43 + wp)*40 + c1;
      sh[dd] = hh; sl[dd] = ll;
    }
  }
  __syncthreads();
  // conv2 via MFMA: wave wid handles t = t0+wid
  const int lane = tid & 63;
  const int wid = tid >> 6;
  const int lr = lane & 15;
  const int lk8 = (lane >> 4) * 8;
  f32x4 acc[2][4] = {};
  #pragma unroll 3
  for (int kw = 0; kw < 12; kw++) {
    bf16x8 bh[4], bl[4];
    #pragma unroll
    for (int nf = 0; nf < 4; nf++) {
      int go = ((nf*12 + kw) << 9) + (lane << 3);
      bh[nf] = *(const bf16x8*)(wh + go);
      bl[nf] = *(const bf16x8*)(wl + go);
    }
    #pragma unroll
    for (int mf = 0; mf < 2; mf++) {
      int lofs = (wid*43 + mf*16 + lr + kw)*40 + lk8;
      bf16x8 ah = *(const bf16x8*)&sh[lofs];
      bf16x8 al = *(const bf16x8*)&sl[lofs];
      #pragma unroll
      for (int nf = 0; nf < 4; nf++) {
        acc[mf][nf] = MFMA(ah, bl[nf], acc[mf][nf]);
        acc[mf][nf] = MFMA(al, bh[nf], acc[mf][nf]);
        acc[mf][nf] = MFMA(ah, bh[nf], acc[mf][nf]);
      }
    }
  }
  const int lg = lane >> 4;
  {
    int t = t0 + wid;
    for (int half = 0; half < 2; half++) {
      #pragma unroll
      for (int mf = 0; mf < 2; mf++)
        #pragma unroll
        for (int r = 0; r < 4; r++) {
          int grow = mf*16 + lg*4 + r;
          int lrow = grow - half*15;
          if (lrow >= 0 && lrow < 15) {
            #pragma unroll
            for (int nf = 0; nf < 4; nf++)
              dmp[wid][lrow][nf*16 + lr] = acc[mf][nf][r];
          }
        }
      asm volatile("s_waitcnt lgkmcnt(0)" ::: "memory");
      #pragma unroll
      for (int it = 0; it < 5; it++) {
        float v = fmaxf(fmaxf(dmp[wid][it*3][lane], dmp[wid][it*3+1][lane]),
                        dmp[wid][it*3+2][lane]);
        v = fmaxf(v + b2[lane], 0.f);
        u16 hh, ll; splitbf(v, hh, ll);
        size_t o = (size_t)((b*T_ + t)*10 + half*5 + it)*64 + lane;
        oh[o] = hh; ol[o] = ll;
      }
      asm volatile("s_waitcnt lgkmcnt(0)" ::: "memory");
    }
  }
}

// ---------------- conv3 (3x6, pad_h=1) + pool3 + relu via MFMA -------------
__global__ __launch_bounds__(256) void k_conv3m(
    const u16* __restrict__ ih, const u16* __restrict__ il,
    const u16* __restrict__ wh, const u16* __restrict__ wl,
    const float* __restrict__ b3, float* __restrict__ hout)
{
  __shared__ u16 sh[18*720];
  __shared__ u16 sl[18*720];
  __shared__ float dmp[48][132];
  const int tid = threadIdx.x;
  const int t0 = (blockIdx.x & 255) * 16;
  const int b = blockIdx.y;
  for (int i = tid; i < 1440; i += 256) {
    int cg = i & 7;
    int w = (i >> 3) % 10;
    int tt = i / 80;
    int t = t0 - 1 + tt;
    int dd = tt*720 + w*72 + cg*8;
    if (t >= 0 && t < T_) {
      size_t so = (size_t)((b*T_ + t)*10 + w)*64 + cg*8;
      *(ulonglong2*)&sh[dd] = *(const ulonglong2*)&ih[so];
      *(ulonglong2*)&sl[dd] = *(const ulonglong2*)&il[so];
    } else {
      ulonglong2 z; z.x = 0; z.y = 0;
      *(ulonglong2*)&sh[dd] = z;
      *(ulonglong2*)&sl[dd] = z;
    }
  }
  __syncthreads();
  const int lane = tid & 63;
  const int wid = tid >> 6;
  const int lr = lane & 15;
  const int lk8 = (lane >> 4) * 8;
  int tlm[3], wom[3];
  #pragma unroll
  for (int mf = 0; mf < 3; mf++) {
    int r = mf*16 + lr;
    tlm[mf] = r / 3;
    wom[mf] = r - tlm[mf]*3;
  }
  f32x4 acc[3][2] = {};
  #pragma unroll 2
  for (int kh = 0; kh < 3; kh++) {
    #pragma unroll
    for (int kw = 0; kw < 6; kw++) {
      #pragma unroll
      for (int chh = 0; chh < 2; chh++) {
        int s = (kh*6 + kw)*2 + chh;
        int ch = chh*32;
        bf16x8 bh[2], bl[2];
        #pragma unroll
        for (int nfl = 0; nfl < 2; nfl++) {
          int go = (((wid*2 + nfl)*36 + s) << 9) + (lane << 3);
          bh[nfl] = *(const bf16x8*)(wh + go);
          bl[nfl] = *(const bf16x8*)(wl + go);
        }
        #pragma unroll
        for (int mf = 0; mf < 3; mf++) {
          int lofs = (tlm[mf] + kh)*720 + (wom[mf] + kw)*72 + ch + lk8;
          bf16x8 ah = *(const bf16x8*)&sh[lofs];
          bf16x8 al = *(const bf16x8*)&sl[lofs];
          #pragma unroll
          for (int nfl = 0; nfl < 2; nfl++) {
            acc[mf][nfl] = MFMA(ah, bl[nfl], acc[mf][nfl]);
            acc[mf][nfl] = MFMA(al, bh[nfl], acc[mf][nfl]);
            acc[mf][nfl] = MFMA(ah, bh[nfl], acc[mf][nfl]);
          }
        }
      }
    }
  }
  const int lg = lane >> 4;
  #pragma unroll
  for (int mf = 0; mf < 3; mf++)
    #pragma unroll
    for (int r = 0; r < 4; r++) {
      int row = mf*16 + lg*4 + r;
      #pragma unroll
      for (int nfl = 0; nfl < 2; nfl++)
        dmp[row][wid*32 + nfl*16 + lr] = acc[mf][nfl][r];
    }
  __syncthreads();
  for (int i = tid; i < 2048; i += 256) {
    int c3 = i & 127;
    int tt = i >> 7;
    float v = fmaxf(fmaxf(dmp[tt*3][c3], dmp[tt*3+1][c3]), dmp[tt*3+2][c3]);
    v = fmaxf(v + b3[c3], 0.f);
    hout[(size_t)(b*T_ + t0 + tt)*128 + c3] = v;
  }
}

__device__ inline float wave_sum(float v) {
  #pragma unroll
  for (int m = 1; m < 64; m <<= 1) v += __shfl_xor(v, m, 64);
  return v;
}

// ---------------- weight prep (single launch, block-uniform segments) ------
__device__ inline void prep_fr(const float* __restrict__ src,
                               u16* __restrict__ dh, u16* __restrict__ dl,
                               int K, int N, int matStride, int idx)
{
  int mat = idx / (K*N);
  int rem = idx - mat*(K*N);
  int k = rem / N;
  int n = rem - k*N;
  float v = src[idx];
  u16 h, l; splitbf(v, h, l);
  int nt = n >> 4, ks = k >> 5, ksub = k & 31;
  size_t o = (size_t)mat*matStride + (size_t)((nt*(K>>5) + ks) << 9)
           + (((ksub >> 3) << 4) + (n & 15))*8 + (ksub & 7);
  dh[o] = h; dl[o] = l;
}

__global__ __launch_bounds__(256) void k_wprep_all(
    const float* __restrict__ Wq, const float* __restrict__ Wk,
    const float* __restrict__ Wv, const float* __restrict__ Wo,
    const float* __restrict__ W1, const float* __restrict__ W2,
    const float* __restrict__ c2w, const float* __restrict__ c3w,
    u16* wqkv_h, u16* wqkv_l, u16* wo_h, u16* wo_l,
    u16* w1t_h, u16* w1t_l, u16* w2t_h, u16* w2t_l,
    u16* wc2_h, u16* wc2_l, u16* wc3_h, u16* wc3_l)
{
  const int bid = blockIdx.x;
  const int tid = threadIdx.x;
  if (bid < 576) {
    prep_fr(Wq, wqkv_h, wqkv_l, 128, 128, 49152, bid*256 + tid);
  } else if (bid < 1152) {
    prep_fr(Wk, wqkv_h + 16384, wqkv_l + 16384, 128, 128, 49152, (bid-576)*256 + tid);
  } else if (bid < 1728) {
    prep_fr(Wv, wqkv_h + 32768, wqkv_l + 32768, 128, 128, 49152, (bid-1152)*256 + tid);
  } else if (bid < 2304) {
    prep_fr(Wo, wo_h, wo_l, 128, 128, 16384, (bid-1728)*256 + tid);
  } else if (bid < 4608) {
    prep_fr(W1, w1t_h, w1t_l, 128, 512, 65536, (bid-2304)*256 + tid);
  } else if (bid < 6912) {
    prep_fr(W2, w2t_h, w2t_l, 512, 128, 65536, (bid-4608)*256 + tid);
  } else if (bid < 7008) {
    int idx = (bid-6912)*256 + tid;
    int c2 = idx / 384;
    int rem = idx - c2*384;
    int c1 = rem / 12;
    int kw = rem - c1*12;
    float v = c2w[idx];
    u16 h, l; splitbf(v, h, l);
    size_t o = (size_t)((((c2 >> 4)*12 + kw) << 9))
             + (((c1 >> 3) << 4) + (c2 & 15))*8 + (c1 & 7);
    wc2_h[o] = h; wc2_l[o] = l;
  } else {
    int idx = (bid-7008)*256 + tid;
    int c3 = idx / 1152;
    int rem = idx - c3*1152;
    int c2 = rem / 18;
    int khkw = rem - c2*18;
    float v = c3w[idx];
    u16 h, l; splitbf(v, h, l);
    int s = khkw*2 + (c2 >> 5);
    int c = c2 & 31;
    size_t o = (size_t)((((c3 >> 4)*36 + s) << 9))
             + (((c >> 3) << 4) + (c3 & 15))*8 + (c & 7);
    wc3_h[o] = h; wc3_l[o] = l;
  }
}

// ---------------- layer-0 pre: LN1 (from hbuf, in LDS) + QKV ---------------
__global__ __launch_bounds__(512) void k_pre0(
    const float* __restrict__ hbuf,
    const float* __restrict__ sc, const float* __restrict__ bi,
    const u16* __restrict__ Qh, const u16* __restrict__ Ql,
    const float* __restrict__ bq, const float* __restrict__ bk,
    const float* __restrict__ bv, float* __restrict__ qout)
{
  __shared__ u16 sAh[32*136], sAl[32*136];
  const int tid = threadIdx.x, lane = tid & 63;
  const int m0 = blockIdx.x * 32;
  {
    const int row = tid >> 4, p = tid & 15;
    float xv[8], s = 0.f;
    const float* hp = &hbuf[(size_t)(m0 + row)*128 + p*8];
    #pragma unroll
    for (int i = 0; i < 8; i++) { xv[i] = hp[i]; s += xv[i]; }
    s += __shfl_xor(s, 1); s += __shfl_xor(s, 2);
    s += __shfl_xor(s, 4); s += __shfl_xor(s, 8);
    float mean = s * (1.f/128.f);
    float v = 0.f;
    #pragma unroll
    for (int i = 0; i < 8; i++) { float d = xv[i]-mean; v += d*d; }
    v += __shfl_xor(v, 1); v += __shfl_xor(v, 2);
    v += __shfl_xor(v, 4); v += __shfl_xor(v, 8);
    float rs = rsqrtf(v*(1.f/128.f) + 1e-5f);
    #pragma unroll
    for (int i = 0; i < 8; i++) {
      int cc = p*8 + i;
      float y = (xv[i]-mean)*rs*sc[cc] + bi[cc];
      u16 hh, ll; splitbf(y, hh, ll);
      sAh[row*136 + cc] = hh; sAl[row*136 + cc] = ll;
    }
  }
  __syncthreads();
  const int wv = tid >> 6, mq = wv >> 2, nq = wv & 3;
  const int lr = lane & 15, lg = lane >> 4, l8 = lg*8;
  for (int z = 0; z < 3; z++) {
    const u16* wh = Qh + z*16384;
    const u16* wl = Ql + z*16384;
    const float* bias = (z == 0) ? bq : (z == 1) ? bk : bv;
    float* C = qout + (size_t)z*2097152;
    f32x4 acc[2] = {};
    #pragma unroll
    for (int ks = 0; ks < 4; ks++) {
      bf16x8 ah = *(const bf16x8*)&sAh[(mq*16 + lr)*136 + ks*32 + l8];
      bf16x8 al = *(const bf16x8*)&sAl[(mq*16 + lr)*136 + ks*32 + l8];
      #pragma unroll
      for (int nf = 0; nf < 2; nf++) {
        int go = (((nq*2 + nf)*4 + ks) << 9) + (lane << 3);
        bf16x8 bh = *(const bf16x8*)(wh + go);
        bf16x8 bl = *(const bf16x8*)(wl + go);
        acc[nf] = MFMA(ah, bl, acc[nf]);
        acc[nf] = MFMA(al, bh, acc[nf]);
        acc[nf] = MFMA(ah, bh, acc[nf]);
      }
    }
    #pragma unroll
    for (int nf = 0; nf < 2; nf++) {
      int col = nq*32 + nf*16 + lr;
      float bb = bias[col];
      #pragma unroll
      for (int r = 0; r < 4; r++)
        C[(size_t)(m0 + mq*16 + lg*4 + r)*128 + col] = acc[nf][r] + bb;
    }
  }
}

// ------- FULL LAYER + (l==8) fused model tail ------------------------------
__global__ __launch_bounds__(512) void k_layer(
    const float* __restrict__ qin,
    const float* __restrict__ Er,
    const u16* __restrict__ Woh, const u16* __restrict__ Wol,
    const float* __restrict__ bo,
    const float* __restrict__ sc2, const float* __restrict__ bi2,
    const u16* __restrict__ W1h, const u16* __restrict__ W1l,
    const float* __restrict__ b1,
    const u16* __restrict__ W2h, const u16* __restrict__ W2l,
    const float* __restrict__ b2,
    float* __restrict__ hbuf, float* __restrict__ ssum, int skip_init,
    int do_qkv,
    const float* __restrict__ sc1, const float* __restrict__ bi1,
    const u16* __restrict__ Qh, const u16* __restrict__ Ql,
    const float* __restrict__ bq, const float* __restrict__ bk,
    const float* __restrict__ bv, float* __restrict__ qout, int dil,
    const float* __restrict__ Wout, const float* __restrict__ bout,
    float* __restrict__ part, float* __restrict__ outf)
{
  __shared__ u16 sAh[32*136], sAl[32*136];
  __shared__ __align__(16) char ureg[17408];   // hid (D) | dmp (B/C/E/F/tail)
  u16* hidH = (u16*)ureg;
  u16* hidL = (u16*)(ureg + 8704);
  float* dmp = (float*)ureg;
  const int tid = threadIdx.x, lane = tid & 63, wv = tid >> 6;
  const int m0 = blockIdx.x * 32;
  const int b = m0 >> 12;
  const int t0 = m0 & 4095;
  const float* qb = qin;
  const float* kb = qin + 2097152;
  const float* vb = qin + 4194304;
  // ---- Phase A: attention (8 waves x 4 rows) -> sA
  for (int rr = 0; rr < 4; rr++) {
    int r = wv*4 + rr;
    int t = t0 + r;
    int bt = m0 + r;
    #pragma unroll
    for (int h = 0; h < 2; h++) {
      float qd = qb[(size_t)bt*128 + h*64 + lane];
      float s[5];
      int tpc_arr[5];
      #pragma unroll
      for (int a = 0; a < 5; a++) {
        int tp = t + (a-2)*dil;
        bool valid = (tp >= 0 && tp < T_);
        int tpc = tp < 0 ? 0 : (tp > T_-1 ? T_-1 : tp);
        tpc_arr[a] = tpc;
        float kd = kb[(size_t)(b*T_ + tpc)*128 + h*64 + lane];
        float er = Er[(h*5 + a)*64 + lane];
        float p = qd * (kd + er);
        p = wave_sum(p);
        s[a] = valid ? p * 0.125f : -1e30f;
      }
      float mx = s[0];
      #pragma unroll
      for (int a = 1; a < 5; a++) mx = fmaxf(mx, s[a]);
      float p[5], psum = 0.f;
      #pragma unroll
      for (int a = 0; a < 5; a++) { p[a] = __expf(s[a]-mx); psum += p[a]; }
      float inv = 1.f/psum;
      float o = 0.f;
      #pragma unroll
      for (int a = 0; a < 5; a++)
        o += p[a] * vb[(size_t)(b*T_ + tpc_arr[a])*128 + h*64 + lane];
      float vo = o * inv;
      u16 hh, ll; splitbf(vo, hh, ll);
      sAh[r*136 + h*64 + lane] = hh;
      sAl[r*136 + h*64 + lane] = ll;
    }
  }
  __syncthreads();
  // ---- Phase B: Wo GEMM + residual + skip-acc
  const int lr = lane & 15, lg = lane >> 4, l8 = lg*8;
  const int mq = wv >> 2, nq = wv & 3;
  {
    f32x4 acc[2] = {};
    #pragma unroll
    for (int ks = 0; ks < 4; ks++) {
      bf16x8 ah = *(const bf16x8*)&sAh[(mq*16 + lr)*136 + ks*32 + l8];
      bf16x8 al = *(const bf16x8*)&sAl[(mq*16 + lr)*136 + ks*32 + l8];
      #pragma unroll
      for (int nf = 0; nf < 2; nf++) {
        int go = (((nq*2 + nf)*4 + ks) << 9) + (lane << 3);
        bf16x8 bh = *(const bf16x8*)(Woh + go);
        bf16x8 bl = *(const bf16x8*)(Wol + go);
        acc[nf] = MFMA(ah, bl, acc[nf]);
        acc[nf] = MFMA(al, bh, acc[nf]);
        acc[nf] = MFMA(ah, bh, acc[nf]);
      }
    }
    #pragma unroll
    for (int nf = 0; nf < 2; nf++) {
      int col = nq*32 + nf*16 + lr;
      float bb = bo[col];
      #pragma unroll
      for (int r = 0; r < 4; r++) {
        int row = mq*16 + lg*4 + r;
        size_t o = (size_t)(m0 + row)*128 + col;
        float val = acc[nf][r] + bb;
        if (skip_init) ssum[o] = val; else ssum[o] += val;
        float hn = hbuf[o] + val;
        hbuf[o] = hn;
        dmp[row*132 + col] = hn;
      }
    }
  }
  __syncthreads();
  // ---- Phase C: LN2 -> sA
  {
    const int row = tid >> 4, p = tid & 15;
    float xv[8], s = 0.f;
    const float* dp = &dmp[row*132 + p*8];
    #pragma unroll
    for (int i = 0; i < 8; i++) { xv[i] = dp[i]; s += xv[i]; }
    s += __shfl_xor(s, 1); s += __shfl_xor(s, 2);
    s += __shfl_xor(s, 4); s += __shfl_xor(s, 8);
    float mean = s * (1.f/128.f);
    float v = 0.f;
    #pragma unroll
    for (int i = 0; i < 8; i++) { float d = xv[i]-mean; v += d*d; }
    v += __shfl_xor(v, 1); v += __shfl_xor(v, 2);
    v += __shfl_xor(v, 4); v += __shfl_xor(v, 8);
    float rs = rsqrtf(v*(1.f/128.f) + 1e-5f);
    #pragma unroll
    for (int i = 0; i < 8; i++) {
      int cc = p*8 + i;
      float y = (xv[i]-mean)*rs*sc2[cc] + bi2[cc];
      u16 hh, ll; splitbf(y, hh, ll);
      sAh[row*136 + cc] = hh; sAl[row*136 + cc] = ll;
    }
  }
  __syncthreads();
  // ---- Phase D: FFN (single-buffered hid aliased over dmp)
  f32x4 acc2[2] = {};
  for (int c = 0; c < 4; c++) {
    f32x4 acc1[2] = {};
    #pragma unroll
    for (int ks = 0; ks < 4; ks++) {
      bf16x8 ah = *(const bf16x8*)&sAh[(mq*16 + lr)*136 + ks*32 + l8];
      bf16x8 al = *(const bf16x8*)&sAl[(mq*16 + lr)*136 + ks*32 + l8];
      #pragma unroll
      for (int nf = 0; nf < 2; nf++) {
        int go = (((c*8 + nq*2 + nf)*4 + ks) << 9) + (lane << 3);
        bf16x8 bh = *(const bf16x8*)(W1h + go);
        bf16x8 bl = *(const bf16x8*)(W1l + go);
        acc1[nf] = MFMA(ah, bl, acc1[nf]);
        acc1[nf] = MFMA(al, bh, acc1[nf]);
        acc1[nf] = MFMA(ah, bh, acc1[nf]);
      }
    }
    __syncthreads();   // prev chunk's GEMM2 reads (or phase-C dmp reads) done
    #pragma unroll
    for (int nf = 0; nf < 2; nf++) {
      int col = nq*32 + nf*16 + lr;
      float bb = b1[c*128 + col];
      #pragma unroll
      for (int r = 0; r < 4; r++) {
        int row = mq*16 + lg*4 + r;
        float hv = fmaxf(acc1[nf][r] + bb, 0.f);
        u16 hh, ll; splitbf(hv, hh, ll);
        hidH[row*136 + col] = hh;
        hidL[row*136 + col] = ll;
      }
    }
    __syncthreads();
    #pragma unroll
    for (int ks = 0; ks < 4; ks++) {
      bf16x8 ah = *(const bf16x8*)&hidH[(mq*16 + lr)*136 + ks*32 + l8];
      bf16x8 al = *(const bf16x8*)&hidL[(mq*16 + lr)*136 + ks*32 + l8];
      #pragma unroll
      for (int nf = 0; nf < 2; nf++) {
        int go = (((nq*2 + nf)*16 + c*4 + ks) << 9) + (lane << 3);
        bf16x8 bh = *(const bf16x8*)(W2h + go);
        bf16x8 bl = *(const bf16x8*)(W2l + go);
        acc2[nf] = MFMA(ah, bl, acc2[nf]);
        acc2[nf] = MFMA(al, bh, acc2[nf]);
        acc2[nf] = MFMA(ah, bh, acc2[nf]);
      }
    }
  }
  __syncthreads();   // all GEMM2 reads done before dmp overwrite
  // ---- Phase E: FFN residual -> hbuf + dmp
  #pragma unroll
  for (int nf = 0; nf < 2; nf++) {
    int col = nq*32 + nf*16 + lr;
    float bb = b2[col];
    #pragma unroll
    for (int r = 0; r < 4; r++) {
      int row = mq*16 + lg*4 + r;
      size_t o = (size_t)(m0 + row)*128 + col;
      float hn = hbuf[o] + acc2[nf][r] + bb;
      hbuf[o] = hn;
      dmp[row*132 + col] = hn;
    }
  }
  __syncthreads();
  if (do_qkv) {
    // ---- Phase F: LN1(next) -> sA, then QKV(next) -> qout
    {
      const int row = tid >> 4, p = tid & 15;
      float xv[8], s = 0.f;
      const float* dp = &dmp[row*132 + p*8];
      #pragma unroll
      for (int i = 0; i < 8; i++) { xv[i] = dp[i]; s += xv[i]; }
      s += __shfl_xor(s, 1); s += __shfl_xor(s, 2);
      s += __shfl_xor(s, 4); s += __shfl_xor(s, 8);
      float mean = s * (1.f/128.f);
      float v = 0.f;
      #pragma unroll
      for (int i = 0; i < 8; i++) { float d = xv[i]-mean; v += d*d; }
      v += __shfl_xor(v, 1); v += __shfl_xor(v, 2);
      v += __shfl_xor(v, 4); v += __shfl_xor(v, 8);
      float rs = rsqrtf(v*(1.f/128.f) + 1e-5f);
      #pragma unroll
      for (int i = 0; i < 8; i++) {
        int cc = p*8 + i;
        float y = (xv[i]-mean)*rs*sc1[cc] + bi1[cc];
        u16 hh, ll; splitbf(y, hh, ll);
        sAh[row*136 + cc] = hh; sAl[row*136 + cc] = ll;
      }
    }
    __syncthreads();
    for (int z = 0; z < 3; z++) {
      const u16* wh = Qh + z*16384;
      const u16* wl = Ql + z*16384;
      const float* bias = (z == 0) ? bq : (z == 1) ? bk : bv;
      float* C = qout + (size_t)z*2097152;
      f32x4 acc[2] = {};
      #pragma unroll
      for (int ks = 0; ks < 4; ks++) {
        bf16x8 ah = *(const bf16x8*)&sAh[(mq*16 + lr)*136 + ks*32 + l8];
        bf16x8 al = *(const bf16x8*)&sAl[(mq*16 + lr)*136 + ks*32 + l8];
        #pragma unroll
        for (int nf = 0; nf < 2; nf++) {
          int go = (((nq*2 + nf)*4 + ks) << 9) + (lane << 3);
          bf16x8 bh = *(const bf16x8*)(wh + go);
          bf16x8 bl = *(const bf16x8*)(wl + go);
          acc[nf] = MFMA(ah, bl, acc[nf]);
          acc[nf] = MFMA(al, bh, acc[nf]);
          acc[nf] = MFMA(ah, bh, acc[nf]);
        }
      }
      #pragma unroll
      for (int nf = 0; nf < 2; nf++) {
        int col = nq*32 + nf*16 + lr;
        float bb = bias[col];
        #pragma unroll
        for (int r = 0; r < 4; r++)
          C[(size_t)(m0 + mq*16 + lg*4 + r)*128 + col] = acc[nf][r] + bb;
      }
    }
  } else {
    // ---- fused model tail (l==8): out head + skip partial
    {
      const int row = tid >> 4, p = tid & 15;
      float o0 = 0.f, o1 = 0.f;
      const float* dp = &dmp[row*132 + p*8];
      #pragma unroll
      for (int i = 0; i < 8; i++) {
        float hv = fmaxf(dp[i], 0.f);
        o0 += hv * Wout[(p*8 + i)*2];
        o1 += hv * Wout[(p*8 + i)*2 + 1];
      }
      o0 += __shfl_xor(o0, 1); o0 += __shfl_xor(o0, 2);
      o0 += __shfl_xor(o0, 4); o0 += __shfl_xor(o0, 8);
      o1 += __shfl_xor(o1, 1); o1 += __shfl_xor(o1, 2);
      o1 += __shfl_xor(o1, 4); o1 += __shfl_xor(o1, 8);
      if (p == 0) {
        outf[(size_t)(m0 + row)*2]     = o0 + bout[0];
        outf[(size_t)(m0 + row)*2 + 1] = o1 + bout[1];
      }
    }
    __syncthreads();   // dmp reads done before reuse as pr
    {
      float* pr = dmp;
      int c = tid & 127, q = tid >> 7;
      float s = 0.f;
      #pragma unroll
      for (int r = 0; r < 8; r++)
        s += fmaxf(ssum[(size_t)(m0 + q*8 + r)*128 + c], 0.f);
      pr[q*128 + c] = s;
      __syncthreads();
      if (tid < 128)
        part[(size_t)blockIdx.x*128 + tid] =
            pr[tid] + pr[128+tid] + pr[256+tid] + pr[384+tid];
    }
  }
}

// ---------------- final tail: mean + t-projection --------------------------
__global__ __launch_bounds__(512) void k_tail2(
    const float* __restrict__ part, const float* __restrict__ Wt,
    const float* __restrict__ btb, float* __restrict__ out)
{
  __shared__ float mb[512];
  const int tid = threadIdx.x;
  int b = tid >> 7, c = tid & 127;
  float s = 0.f;
  for (int j = 0; j < 128; j++)
    s += part[(size_t)(b*128 + j)*128 + c];
  mb[tid] = s * (1.f/4096.f);
  __syncthreads();
  for (int i = tid; i < 1200; i += 512) {
    int bb = i / 300, j = i - bb*300;
    float acc = btb[j];
    #pragma unroll 4
    for (int k2 = 0; k2 < 128; k2++)
      acc += mb[bb*128 + k2] * Wt[k2*300 + j];
    out[32768 + i] = acc;
  }
}

// ---------------- launcher -------------------------------------------------
extern "C" void kernel_launch(void* const* d_in, const int* in_sizes, int n_in,
                              void* d_out, int out_size, void* d_ws, size_t ws_size,
                              hipStream_t stream)
{
  const float* x    = (const float*)d_in[0];
  const float* c1w  = (const float*)d_in[1];
  const float* c1b  = (const float*)d_in[2];
  const float* c2w  = (const float*)d_in[3];
  const float* c2b  = (const float*)d_in[4];
  const float* c3w  = (const float*)d_in[5];
  const float* c3b  = (const float*)d_in[6];
  const float* ln1s = (const float*)d_in[7];
  const float* ln1b = (const float*)d_in[8];
  const float* ln2s = (const float*)d_in[9];
  const float* ln2b = (const float*)d_in[10];
  const float* Wq   = (const float*)d_in[11];
  const float* bq   = (const float*)d_in[12];
  const float* Wk   = (const float*)d_in[13];
  const float* bk   = (const float*)d_in[14];
  const float* Wv   = (const float*)d_in[15];
  const float* bv   = (const float*)d_in[16];
  const float* Wo   = (const float*)d_in[17];
  const float* bo   = (const float*)d_in[18];
  const float* Er   = (const float*)d_in[19];
  const float* W1   = (const float*)d_in[20];
  const float* b1   = (const float*)d_in[21];
  const float* W2   = (const float*)d_in[22];
  const float* b2   = (const float*)d_in[23];
  const float* Wout = (const float*)d_in[24];
  const float* bout = (const float*)d_in[25];
  const float* Wt   = (const float*)d_in[26];
  const float* bt   = (const float*)d_in[27];

  char* W = (char*)d_ws;
  u16* c2o_h = (u16*)W;                      // conv transient (0..42MB)
  u16* c2o_l = (u16*)(W + 20971520);
  char* RB = W + 41943040;
  float* qbuf0 = (float*)RB;                 // qkv ping (25.2 MB)
  float* qbuf1 = (float*)(RB + 25165824);    // qkv pong (25.2 MB)
  char* RC = W + 100663296;
  float* hbuf = (float*)RC;
  float* ssum = (float*)(RC + 8388608);
  u16* wqkv_h = (u16*)(RC + 16777216);
  u16* wqkv_l = wqkv_h + 442368;
  u16* wo_h   = wqkv_l + 442368;
  u16* wo_l   = wo_h + 147456;
  u16* w1t_h  = wo_l + 147456;
  u16* w1t_l  = w1t_h + 589824;
  u16* w2t_h  = w1t_l + 589824;
  u16* w2t_l  = w2t_h + 589824;
  u16* wc2_h  = w2t_l + 589824;
  u16* wc2_l  = wc2_h + 24576;
  u16* wc3_h  = wc2_l + 24576;
  u16* wc3_l  = wc3_h + 147456;
  float* part  = (float*)(wc3_l + 147456);   // 512*128 floats
  float* outf  = (float*)d_out;

  k_wprep_all<<<7584, 256, 0, stream>>>(
      Wq, Wk, Wv, Wo, W1, W2, c2w, c3w,
      wqkv_h, wqkv_l, wo_h, wo_l, w1t_h, w1t_l, w2t_h, w2t_l,
      wc2_h, wc2_l, wc3_h, wc3_l);

  k_conv12m<<<dim3(1024, B_), 256, 0, stream>>>(x, c1w, c1b, wc2_h, wc2_l, c2b,
                                                c2o_h, c2o_l);
  k_conv3m<<<dim3(256, B_), 256, 0, stream>>>(c2o_h, c2o_l, wc3_h, wc3_l, c3b, hbuf);

  // layer-0 LN1 + QKV into qbuf0 (single launch)
  k_pre0<<<512, 512, 0, stream>>>(hbuf, ln1s, ln1b,
                                  wqkv_h, wqkv_l, bq, bk, bv, qbuf0);

  for (int l = 0; l < 9; l++) {
    int ln = (l < 8) ? (l + 1) : 0;
    float* qin  = (l & 1) ? qbuf1 : qbuf0;
    float* qout = (l & 1) ? qbuf0 : qbuf1;
    k_layer<<<512, 512, 0, stream>>>(
        qin, Er + l*640,
        wo_h + l*16384, wo_l + l*16384, bo + l*128,
        ln2s + l*128, ln2b + l*128,
        w1t_h + l*65536, w1t_l + l*65536, b1 + l*512,
        w2t_h + l*65536, w2t_l + l*65536, b2 + l*128,
        hbuf, ssum, (l == 0) ? 1 : 0,
        (l < 8) ? 1 : 0,
        ln1s + ln*128, ln1b + ln*128,
        wqkv_h + ln*49152, wqkv_l + ln*49152,
        bq + ln*128, bk + ln*128, bv + ln*128, qout, 1 << l,
        Wout, bout, part, outf);
  }

  k_tail2<<<1, 512, 0, stream>>>(part, Wt, bt, outf);
}